// Round 5
// baseline (743.800 us; speedup 1.0000x reference)
//
#include <hip/hip_runtime.h>

#define T_TOK 1024
#define H_DIM 2048
#define I_DIM 7168
#define E_NUM 8
#define R_RANK 159
#define RP 160
#define P_PAIRS 2048

typedef __attribute__((ext_vector_type(8))) short short8;
typedef __attribute__((ext_vector_type(4))) float f32x4;

__device__ __forceinline__ ushort f2b(float f) {
  uint u = __float_as_uint(f);
  uint r = (u + 0x7FFFu + ((u >> 16) & 1u)) >> 16;
  return (ushort)r;
}
__device__ __forceinline__ float b2f(ushort u) {
  return __uint_as_float(((uint)u) << 16);
}
__device__ __forceinline__ short8 pack8(float4 a, float4 b) {
  short8 o;
  o[0] = (short)f2b(a.x); o[1] = (short)f2b(a.y); o[2] = (short)f2b(a.z); o[3] = (short)f2b(a.w);
  o[4] = (short)f2b(b.x); o[5] = (short)f2b(b.y); o[6] = (short)f2b(b.z); o[7] = (short)f2b(b.w);
  return o;
}
__device__ __forceinline__ short8 zero8() {
  short8 z;
#pragma unroll
  for (int q = 0; q < 8; ++q) z[q] = 0;
  return z;
}

#define GLOAD(gptr, lptr) \
  __builtin_amdgcn_global_load_lds((const __attribute__((address_space(1))) void*)(gptr), \
                                   (__attribute__((address_space(3))) void*)(lptr), 16, 0, 0)

// ---------------- router ----------------
__global__ __launch_bounds__(256) void router_kernel(
    const float* __restrict__ x, const float* __restrict__ gw,
    float* __restrict__ logits, float* __restrict__ comb,
    int* __restrict__ sel_e, int* __restrict__ cnt) {
  int wave = threadIdx.x >> 6, lane = threadIdx.x & 63;
  int t = blockIdx.x * 4 + wave;
  const float* xr = x + (long)t * H_DIM;
  float acc[8] = {0.f,0.f,0.f,0.f,0.f,0.f,0.f,0.f};
  for (int h = lane * 4; h < H_DIM; h += 256) {
    const float4 xv = *(const float4*)&xr[h];
#pragma unroll
    for (int e = 0; e < 8; ++e) {
      const float4 gv = *(const float4*)&gw[e * H_DIM + h];
      acc[e] += xv.x * gv.x + xv.y * gv.y + xv.z * gv.z + xv.w * gv.w;
    }
  }
#pragma unroll
  for (int off = 32; off > 0; off >>= 1)
#pragma unroll
    for (int e = 0; e < 8; ++e) acc[e] += __shfl_down(acc[e], off);
  if (lane == 0) {
#pragma unroll
    for (int e = 0; e < 8; ++e) logits[(long)t * 8 + e] = acc[e];
    int i0 = 0;
    for (int e = 1; e < 8; ++e) if (acc[e] > acc[i0]) i0 = e;
    int i1 = (i0 == 0) ? 1 : 0;
    for (int e = 0; e < 8; ++e) if (e != i0 && acc[e] > acc[i1]) i1 = e;
    float ee = __expf(acc[i1] - acc[i0]);
    float w0 = 1.f / (1.f + ee), w1 = ee / (1.f + ee);
    for (int e = 0; e < 8; ++e) comb[t * 8 + e] = 0.f;
    comb[t * 8 + i0] = w0;
    comb[t * 8 + i1] = w1;
    sel_e[t * 2] = i0;
    sel_e[t * 2 + 1] = i1;
    atomicAdd(&cnt[i0], 1);
    atomicAdd(&cnt[i1], 1);
  }
}

__global__ void init_kernel(int* cnt, int* cursor) {
  int i = threadIdx.x;
  if (i < 8) { cnt[i] = 0; cursor[i] = 0; }
}

__global__ void scan_kernel(const int* cnt, int* seg) {
  if (threadIdx.x == 0) {
    int s = 0;
    for (int e = 0; e < 8; ++e) { seg[e] = s; s += cnt[e]; }
    seg[8] = s;
  }
}

__global__ void assign_kernel(const int* __restrict__ sel_e, const float* __restrict__ comb,
                              const int* __restrict__ seg, int* __restrict__ cursor,
                              int* __restrict__ tok, float* __restrict__ wrow,
                              int* __restrict__ row_of) {
  int t = blockIdx.x * blockDim.x + threadIdx.x;
  if (t >= T_TOK) return;
  for (int k = 0; k < 2; ++k) {
    int e = sel_e[t * 2 + k];
    int pos = atomicAdd(&cursor[e], 1);
    int row = seg[e] + pos;
    tok[row] = t;
    wrow[row] = comb[t * 8 + e];
    row_of[t * 2 + k] = row;
  }
}

// ---------------- casts ----------------
__global__ void cast8_kernel(const float* __restrict__ src, ushort* __restrict__ dst, long n8) {
  long idx = (long)blockIdx.x * blockDim.x + threadIdx.x;
  long stride = (long)gridDim.x * blockDim.x;
  for (long i = idx; i < n8; i += stride) {
    const float4 a = *(const float4*)&src[i * 8];
    const float4 b = *(const float4*)&src[i * 8 + 4];
    *(short8*)&dst[i * 8] = pack8(a, b);
  }
}

__global__ void padcast8_kernel(const float* __restrict__ src, ushort* __restrict__ dst, long rows) {
  long n8 = rows * (RP / 8);
  long idx = (long)blockIdx.x * blockDim.x + threadIdx.x;
  long stride = (long)gridDim.x * blockDim.x;
  for (long i = idx; i < n8; i += stride) {
    long row = i / (RP / 8);
    int c0 = (int)(i % (RP / 8)) * 8;
    short8 o;
#pragma unroll
    for (int j = 0; j < 8; ++j) {
      int c = c0 + j;
      o[j] = (c < R_RANK) ? (short)f2b(src[row * R_RANK + c]) : (short)0;
    }
    *(short8*)&dst[row * RP + c0] = o;
  }
}

// hc[t,i] = hmid[row0,i] + hmid[row1,i]   (bf16)
__global__ void hcomb_kernel(const ushort* __restrict__ hmid, const int* __restrict__ row_of,
                             ushort* __restrict__ hc) {
  long idx = (long)blockIdx.x * blockDim.x + threadIdx.x;
  long total = (long)T_TOK * I_DIM / 8;
  if (idx >= total) return;
  long i = idx * 8;
  int t = (int)(i / I_DIM);
  int col = (int)(i % I_DIM);
  int r0 = row_of[t * 2], r1 = row_of[t * 2 + 1];
  const short8 a = *(const short8*)&hmid[(long)r0 * I_DIM + col];
  const short8 b = *(const short8*)&hmid[(long)r1 * I_DIM + col];
  short8 o;
#pragma unroll
  for (int j = 0; j < 8; ++j)
    o[j] = (short)f2b(b2f((ushort)a[j]) + b2f((ushort)b[j]));
  *(short8*)&hc[i] = o;
}

// plan B epilogue
__global__ void finalfix_kernel(float* __restrict__ out, const ushort* __restrict__ delta,
                                const int* __restrict__ row_of) {
  long idx = (long)blockIdx.x * blockDim.x + threadIdx.x;
  long total = (long)T_TOK * H_DIM / 4;
  if (idx >= total) return;
  long i = idx * 4;
  int t = (int)(i / H_DIM);
  int col = (int)(i % H_DIM);
  int r0 = row_of[t * 2], r1 = row_of[t * 2 + 1];
  float4 d = *(float4*)&out[i];
  d.x += b2f(delta[(long)r0 * H_DIM + col + 0]) + b2f(delta[(long)r1 * H_DIM + col + 0]);
  d.y += b2f(delta[(long)r0 * H_DIM + col + 1]) + b2f(delta[(long)r1 * H_DIM + col + 1]);
  d.z += b2f(delta[(long)r0 * H_DIM + col + 2]) + b2f(delta[(long)r1 * H_DIM + col + 2]);
  d.w += b2f(delta[(long)r0 * H_DIM + col + 3]) + b2f(delta[(long)r1 * H_DIM + col + 3]);
  *(float4*)&out[i] = d;
}

// plan A epilogue: out = sum_{ks<4} dp + delta[row0] + delta[row1]
__global__ void finalfixA_kernel(float* __restrict__ out, const float* __restrict__ dp,
                                 const ushort* __restrict__ delta, const int* __restrict__ row_of) {
  long idx = (long)blockIdx.x * blockDim.x + threadIdx.x;
  long total = (long)T_TOK * H_DIM / 4;
  if (idx >= total) return;
  long i = idx * 4;
  int t = (int)(i / H_DIM);
  int col = (int)(i % H_DIM);
  int r0 = row_of[t * 2], r1 = row_of[t * 2 + 1];
  const long plane = (long)T_TOK * H_DIM;
  float4 s = *(const float4*)&dp[i];
#pragma unroll
  for (int k = 1; k < 4; ++k) {
    const float4 q = *(const float4*)&dp[k * plane + i];
    s.x += q.x; s.y += q.y; s.z += q.z; s.w += q.w;
  }
  s.x += b2f(delta[(long)r0 * H_DIM + col + 0]) + b2f(delta[(long)r1 * H_DIM + col + 0]);
  s.y += b2f(delta[(long)r0 * H_DIM + col + 1]) + b2f(delta[(long)r1 * H_DIM + col + 1]);
  s.z += b2f(delta[(long)r0 * H_DIM + col + 2]) + b2f(delta[(long)r1 * H_DIM + col + 2]);
  s.w += b2f(delta[(long)r0 * H_DIM + col + 3]) + b2f(delta[(long)r1 * H_DIM + col + 3]);
  *(float4*)&out[i] = s;
}

template <int KS>
__global__ void reduce_cast_kernel(const float* __restrict__ P, long plane,
                                   ushort* __restrict__ out, long n) {
  long i = (long)blockIdx.x * blockDim.x + threadIdx.x;
  if (i >= n) return;
  float s = 0.f;
#pragma unroll
  for (int k = 0; k < KS; ++k) s += P[(long)k * plane + i];
  out[i] = f2b(s);
}

// dual reduce: p1->t1g, p3->t3g in one launch
__global__ void reduce2_kernel(const float* __restrict__ p1, const float* __restrict__ p3,
                               ushort* __restrict__ t1g, ushort* __restrict__ t3g, long n) {
  long i = (long)blockIdx.x * blockDim.x + threadIdx.x;
  if (i >= 2 * n) return;
  const float* P = (i < n) ? p1 : p3;
  ushort* o = (i < n) ? t1g : t3g;
  long ii = (i < n) ? i : i - n;
  float s = 0.f;
#pragma unroll
  for (int k = 0; k < 8; ++k) s += P[(long)k * n + ii];
  o[ii] = f2b(s);
}

// ================= OLD general GEMM (plan B fallback + delta) =================
template <int AF32, int BF32, int CBF16, int PEREXP, int AMAP>
__global__ __launch_bounds__(256) void gemm_f(
    const void* __restrict__ Ap, int lda,
    const void* __restrict__ Bp, int ldb, long Bstride,
    int M, int N, int K, int Npad,
    float* __restrict__ Cf, ushort* __restrict__ Cb, int ldc,
    const int* __restrict__ tok, const int* __restrict__ seg, const int* __restrict__ cnt) {
  __shared__ ushort smem[16384];
  ushort* As = smem;
  ushort* Bs = smem + 4096;
  const float* Af = (const float*)Ap;
  const ushort* Ab = (const ushort*)Ap;
  const float* Bf = (const float*)Bp;
  const ushort* Bb = (const ushort*)Bp;
  const int* amap = tok;
  if (PEREXP) {
    int e = blockIdx.z;
    int m0 = seg[e];
    M = cnt[e];
    if ((int)(blockIdx.y * 128) >= M) return;
    if (AMAP) {
      amap = tok + m0;
    } else {
      if (AF32) Af += (long)m0 * lda; else Ab += (long)m0 * lda;
    }
    if (BF32) Bf += (long)e * Bstride; else Bb += (long)e * Bstride;
    if (CBF16) Cb += (long)m0 * ldc; else Cf += (long)m0 * ldc;
  }
  const int tid = threadIdx.x;
  const int lane = tid & 63, wave = tid >> 6;
  const int wm = (wave >> 1) * 64, wn = (wave & 1) * 64;
  const int row0 = blockIdx.y * 128, col0 = blockIdx.x * 128;
  const int sub_r = tid >> 2;
  const int sub_c = (tid & 3) * 8;

  const float* afrow[2]; const ushort* abrow[2];
  const float* bfrow[2]; const ushort* bbrow[2];
#pragma unroll
  for (int p = 0; p < 2; ++p) {
    int r = row0 + p * 64 + sub_r; if (r > M - 1) r = M - 1;
    if (AMAP) r = amap[r];
    if (AF32) afrow[p] = Af + (long)r * lda + sub_c;
    else      abrow[p] = Ab + (long)r * lda + sub_c;
    int q = col0 + p * 64 + sub_r; if (q > N - 1) q = N - 1;
    if (BF32) bfrow[p] = Bf + (long)q * ldb + sub_c;
    else      bbrow[p] = Bb + (long)q * ldb + sub_c;
  }

  f32x4 acc[4][4] = {};

  for (int k0 = 0; k0 < K; k0 += 32) {
    float4 a0[2], a1[2], b0[2], b1[2];
    if (AF32) {
#pragma unroll
      for (int p = 0; p < 2; ++p) {
        a0[p] = *(const float4*)(afrow[p] + k0);
        a1[p] = *(const float4*)(afrow[p] + k0 + 4);
      }
    }
    if (BF32) {
#pragma unroll
      for (int p = 0; p < 2; ++p) {
        b0[p] = *(const float4*)(bfrow[p] + k0);
        b1[p] = *(const float4*)(bfrow[p] + k0 + 4);
      }
    }
    __syncthreads();
#pragma unroll
    for (int p = 0; p < 2; ++p) {
      if (AF32) {
        *(short8*)&As[(p * 256 + tid) * 8] = pack8(a0[p], a1[p]);
      } else {
        GLOAD(abrow[p] + k0, &As[(p * 256 + tid) * 8]);
      }
      if (BF32) {
        *(short8*)&Bs[(p * 256 + tid) * 8] = pack8(b0[p], b1[p]);
      } else {
        GLOAD(bbrow[p] + k0, &Bs[(p * 256 + tid) * 8]);
      }
    }
    __syncthreads();

    short8 av[4], bv[4];
#pragma unroll
    for (int mi = 0; mi < 4; ++mi)
      av[mi] = *(const short8*)&As[(wm + mi * 16 + (lane & 15)) * 32 + (lane >> 4) * 8];
#pragma unroll
    for (int ni = 0; ni < 4; ++ni)
      bv[ni] = *(const short8*)&Bs[(wn + ni * 16 + (lane & 15)) * 32 + (lane >> 4) * 8];
#pragma unroll
    for (int mi = 0; mi < 4; ++mi)
#pragma unroll
      for (int ni = 0; ni < 4; ++ni)
        acc[mi][ni] = __builtin_amdgcn_mfma_f32_16x16x32_bf16(av[mi], bv[ni], acc[mi][ni], 0, 0, 0);
  }

  const int er = (lane >> 4) * 4;
  const int ec = lane & 15;
  if (CBF16) {
    __syncthreads();
    ushort* Cs = smem;
#pragma unroll
    for (int mi = 0; mi < 4; ++mi)
#pragma unroll
      for (int ni = 0; ni < 4; ++ni)
#pragma unroll
        for (int j = 0; j < 4; ++j) {
          int rr = wm + mi * 16 + er + j;
          int c = wn + ni * 16 + ec;
          Cs[rr * 128 + (c ^ ((rr & 7) << 3))] =
              (col0 + c < N) ? f2b(acc[mi][ni][j]) : (ushort)0;
        }
    __syncthreads();
    const int rl = tid >> 1;
    const int clb = (tid & 1) * 64;
    const int r = row0 + rl;
    if (r < M) {
      const int k8 = (rl & 7) << 3;
#pragma unroll
      for (int jj = 0; jj < 8; ++jj) {
        int cg = col0 + clb + jj * 8;
        if (cg < Npad) {
          short8 v = *(const short8*)&Cs[rl * 128 + ((clb + jj * 8) ^ k8)];
          *(short8*)&Cb[(long)r * ldc + cg] = v;
        }
      }
    }
  } else {
#pragma unroll
    for (int mi = 0; mi < 4; ++mi)
#pragma unroll
      for (int ni = 0; ni < 4; ++ni)
#pragma unroll
        for (int j = 0; j < 4; ++j) {
          int r = row0 + wm + mi * 16 + er + j;
          int c = col0 + wn + ni * 16 + ec;
          if (r < M && c < Npad)
            Cf[(long)r * ldc + c] = (c < N) ? acc[mi][ni][j] : 0.f;
        }
  }
}

// ================= NEW pipelined kernels (prefetch-1, dbuf) =================

// fused base: bgate = xb@Wm1^T, bup = xb@Wm3^T ; B from f32, cast in staging
__global__ __launch_bounds__(256) void gemm_base(
    const ushort* __restrict__ Ab, const float* __restrict__ B1f, const float* __restrict__ B3f,
    ushort* __restrict__ C1, ushort* __restrict__ C3) {
  __shared__ ushort smem[24576];  // As[2][4096] | Bs1[2][4096] | Bs3[2][4096]
  ushort* As  = smem;
  ushort* Bs1 = smem + 8192;
  ushort* Bs3 = smem + 16384;
  const int tid = threadIdx.x;
  const int lane = tid & 63, wave = tid >> 6;
  const int wm = (wave >> 1) * 64, wn = (wave & 1) * 64;
  const int row0 = blockIdx.y * 128, col0 = blockIdx.x * 128;
  const int sub_r = tid >> 2, sub_c = (tid & 3) * 8;

  const ushort* arow[2]; const float* b1row[2]; const float* b3row[2];
#pragma unroll
  for (int p = 0; p < 2; ++p) {
    arow[p]  = Ab + (long)(row0 + p * 64 + sub_r) * H_DIM + sub_c;
    b1row[p] = B1f + (long)(col0 + p * 64 + sub_r) * H_DIM + sub_c;
    b3row[p] = B3f + (long)(col0 + p * 64 + sub_r) * H_DIM + sub_c;
  }

  f32x4 acc1[4][4] = {}, acc3[4][4] = {};

  // prologue: stage tile 0
  {
    float4 c1a[2], c1b[2], c3a[2], c3b[2];
#pragma unroll
    for (int p = 0; p < 2; ++p) {
      c1a[p] = *(const float4*)(b1row[p]);
      c1b[p] = *(const float4*)(b1row[p] + 4);
      c3a[p] = *(const float4*)(b3row[p]);
      c3b[p] = *(const float4*)(b3row[p] + 4);
      GLOAD(arow[p], &As[(p * 256 + tid) * 8]);
    }
#pragma unroll
    for (int p = 0; p < 2; ++p) {
      *(short8*)&Bs1[(p * 256 + tid) * 8] = pack8(c1a[p], c1b[p]);
      *(short8*)&Bs3[(p * 256 + tid) * 8] = pack8(c3a[p], c3b[p]);
    }
    __syncthreads();
  }

  const int NT = H_DIM / 32;  // 64
  for (int t = 0; t < NT; ++t) {
    const int cur = t & 1, nxt = cur ^ 1;
    const bool more = (t + 1 < NT);
    float4 c1a[2], c1b[2], c3a[2], c3b[2];
    if (more) {
      const int ko = (t + 1) * 32;
#pragma unroll
      for (int p = 0; p < 2; ++p) {
        c1a[p] = *(const float4*)(b1row[p] + ko);
        c1b[p] = *(const float4*)(b1row[p] + ko + 4);
        c3a[p] = *(const float4*)(b3row[p] + ko);
        c3b[p] = *(const float4*)(b3row[p] + ko + 4);
        GLOAD(arow[p] + ko, &As[nxt * 4096 + (p * 256 + tid) * 8]);
      }
    }
    short8 av[4], bv1[4], bv3[4];
#pragma unroll
    for (int mi = 0; mi < 4; ++mi)
      av[mi] = *(const short8*)&As[cur * 4096 + (wm + mi * 16 + (lane & 15)) * 32 + (lane >> 4) * 8];
#pragma unroll
    for (int ni = 0; ni < 4; ++ni) {
      bv1[ni] = *(const short8*)&Bs1[cur * 4096 + (wn + ni * 16 + (lane & 15)) * 32 + (lane >> 4) * 8];
      bv3[ni] = *(const short8*)&Bs3[cur * 4096 + (wn + ni * 16 + (lane & 15)) * 32 + (lane >> 4) * 8];
    }
#pragma unroll
    for (int mi = 0; mi < 4; ++mi)
#pragma unroll
      for (int ni = 0; ni < 4; ++ni) {
        acc1[mi][ni] = __builtin_amdgcn_mfma_f32_16x16x32_bf16(av[mi], bv1[ni], acc1[mi][ni], 0, 0, 0);
        acc3[mi][ni] = __builtin_amdgcn_mfma_f32_16x16x32_bf16(av[mi], bv3[ni], acc3[mi][ni], 0, 0, 0);
      }
    __syncthreads();  // done reading cur; A gload into nxt drained
    if (more) {
#pragma unroll
      for (int p = 0; p < 2; ++p) {
        *(short8*)&Bs1[nxt * 4096 + (p * 256 + tid) * 8] = pack8(c1a[p], c1b[p]);
        *(short8*)&Bs3[nxt * 4096 + (p * 256 + tid) * 8] = pack8(c3a[p], c3b[p]);
      }
      __syncthreads();
    }
  }

  // epilogue: LDS-transpose, two phases (Cs = 32KB alias)
  const int er = (lane >> 4) * 4, ec = lane & 15;
  const int rl = tid >> 1, clb = (tid & 1) * 64;
  const int r = row0 + rl;
  const int k8 = (rl & 7) << 3;
  ushort* Cs = smem;
#pragma unroll
  for (int mi = 0; mi < 4; ++mi)
#pragma unroll
    for (int ni = 0; ni < 4; ++ni)
#pragma unroll
      for (int j = 0; j < 4; ++j) {
        int rr = wm + mi * 16 + er + j, c = wn + ni * 16 + ec;
        Cs[rr * 128 + (c ^ ((rr & 7) << 3))] = f2b(acc1[mi][ni][j]);
      }
  __syncthreads();
#pragma unroll
  for (int jj = 0; jj < 8; ++jj) {
    int cc = clb + jj * 8;
    *(short8*)&C1[(long)r * I_DIM + col0 + cc] = *(const short8*)&Cs[rl * 128 + (cc ^ k8)];
  }
  __syncthreads();
#pragma unroll
  for (int mi = 0; mi < 4; ++mi)
#pragma unroll
    for (int ni = 0; ni < 4; ++ni)
#pragma unroll
      for (int j = 0; j < 4; ++j) {
        int rr = wm + mi * 16 + er + j, c = wn + ni * 16 + ec;
        Cs[rr * 128 + (c ^ ((rr & 7) << 3))] = f2b(acc3[mi][ni][j]);
      }
  __syncthreads();
#pragma unroll
  for (int jj = 0; jj < 8; ++jj) {
    int cc = clb + jj * 8;
    *(short8*)&C3[(long)r * I_DIM + col0 + cc] = *(const short8*)&Cs[rl * 128 + (cc ^ k8)];
  }
}

// t1/t3 fused dual-B (dv1/dv3 f32), split-K8 per expert, f32 partial out
__global__ __launch_bounds__(256) void gemm_t13f(
    const ushort* __restrict__ xb, const float* __restrict__ dv1, const float* __restrict__ dv3,
    const int* __restrict__ tok, const int* __restrict__ seg, const int* __restrict__ cnt,
    float* __restrict__ p1, float* __restrict__ p3) {
  __shared__ ushort smem[24576];
  ushort* As  = smem;
  ushort* Bs1 = smem + 8192;
  ushort* Bs3 = smem + 16384;
  const int e = blockIdx.z >> 3;
  const int ks = blockIdx.z & 7;
  const int m0 = seg[e], M = cnt[e];
  const int row0 = blockIdx.y * 128, col0 = blockIdx.x * 128;
  if (row0 >= M) return;
  const int kbase = ks * 256;

  const int tid = threadIdx.x;
  const int lane = tid & 63, wave = tid >> 6;
  const int wm = (wave >> 1) * 64, wn = (wave & 1) * 64;
  const int sub_r = tid >> 2, sub_c = (tid & 3) * 8;

  const ushort* arow[2]; const float* b1row[2]; const float* b3row[2];
#pragma unroll
  for (int p = 0; p < 2; ++p) {
    int rr = row0 + p * 64 + sub_r; if (rr > M - 1) rr = M - 1;
    arow[p] = xb + (long)tok[m0 + rr] * H_DIM + kbase + sub_c;
    int q = col0 + p * 64 + sub_r; if (q > R_RANK - 1) q = R_RANK - 1;
    b1row[p] = dv1 + (long)e * R_RANK * H_DIM + (long)q * H_DIM + kbase + sub_c;
    b3row[p] = dv3 + (long)e * R_RANK * H_DIM + (long)q * H_DIM + kbase + sub_c;
  }

  f32x4 acc1[4][4] = {}, acc3[4][4] = {};

  {
    float4 c1a[2], c1b[2], c3a[2], c3b[2];
#pragma unroll
    for (int p = 0; p < 2; ++p) {
      c1a[p] = *(const float4*)(b1row[p]);
      c1b[p] = *(const float4*)(b1row[p] + 4);
      c3a[p] = *(const float4*)(b3row[p]);
      c3b[p] = *(const float4*)(b3row[p] + 4);
      GLOAD(arow[p], &As[(p * 256 + tid) * 8]);
    }
#pragma unroll
    for (int p = 0; p < 2; ++p) {
      *(short8*)&Bs1[(p * 256 + tid) * 8] = pack8(c1a[p], c1b[p]);
      *(short8*)&Bs3[(p * 256 + tid) * 8] = pack8(c3a[p], c3b[p]);
    }
    __syncthreads();
  }

  const int NT = 8;
  for (int t = 0; t < NT; ++t) {
    const int cur = t & 1, nxt = cur ^ 1;
    const bool more = (t + 1 < NT);
    float4 c1a[2], c1b[2], c3a[2], c3b[2];
    if (more) {
      const int ko = (t + 1) * 32;
#pragma unroll
      for (int p = 0; p < 2; ++p) {
        c1a[p] = *(const float4*)(b1row[p] + ko);
        c1b[p] = *(const float4*)(b1row[p] + ko + 4);
        c3a[p] = *(const float4*)(b3row[p] + ko);
        c3b[p] = *(const float4*)(b3row[p] + ko + 4);
        GLOAD(arow[p] + ko, &As[nxt * 4096 + (p * 256 + tid) * 8]);
      }
    }
    short8 av[4], bv1[4], bv3[4];
#pragma unroll
    for (int mi = 0; mi < 4; ++mi)
      av[mi] = *(const short8*)&As[cur * 4096 + (wm + mi * 16 + (lane & 15)) * 32 + (lane >> 4) * 8];
#pragma unroll
    for (int ni = 0; ni < 4; ++ni) {
      bv1[ni] = *(const short8*)&Bs1[cur * 4096 + (wn + ni * 16 + (lane & 15)) * 32 + (lane >> 4) * 8];
      bv3[ni] = *(const short8*)&Bs3[cur * 4096 + (wn + ni * 16 + (lane & 15)) * 32 + (lane >> 4) * 8];
    }
#pragma unroll
    for (int mi = 0; mi < 4; ++mi)
#pragma unroll
      for (int ni = 0; ni < 4; ++ni) {
        acc1[mi][ni] = __builtin_amdgcn_mfma_f32_16x16x32_bf16(av[mi], bv1[ni], acc1[mi][ni], 0, 0, 0);
        acc3[mi][ni] = __builtin_amdgcn_mfma_f32_16x16x32_bf16(av[mi], bv3[ni], acc3[mi][ni], 0, 0, 0);
      }
    __syncthreads();
    if (more) {
#pragma unroll
      for (int p = 0; p < 2; ++p) {
        *(short8*)&Bs1[nxt * 4096 + (p * 256 + tid) * 8] = pack8(c1a[p], c1b[p]);
        *(short8*)&Bs3[nxt * 4096 + (p * 256 + tid) * 8] = pack8(c3a[p], c3b[p]);
      }
      __syncthreads();
    }
  }

  const int er = (lane >> 4) * 4, ec = lane & 15;
  const long plane = (long)P_PAIRS * RP;
#pragma unroll
  for (int mi = 0; mi < 4; ++mi)
#pragma unroll
    for (int ni = 0; ni < 4; ++ni)
#pragma unroll
      for (int j = 0; j < 4; ++j) {
        int r = row0 + wm + mi * 16 + er + j;
        int c = col0 + wn + ni * 16 + ec;
        if (r < M && c < RP) {
          long o = (long)ks * plane + (long)(m0 + r) * RP + c;
          p1[o] = (c < R_RANK) ? acc1[mi][ni][j] : 0.f;
          p3[o] = (c < R_RANK) ? acc3[mi][ni][j] : 0.f;
        }
      }
}

// down proj split-K4: A=hc bf16, B=Wm2 f32, out f32 partial planes
__global__ __launch_bounds__(256) void gemm_downk(
    const ushort* __restrict__ A, const float* __restrict__ Bf, float* __restrict__ P) {
  __shared__ ushort smem[16384];  // As[2][4096] | Bs[2][4096]
  ushort* As = smem;
  ushort* Bs = smem + 8192;
  const int ks = blockIdx.z;
  const int kbase = ks * (I_DIM / 4);
  const int tid = threadIdx.x;
  const int lane = tid & 63, wave = tid >> 6;
  const int wm = (wave >> 1) * 64, wn = (wave & 1) * 64;
  const int row0 = blockIdx.y * 128, col0 = blockIdx.x * 128;
  const int sub_r = tid >> 2, sub_c = (tid & 3) * 8;

  const ushort* arow[2]; const float* brow[2];
#pragma unroll
  for (int p = 0; p < 2; ++p) {
    arow[p] = A + (long)(row0 + p * 64 + sub_r) * I_DIM + kbase + sub_c;
    brow[p] = Bf + (long)(col0 + p * 64 + sub_r) * I_DIM + kbase + sub_c;
  }

  f32x4 acc[4][4] = {};
  {
    float4 ba[2], bb[2];
#pragma unroll
    for (int p = 0; p < 2; ++p) {
      ba[p] = *(const float4*)(brow[p]);
      bb[p] = *(const float4*)(brow[p] + 4);
      GLOAD(arow[p], &As[(p * 256 + tid) * 8]);
    }
#pragma unroll
    for (int p = 0; p < 2; ++p)
      *(short8*)&Bs[(p * 256 + tid) * 8] = pack8(ba[p], bb[p]);
    __syncthreads();
  }

  const int NT = (I_DIM / 4) / 32;  // 56
  for (int t = 0; t < NT; ++t) {
    const int cur = t & 1, nxt = cur ^ 1;
    const bool more = (t + 1 < NT);
    float4 ba[2], bb[2];
    if (more) {
      const int ko = (t + 1) * 32;
#pragma unroll
      for (int p = 0; p < 2; ++p) {
        ba[p] = *(const float4*)(brow[p] + ko);
        bb[p] = *(const float4*)(brow[p] + ko + 4);
        GLOAD(arow[p] + ko, &As[nxt * 4096 + (p * 256 + tid) * 8]);
      }
    }
    short8 av[4], bv[4];
#pragma unroll
    for (int mi = 0; mi < 4; ++mi)
      av[mi] = *(const short8*)&As[cur * 4096 + (wm + mi * 16 + (lane & 15)) * 32 + (lane >> 4) * 8];
#pragma unroll
    for (int ni = 0; ni < 4; ++ni)
      bv[ni] = *(const short8*)&Bs[cur * 4096 + (wn + ni * 16 + (lane & 15)) * 32 + (lane >> 4) * 8];
#pragma unroll
    for (int mi = 0; mi < 4; ++mi)
#pragma unroll
      for (int ni = 0; ni < 4; ++ni)
        acc[mi][ni] = __builtin_amdgcn_mfma_f32_16x16x32_bf16(av[mi], bv[ni], acc[mi][ni], 0, 0, 0);
    __syncthreads();
    if (more) {
#pragma unroll
      for (int p = 0; p < 2; ++p)
        *(short8*)&Bs[nxt * 4096 + (p * 256 + tid) * 8] = pack8(ba[p], bb[p]);
      __syncthreads();
    }
  }

  const int er = (lane >> 4) * 4, ec = lane & 15;
  float* Pk = P + (long)ks * T_TOK * H_DIM;
#pragma unroll
  for (int mi = 0; mi < 4; ++mi)
#pragma unroll
    for (int ni = 0; ni < 4; ++ni)
#pragma unroll
      for (int j = 0; j < 4; ++j) {
        int r = row0 + wm + mi * 16 + er + j;
        int c = col0 + wn + ni * 16 + ec;
        Pk[(long)r * H_DIM + c] = acc[mi][ni][j];
      }
}

// t2 split-K8 per expert: A=hmidg bf16, B=dv2 f32, f32 partial out (pad col 159->0)
__global__ __launch_bounds__(256) void gemm_t2k(
    const ushort* __restrict__ A, const float* __restrict__ dv2,
    const int* __restrict__ seg, const int* __restrict__ cnt, float* __restrict__ P) {
  __shared__ ushort smem[16384];
  ushort* As = smem;
  ushort* Bs = smem + 8192;
  const int e = blockIdx.z >> 3;
  const int ks = blockIdx.z & 7;
  const int m0 = seg[e], M = cnt[e];
  const int row0 = blockIdx.y * 128, col0 = blockIdx.x * 128;
  if (row0 >= M) return;
  const int kbase = ks * (I_DIM / 8);
  const int tid = threadIdx.x;
  const int lane = tid & 63, wave = tid >> 6;
  const int wm = (wave >> 1) * 64, wn = (wave & 1) * 64;
  const int sub_r = tid >> 2, sub_c = (tid & 3) * 8;

  const ushort* arow[2]; const float* brow[2];
#pragma unroll
  for (int p = 0; p < 2; ++p) {
    int rr = row0 + p * 64 + sub_r; if (rr > M - 1) rr = M - 1;
    arow[p] = A + (long)(m0 + rr) * I_DIM + kbase + sub_c;
    int q = col0 + p * 64 + sub_r; if (q > R_RANK - 1) q = R_RANK - 1;
    brow[p] = dv2 + (long)e * R_RANK * I_DIM + (long)q * I_DIM + kbase + sub_c;
  }

  f32x4 acc[4][4] = {};
  {
    float4 ba[2], bb[2];
#pragma unroll
    for (int p = 0; p < 2; ++p) {
      ba[p] = *(const float4*)(brow[p]);
      bb[p] = *(const float4*)(brow[p] + 4);
      GLOAD(arow[p], &As[(p * 256 + tid) * 8]);
    }
#pragma unroll
    for (int p = 0; p < 2; ++p)
      *(short8*)&Bs[(p * 256 + tid) * 8] = pack8(ba[p], bb[p]);
    __syncthreads();
  }

  const int NT = (I_DIM / 8) / 32;  // 28
  for (int t = 0; t < NT; ++t) {
    const int cur = t & 1, nxt = cur ^ 1;
    const bool more = (t + 1 < NT);
    float4 ba[2], bb[2];
    if (more) {
      const int ko = (t + 1) * 32;
#pragma unroll
      for (int p = 0; p < 2; ++p) {
        ba[p] = *(const float4*)(brow[p] + ko);
        bb[p] = *(const float4*)(brow[p] + ko + 4);
        GLOAD(arow[p] + ko, &As[nxt * 4096 + (p * 256 + tid) * 8]);
      }
    }
    short8 av[4], bv[4];
#pragma unroll
    for (int mi = 0; mi < 4; ++mi)
      av[mi] = *(const short8*)&As[cur * 4096 + (wm + mi * 16 + (lane & 15)) * 32 + (lane >> 4) * 8];
#pragma unroll
    for (int ni = 0; ni < 4; ++ni)
      bv[ni] = *(const short8*)&Bs[cur * 4096 + (wn + ni * 16 + (lane & 15)) * 32 + (lane >> 4) * 8];
#pragma unroll
    for (int mi = 0; mi < 4; ++mi)
#pragma unroll
      for (int ni = 0; ni < 4; ++ni)
        acc[mi][ni] = __builtin_amdgcn_mfma_f32_16x16x32_bf16(av[mi], bv[ni], acc[mi][ni], 0, 0, 0);
    __syncthreads();
    if (more) {
#pragma unroll
      for (int p = 0; p < 2; ++p)
        *(short8*)&Bs[nxt * 4096 + (p * 256 + tid) * 8] = pack8(ba[p], bb[p]);
      __syncthreads();
    }
  }

  const int er = (lane >> 4) * 4, ec = lane & 15;
  const long plane = (long)P_PAIRS * RP;
#pragma unroll
  for (int mi = 0; mi < 4; ++mi)
#pragma unroll
    for (int ni = 0; ni < 4; ++ni)
#pragma unroll
      for (int j = 0; j < 4; ++j) {
        int r = row0 + wm + mi * 16 + er + j;
        int c = col0 + wn + ni * 16 + ec;
        if (r < M && c < RP)
          P[(long)ks * plane + (long)(m0 + r) * RP + c] = (c < R_RANK) ? acc[mi][ni][j] : 0.f;
      }
}

// fused dual hmid: dbuf single-barrier K-loop + merged single-pass epilogue
__global__ __launch_bounds__(256) void gemm_hmid(
    const ushort* __restrict__ t1g, const ushort* __restrict__ t3g,
    const ushort* __restrict__ du1b, const ushort* __restrict__ du3b,
    const ushort* __restrict__ bgate, const ushort* __restrict__ bup,
    const int* __restrict__ tok, const float* __restrict__ wrow,
    const int* __restrict__ seg, const int* __restrict__ cnt,
    ushort* __restrict__ hmid) {
  __shared__ ushort smem[32768];  // 4 arrays x dbuf x 4096 = 64KB ; epilogue: Cs1|Cs2
  ushort* As1 = smem;
  ushort* As3 = smem + 8192;
  ushort* Bs1 = smem + 16384;
  ushort* Bs3 = smem + 24576;
  int e = blockIdx.z;
  int m0 = seg[e], M = cnt[e];
  if ((int)(blockIdx.y * 128) >= M) return;
  const ushort* A1 = t1g + (long)m0 * RP;
  const ushort* A3 = t3g + (long)m0 * RP;
  const ushort* B1 = du1b + (long)e * I_DIM * RP;
  const ushort* B3 = du3b + (long)e * I_DIM * RP;
  tok += m0; wrow += m0;
  ushort* H = hmid + (long)m0 * I_DIM;

  const int tid = threadIdx.x;
  const int lane = tid & 63, wave = tid >> 6;
  const int wm = (wave >> 1) * 64, wn = (wave & 1) * 64;
  const int row0 = blockIdx.y * 128, col0 = blockIdx.x * 128;
  const int sub_r = tid >> 2, sub_c = (tid & 3) * 8;

  const ushort *a1r[2], *a3r[2], *b1r[2], *b3r[2];
#pragma unroll
  for (int p = 0; p < 2; ++p) {
    int r = row0 + p * 64 + sub_r; if (r > M - 1) r = M - 1;
    a1r[p] = A1 + (long)r * RP + sub_c;
    a3r[p] = A3 + (long)r * RP + sub_c;
    int q = col0 + p * 64 + sub_r; if (q > I_DIM - 1) q = I_DIM - 1;
    b1r[p] = B1 + (long)q * RP + sub_c;
    b3r[p] = B3 + (long)q * RP + sub_c;
  }

  f32x4 acc1[4][4] = {}, acc3[4][4] = {};

  // prologue: stage tile 0 into buf 0
#pragma unroll
  for (int p = 0; p < 2; ++p) {
    GLOAD(a1r[p], &As1[(p * 256 + tid) * 8]);
    GLOAD(a3r[p], &As3[(p * 256 + tid) * 8]);
    GLOAD(b1r[p], &Bs1[(p * 256 + tid) * 8]);
    GLOAD(b3r[p], &Bs3[(p * 256 + tid) * 8]);
  }
  __syncthreads();

  const int NT = RP / 32;  // 5
  for (int t = 0; t < NT; ++t) {
    const int cur = t & 1, nxt = cur ^ 1;
    if (t + 1 < NT) {
      const int ko = (t + 1) * 32;
#pragma unroll
      for (int p = 0; p < 2; ++p) {
        GLOAD(a1r[p] + ko, &As1[nxt * 4096 + (p * 256 + tid) * 8]);
        GLOAD(a3r[p] + ko, &As3[nxt * 4096 + (p * 256 + tid) * 8]);
        GLOAD(b1r[p] + ko, &Bs1[nxt * 4096 + (p * 256 + tid) * 8]);
        GLOAD(b3r[p] + ko, &Bs3[nxt * 4096 + (p * 256 + tid) * 8]);
      }
    }
    short8 av1[4], av3[4], bv1[4], bv3[4];
#pragma unroll
    for (int mi = 0; mi < 4; ++mi) {
      av1[mi] = *(const short8*)&As1[cur * 4096 + (wm + mi * 16 + (lane & 15)) * 32 + (lane >> 4) * 8];
      av3[mi] = *(const short8*)&As3[cur * 4096 + (wm + mi * 16 + (lane & 15)) * 32 + (lane >> 4) * 8];
    }
#pragma unroll
    for (int ni = 0; ni < 4; ++ni) {
      bv1[ni] = *(const short8*)&Bs1[cur * 4096 + (wn + ni * 16 + (lane & 15)) * 32 + (lane >> 4) * 8];
      bv3[ni] = *(const short8*)&Bs3[cur * 4096 + (wn + ni * 16 + (lane & 15)) * 32 + (lane >> 4) * 8];
    }
#pragma unroll
    for (int mi = 0; mi < 4; ++mi)
#pragma unroll
      for (int ni = 0; ni < 4; ++ni) {
        acc1[mi][ni] = __builtin_amdgcn_mfma_f32_16x16x32_bf16(av1[mi], bv1[ni], acc1[mi][ni], 0, 0, 0);
        acc3[mi][ni] = __builtin_amdgcn_mfma_f32_16x16x32_bf16(av3[mi], bv3[ni], acc3[mi][ni], 0, 0, 0);
      }
    __syncthreads();  // drains nxt gloads; all done reading cur
  }

  // merged epilogue: both matrices transposed at once (64KB)
  const int er = (lane >> 4) * 4, ec = lane & 15;
  ushort* Cs1 = smem;           // 16384 ushorts
  ushort* Cs2 = smem + 16384;
#pragma unroll
  for (int mi = 0; mi < 4; ++mi)
#pragma unroll
    for (int ni = 0; ni < 4; ++ni)
#pragma unroll
      for (int j = 0; j < 4; ++j) {
        int rr = wm + mi * 16 + er + j;
        int c = wn + ni * 16 + ec;
        int sw = rr * 128 + (c ^ ((rr & 7) << 3));
        Cs1[sw] = f2b(acc1[mi][ni][j]);
        Cs2[sw] = f2b(acc3[mi][ni][j]);
      }
  __syncthreads();
  const int rl = tid >> 1, clb = (tid & 1) * 64;
  const int r = row0 + rl;
  const bool rok = (r < M);
  const int t = rok ? tok[r] : 0;
  const float w = rok ? wrow[r] : 0.f;
  const int k8 = (rl & 7) << 3;
#pragma unroll
  for (int jj = 0; jj < 8; ++jj) {
    int cc = clb + jj * 8;
    short8 gv = *(const short8*)&Cs1[rl * 128 + (cc ^ k8)];
    short8 uv = *(const short8*)&Cs2[rl * 128 + (cc ^ k8)];
    short8 gb = zero8(), ub = zero8();
    if (rok) {
      gb = *(const short8*)&bgate[(long)t * I_DIM + col0 + cc];
      ub = *(const short8*)&bup[(long)t * I_DIM + col0 + cc];
    }
    short8 o;
#pragma unroll
    for (int q = 0; q < 8; ++q) {
      float g = b2f((ushort)gv[q]) + b2f((ushort)gb[q]);
      float u = b2f((ushort)uv[q]) + b2f((ushort)ub[q]);
      float s = g / (1.f + __expf(-g));
      o[q] = (short)f2b(w * s * u);
    }
    if (rok) *(short8*)&H[(long)r * I_DIM + col0 + cc] = o;
  }
}

// ---------------- launch ----------------
extern "C" void kernel_launch(void* const* d_in, const int* in_sizes, int n_in,
                              void* d_out, int out_size, void* d_ws, size_t ws_size,
                              hipStream_t stream) {
  const float* x   = (const float*)d_in[0];
  const float* gw  = (const float*)d_in[1];
  const float* Wm1 = (const float*)d_in[2];
  const float* Wm2 = (const float*)d_in[3];
  const float* Wm3 = (const float*)d_in[4];
  const float* du1 = (const float*)d_in[5];
  const float* dv1 = (const float*)d_in[6];
  const float* du2 = (const float*)d_in[7];
  const float* dv2 = (const float*)d_in[8];
  const float* du3 = (const float*)d_in[9];
  const float* dv3 = (const float*)d_in[10];

  float* out_final  = (float*)d_out;
  float* out_logits = out_final + (long)T_TOK * H_DIM;

  char* p = (char*)d_ws;
  auto alloc = [&](size_t bytes) {
    char* r = p;
    p += (bytes + 255) & ~(size_t)255;
    return r;
  };

  float* comb   = (float*)alloc((size_t)T_TOK * E_NUM * 4);
  float* wrow   = (float*)alloc((size_t)P_PAIRS * 4);
  int* cnt      = (int*)alloc(64);
  int* cursor   = (int*)alloc(64);
  int* seg      = (int*)alloc(64);
  int* sel_e    = (int*)alloc((size_t)T_TOK * 2 * 4);
  int* tok      = (int*)alloc((size_t)P_PAIRS * 4);
  int* row_of   = (int*)alloc((size_t)T_TOK * 2 * 4);
  ushort* bgate_b = (ushort*)alloc((size_t)T_TOK * I_DIM * 2);   // later: hc, then p2
  ushort* bup_b   = (ushort*)alloc((size_t)T_TOK * I_DIM * 2);   // later: deltab
  ushort* hmidg   = (ushort*)alloc((size_t)P_PAIRS * I_DIM * 2); // earlier: p1|p3
  ushort* t1g     = (ushort*)alloc((size_t)P_PAIRS * RP * 2);
  ushort* t3g     = (ushort*)alloc((size_t)P_PAIRS * RP * 2);
  ushort* t2g     = (ushort*)alloc((size_t)P_PAIRS * RP * 2);
  ushort* du1b    = (ushort*)alloc((size_t)E_NUM * I_DIM * RP * 2);  // later: dp (w/ du3b)
  ushort* du3b    = (ushort*)alloc((size_t)E_NUM * I_DIM * RP * 2);
  ushort* du2b    = (ushort*)alloc((size_t)E_NUM * H_DIM * RP * 2);
  size_t needed_B = (size_t)(p - (char*)d_ws);
  ushort* xb   = (ushort*)alloc((size_t)T_TOK * H_DIM * 2);
  size_t needed_A = (size_t)(p - (char*)d_ws);

  ushort* hc     = bgate_b;
  ushort* deltab = bup_b;

  if (ws_size < needed_B) return;
  const bool planA = (ws_size >= needed_A);

  dim3 blk(256);

  init_kernel<<<1, 64, 0, stream>>>(cnt, cursor);
  router_kernel<<<T_TOK / 4, 256, 0, stream>>>(x, gw, out_logits, comb, sel_e, cnt);
  scan_kernel<<<1, 64, 0, stream>>>(cnt, seg);
  assign_kernel<<<4, 256, 0, stream>>>(sel_e, comb, seg, cursor, tok, wrow, row_of);

  padcast8_kernel<<<4480, 256, 0, stream>>>(du1, du1b, (long)E_NUM * I_DIM);
  padcast8_kernel<<<4480, 256, 0, stream>>>(du3, du3b, (long)E_NUM * I_DIM);
  padcast8_kernel<<<1280, 256, 0, stream>>>(du2, du2b, (long)E_NUM * H_DIM);

  if (planA) {
    cast8_kernel<<<1024, 256, 0, stream>>>(x, xb, (long)T_TOK * H_DIM / 8);

    // fused base gate/up (Wm1/Wm3 f32 cast-in-staging)
    gemm_base<<<dim3(I_DIM / 128, T_TOK / 128), blk, 0, stream>>>(xb, Wm1, Wm3, bgate_b, bup_b);

    // t1/t3 fused dual-B split-K8 (dv f32), partials in hmidg region
    float* p1 = (float*)hmidg;
    float* p3 = p1 + (long)8 * P_PAIRS * RP;
    gemm_t13f<<<dim3(2, 16, 64), blk, 0, stream>>>(xb, dv1, dv3, tok, seg, cnt, p1, p3);
    reduce2_kernel<<<2560, 256, 0, stream>>>(p1, p3, t1g, t3g, (long)P_PAIRS * RP);

    // hmid (overwrites partial region)
    gemm_hmid<<<dim3(I_DIM / 128, 16, E_NUM), blk, 0, stream>>>(
        t1g, t3g, du1b, du3b, bgate_b, bup_b, tok, wrow, seg, cnt, hmidg);

    hcomb_kernel<<<(int)(((long)T_TOK * I_DIM / 8 + 255) / 256), 256, 0, stream>>>(hmidg, row_of, hc);

    // down proj split-K4 (Wm2 f32), partials in du1b/du3b region
    float* dp = (float*)du1b;
    gemm_downk<<<dim3(H_DIM / 128, T_TOK / 128, 4), blk, 0, stream>>>(hc, Wm2, dp);

    // t2 split-K8 (dv2 f32), partials in bgate/hc region (dead after down)
    float* p2 = (float*)bgate_b;
    gemm_t2k<<<dim3(2, 16, 64), blk, 0, stream>>>(hmidg, dv2, seg, cnt, p2);
    reduce_cast_kernel<8><<<1280, 256, 0, stream>>>(p2, (long)P_PAIRS * RP, t2g, (long)P_PAIRS * RP);

    // delta = t2g @ du2^T (bf16, K=160)
    gemm_f<0, 0, 1, 1, 0><<<dim3(H_DIM / 128, 16, E_NUM), blk, 0, stream>>>(
        t2g, RP, du2b, RP, (long)H_DIM * RP, 0, H_DIM, RP, H_DIM,
        nullptr, deltab, H_DIM, tok, seg, cnt);

    finalfixA_kernel<<<2048, 256, 0, stream>>>(out_final, dp, deltab, row_of);
  } else {
    // plan B fallback (old unpipelined path, f32 direct)
    gemm_f<1, 1, 1, 0, 0><<<dim3(I_DIM / 128, T_TOK / 128, 1), blk, 0, stream>>>(
        x, H_DIM, Wm1, H_DIM, 0L, T_TOK, I_DIM, H_DIM, I_DIM,
        nullptr, bgate_b, I_DIM, nullptr, nullptr, nullptr);
    gemm_f<1, 1, 1, 0, 0><<<dim3(I_DIM / 128, T_TOK / 128, 1), blk, 0, stream>>>(
        x, H_DIM, Wm3, H_DIM, 0L, T_TOK, I_DIM, H_DIM, I_DIM,
        nullptr, bup_b, I_DIM, nullptr, nullptr, nullptr);
    gemm_f<1, 1, 1, 1, 1><<<dim3(2, 16, E_NUM), blk, 0, stream>>>(
        x, H_DIM, dv1, H_DIM, (long)R_RANK * H_DIM, 0, R_RANK, H_DIM, RP,
        nullptr, t1g, RP, tok, seg, cnt);
    gemm_f<1, 1, 1, 1, 1><<<dim3(2, 16, E_NUM), blk, 0, stream>>>(
        x, H_DIM, dv3, H_DIM, (long)R_RANK * H_DIM, 0, R_RANK, H_DIM, RP,
        nullptr, t3g, RP, tok, seg, cnt);
    gemm_hmid<<<dim3(I_DIM / 128, 16, E_NUM), blk, 0, stream>>>(
        t1g, t3g, du1b, du3b, bgate_b, bup_b, tok, wrow, seg, cnt, hmidg);
    hcomb_kernel<<<(int)(((long)T_TOK * I_DIM / 8 + 255) / 256), 256, 0, stream>>>(hmidg, row_of, hc);
    gemm_f<0, 1, 0, 0, 0><<<dim3(H_DIM / 128, T_TOK / 128, 1), blk, 0, stream>>>(
        hc, I_DIM, Wm2, I_DIM, 0L, T_TOK, H_DIM, I_DIM, H_DIM,
        out_final, nullptr, H_DIM, nullptr, nullptr, nullptr);
    gemm_f<0, 1, 1, 1, 0><<<dim3(2, 16, E_NUM), blk, 0, stream>>>(
        hmidg, I_DIM, dv2, I_DIM, (long)R_RANK * I_DIM, 0, R_RANK, I_DIM, RP,
        nullptr, t2g, RP, tok, seg, cnt);
    gemm_f<0, 0, 1, 1, 0><<<dim3(H_DIM / 128, 16, E_NUM), blk, 0, stream>>>(
        t2g, RP, du2b, RP, (long)H_DIM * RP, 0, H_DIM, RP, H_DIM,
        nullptr, deltab, H_DIM, tok, seg, cnt);
    finalfix_kernel<<<(int)(((long)T_TOK * H_DIM / 4 + 255) / 256), 256, 0, stream>>>(
        out_final, deltab, row_of);
  }
}

// Round 6
// 530.892 us; speedup vs baseline: 1.4010x; 1.4010x over previous
//
#include <hip/hip_runtime.h>

#define T_TOK 1024
#define H_DIM 2048
#define I_DIM 7168
#define E_NUM 8
#define R_RANK 159
#define RP 160
#define P_PAIRS 2048

typedef __attribute__((ext_vector_type(8))) short short8;
typedef __attribute__((ext_vector_type(4))) float f32x4;

__device__ __forceinline__ ushort f2b(float f) {
  uint u = __float_as_uint(f);
  uint r = (u + 0x7FFFu + ((u >> 16) & 1u)) >> 16;
  return (ushort)r;
}
__device__ __forceinline__ float b2f(ushort u) {
  return __uint_as_float(((uint)u) << 16);
}
__device__ __forceinline__ short8 pack8(float4 a, float4 b) {
  short8 o;
  o[0] = (short)f2b(a.x); o[1] = (short)f2b(a.y); o[2] = (short)f2b(a.z); o[3] = (short)f2b(a.w);
  o[4] = (short)f2b(b.x); o[5] = (short)f2b(b.y); o[6] = (short)f2b(b.z); o[7] = (short)f2b(b.w);
  return o;
}
__device__ __forceinline__ short8 zero8() {
  short8 z;
#pragma unroll
  for (int q = 0; q < 8; ++q) z[q] = 0;
  return z;
}

#define GLOAD(gptr, lptr) \
  __builtin_amdgcn_global_load_lds((const __attribute__((address_space(1))) void*)(gptr), \
                                   (__attribute__((address_space(3))) void*)(lptr), 16, 0, 0)

// ---------------- router ----------------
__global__ __launch_bounds__(256) void router_kernel(
    const float* __restrict__ x, const float* __restrict__ gw,
    float* __restrict__ logits, float* __restrict__ comb,
    int* __restrict__ sel_e, int* __restrict__ cnt) {
  int wave = threadIdx.x >> 6, lane = threadIdx.x & 63;
  int t = blockIdx.x * 4 + wave;
  const float* xr = x + (long)t * H_DIM;
  float acc[8] = {0.f,0.f,0.f,0.f,0.f,0.f,0.f,0.f};
  for (int h = lane * 4; h < H_DIM; h += 256) {
    const float4 xv = *(const float4*)&xr[h];
#pragma unroll
    for (int e = 0; e < 8; ++e) {
      const float4 gv = *(const float4*)&gw[e * H_DIM + h];
      acc[e] += xv.x * gv.x + xv.y * gv.y + xv.z * gv.z + xv.w * gv.w;
    }
  }
#pragma unroll
  for (int off = 32; off > 0; off >>= 1)
#pragma unroll
    for (int e = 0; e < 8; ++e) acc[e] += __shfl_down(acc[e], off);
  if (lane == 0) {
#pragma unroll
    for (int e = 0; e < 8; ++e) logits[(long)t * 8 + e] = acc[e];
    int i0 = 0;
    for (int e = 1; e < 8; ++e) if (acc[e] > acc[i0]) i0 = e;
    int i1 = (i0 == 0) ? 1 : 0;
    for (int e = 0; e < 8; ++e) if (e != i0 && acc[e] > acc[i1]) i1 = e;
    float ee = __expf(acc[i1] - acc[i0]);
    float w0 = 1.f / (1.f + ee), w1 = ee / (1.f + ee);
    for (int e = 0; e < 8; ++e) comb[t * 8 + e] = 0.f;
    comb[t * 8 + i0] = w0;
    comb[t * 8 + i1] = w1;
    sel_e[t * 2] = i0;
    sel_e[t * 2 + 1] = i1;
    atomicAdd(&cnt[i0], 1);
    atomicAdd(&cnt[i1], 1);
  }
}

__global__ void init_kernel(int* cnt, int* cursor) {
  int i = threadIdx.x;
  if (i < 8) { cnt[i] = 0; cursor[i] = 0; }
}

__global__ void scan_kernel(const int* cnt, int* seg) {
  if (threadIdx.x == 0) {
    int s = 0;
    for (int e = 0; e < 8; ++e) { seg[e] = s; s += cnt[e]; }
    seg[8] = s;
  }
}

__global__ void assign_kernel(const int* __restrict__ sel_e, const float* __restrict__ comb,
                              const int* __restrict__ seg, int* __restrict__ cursor,
                              int* __restrict__ tok, float* __restrict__ wrow,
                              int* __restrict__ row_of) {
  int t = blockIdx.x * blockDim.x + threadIdx.x;
  if (t >= T_TOK) return;
  for (int k = 0; k < 2; ++k) {
    int e = sel_e[t * 2 + k];
    int pos = atomicAdd(&cursor[e], 1);
    int row = seg[e] + pos;
    tok[row] = t;
    wrow[row] = comb[t * 8 + e];
    row_of[t * 2 + k] = row;
  }
}

// ---------------- casts ----------------
__global__ void cast8_kernel(const float* __restrict__ src, ushort* __restrict__ dst, long n8) {
  long idx = (long)blockIdx.x * blockDim.x + threadIdx.x;
  long stride = (long)gridDim.x * blockDim.x;
  for (long i = idx; i < n8; i += stride) {
    const float4 a = *(const float4*)&src[i * 8];
    const float4 b = *(const float4*)&src[i * 8 + 4];
    *(short8*)&dst[i * 8] = pack8(a, b);
  }
}

__global__ void padcast8_kernel(const float* __restrict__ src, ushort* __restrict__ dst, long rows) {
  long n8 = rows * (RP / 8);
  long idx = (long)blockIdx.x * blockDim.x + threadIdx.x;
  long stride = (long)gridDim.x * blockDim.x;
  for (long i = idx; i < n8; i += stride) {
    long row = i / (RP / 8);
    int c0 = (int)(i % (RP / 8)) * 8;
    short8 o;
#pragma unroll
    for (int j = 0; j < 8; ++j) {
      int c = c0 + j;
      o[j] = (c < R_RANK) ? (short)f2b(src[row * R_RANK + c]) : (short)0;
    }
    *(short8*)&dst[row * RP + c0] = o;
  }
}

// hc[t,i] = hmid[row0,i] + hmid[row1,i]
__global__ void hcomb_kernel(const ushort* __restrict__ hmid, const int* __restrict__ row_of,
                             ushort* __restrict__ hc) {
  long idx = (long)blockIdx.x * blockDim.x + threadIdx.x;
  long total = (long)T_TOK * I_DIM / 8;
  if (idx >= total) return;
  long i = idx * 8;
  int t = (int)(i / I_DIM);
  int col = (int)(i % I_DIM);
  int r0 = row_of[t * 2], r1 = row_of[t * 2 + 1];
  const short8 a = *(const short8*)&hmid[(long)r0 * I_DIM + col];
  const short8 b = *(const short8*)&hmid[(long)r1 * I_DIM + col];
  short8 o;
#pragma unroll
  for (int j = 0; j < 8; ++j)
    o[j] = (short)f2b(b2f((ushort)a[j]) + b2f((ushort)b[j]));
  *(short8*)&hc[i] = o;
}

// plan B epilogue
__global__ void finalfix_kernel(float* __restrict__ out, const ushort* __restrict__ delta,
                                const int* __restrict__ row_of) {
  long idx = (long)blockIdx.x * blockDim.x + threadIdx.x;
  long total = (long)T_TOK * H_DIM / 4;
  if (idx >= total) return;
  long i = idx * 4;
  int t = (int)(i / H_DIM);
  int col = (int)(i % H_DIM);
  int r0 = row_of[t * 2], r1 = row_of[t * 2 + 1];
  float4 d = *(float4*)&out[i];
  d.x += b2f(delta[(long)r0 * H_DIM + col + 0]) + b2f(delta[(long)r1 * H_DIM + col + 0]);
  d.y += b2f(delta[(long)r0 * H_DIM + col + 1]) + b2f(delta[(long)r1 * H_DIM + col + 1]);
  d.z += b2f(delta[(long)r0 * H_DIM + col + 2]) + b2f(delta[(long)r1 * H_DIM + col + 2]);
  d.w += b2f(delta[(long)r0 * H_DIM + col + 3]) + b2f(delta[(long)r1 * H_DIM + col + 3]);
  *(float4*)&out[i] = d;
}

// plan A epilogue
__global__ void finalfixA_kernel(float* __restrict__ out, const float* __restrict__ dp,
                                 const ushort* __restrict__ delta, const int* __restrict__ row_of) {
  long idx = (long)blockIdx.x * blockDim.x + threadIdx.x;
  long total = (long)T_TOK * H_DIM / 4;
  if (idx >= total) return;
  long i = idx * 4;
  int t = (int)(i / H_DIM);
  int col = (int)(i % H_DIM);
  int r0 = row_of[t * 2], r1 = row_of[t * 2 + 1];
  const long plane = (long)T_TOK * H_DIM;
  float4 s = *(const float4*)&dp[i];
#pragma unroll
  for (int k = 1; k < 4; ++k) {
    const float4 q = *(const float4*)&dp[k * plane + i];
    s.x += q.x; s.y += q.y; s.z += q.z; s.w += q.w;
  }
  s.x += b2f(delta[(long)r0 * H_DIM + col + 0]) + b2f(delta[(long)r1 * H_DIM + col + 0]);
  s.y += b2f(delta[(long)r0 * H_DIM + col + 1]) + b2f(delta[(long)r1 * H_DIM + col + 1]);
  s.z += b2f(delta[(long)r0 * H_DIM + col + 2]) + b2f(delta[(long)r1 * H_DIM + col + 2]);
  s.w += b2f(delta[(long)r0 * H_DIM + col + 3]) + b2f(delta[(long)r1 * H_DIM + col + 3]);
  *(float4*)&out[i] = s;
}

template <int KS>
__global__ void reduce_cast_kernel(const float* __restrict__ P, long plane,
                                   ushort* __restrict__ out, long n) {
  long i = (long)blockIdx.x * blockDim.x + threadIdx.x;
  if (i >= n) return;
  float s = 0.f;
#pragma unroll
  for (int k = 0; k < KS; ++k) s += P[(long)k * plane + i];
  out[i] = f2b(s);
}

__global__ void reduce2_kernel(const float* __restrict__ p1, const float* __restrict__ p3,
                               ushort* __restrict__ t1g, ushort* __restrict__ t3g, long n) {
  long i = (long)blockIdx.x * blockDim.x + threadIdx.x;
  if (i >= 2 * n) return;
  const float* P = (i < n) ? p1 : p3;
  ushort* o = (i < n) ? t1g : t3g;
  long ii = (i < n) ? i : i - n;
  float s = 0.f;
#pragma unroll
  for (int k = 0; k < 8; ++k) s += P[(long)k * n + ii];
  o[ii] = f2b(s);
}

// ================= shared GEMM pieces (round-4 proven bodies) =================

// K-loop: pure global_load_lds bf16, 2 barriers per K-step (m97 family)
__device__ __forceinline__ void kloop_bf16(
    const ushort* ar0, const ushort* ar1,
    const ushort* br0, const ushort* br1,
    int K, ushort* As, ushort* Bs,
    int tid, int lane, int wm, int wn, f32x4 acc[4][4]) {
  for (int k0 = 0; k0 < K; k0 += 32) {
    __syncthreads();
    GLOAD(ar0 + k0, &As[tid * 8]);
    GLOAD(ar1 + k0, &As[(256 + tid) * 8]);
    GLOAD(br0 + k0, &Bs[tid * 8]);
    GLOAD(br1 + k0, &Bs[(256 + tid) * 8]);
    __syncthreads();
    short8 av[4], bv[4];
#pragma unroll
    for (int mi = 0; mi < 4; ++mi)
      av[mi] = *(const short8*)&As[(wm + mi * 16 + (lane & 15)) * 32 + (lane >> 4) * 8];
#pragma unroll
    for (int ni = 0; ni < 4; ++ni)
      bv[ni] = *(const short8*)&Bs[(wn + ni * 16 + (lane & 15)) * 32 + (lane >> 4) * 8];
#pragma unroll
    for (int mi = 0; mi < 4; ++mi)
#pragma unroll
      for (int ni = 0; ni < 4; ++ni)
        acc[mi][ni] = __builtin_amdgcn_mfma_f32_16x16x32_bf16(av[mi], bv[ni], acc[mi][ni], 0, 0, 0);
  }
}

// bf16 epilogue: LDS-transpose (32KB alias), coalesced short8 stores
__device__ __forceinline__ void epi_bf16(
    f32x4 acc[4][4], ushort* smem, int tid, int lane, int wm, int wn,
    int row0, int col0, int M, int Nvalid, int Npad, ushort* Cb, int ldc) {
  const int er = (lane >> 4) * 4, ec = lane & 15;
  __syncthreads();
#pragma unroll
  for (int mi = 0; mi < 4; ++mi)
#pragma unroll
    for (int ni = 0; ni < 4; ++ni)
#pragma unroll
      for (int j = 0; j < 4; ++j) {
        int rr = wm + mi * 16 + er + j;
        int c = wn + ni * 16 + ec;
        smem[rr * 128 + (c ^ ((rr & 7) << 3))] =
            (col0 + c < Nvalid) ? f2b(acc[mi][ni][j]) : (ushort)0;
      }
  __syncthreads();
  const int rl = tid >> 1, clb = (tid & 1) * 64;
  const int r = row0 + rl;
  if (r < M) {
    const int k8 = (rl & 7) << 3;
#pragma unroll
    for (int jj = 0; jj < 8; ++jj) {
      int cg = col0 + clb + jj * 8;
      if (cg < Npad) {
        short8 v = *(const short8*)&smem[rl * 128 + ((clb + jj * 8) ^ k8)];
        *(short8*)&Cb[(long)r * ldc + cg] = v;
      }
    }
  }
}

// ================= merged launches =================

// base: z=0 -> bgate = xb@Wm1b^T ; z=1 -> bup = xb@Wm3b^T   (896 blocks)
__global__ __launch_bounds__(256) void k_base(
    const ushort* __restrict__ xb, const ushort* __restrict__ w1b, const ushort* __restrict__ w3b,
    ushort* __restrict__ bgate, ushort* __restrict__ bup) {
  __shared__ ushort smem[16384];
  ushort* As = smem;
  ushort* Bs = smem + 4096;
  const ushort* B = blockIdx.z ? w3b : w1b;
  ushort* C = blockIdx.z ? bup : bgate;
  const int tid = threadIdx.x;
  const int lane = tid & 63, wave = tid >> 6;
  const int wm = (wave >> 1) * 64, wn = (wave & 1) * 64;
  const int row0 = blockIdx.y * 128, col0 = blockIdx.x * 128;
  const int sub_r = tid >> 2, sub_c = (tid & 3) * 8;
  const ushort* ar0 = xb + (long)(row0 + sub_r) * H_DIM + sub_c;
  const ushort* ar1 = xb + (long)(row0 + 64 + sub_r) * H_DIM + sub_c;
  const ushort* br0 = B + (long)(col0 + sub_r) * H_DIM + sub_c;
  const ushort* br1 = B + (long)(col0 + 64 + sub_r) * H_DIM + sub_c;
  f32x4 acc[4][4] = {};
  kloop_bf16(ar0, ar1, br0, br1, H_DIM, As, Bs, tid, lane, wm, wn, acc);
  epi_bf16(acc, smem, tid, lane, wm, wn, row0, col0, T_TOK, I_DIM, I_DIM, C, I_DIM);
}

// t1/t3: z&1 picks (dv1b->p1 | dv3b->p3); z>>1 = e*8+ks ; split-K8   (2048 blocks)
__global__ __launch_bounds__(256) void k_t13(
    const ushort* __restrict__ xb, const ushort* __restrict__ dv1b, const ushort* __restrict__ dv3b,
    const int* __restrict__ tok, const int* __restrict__ seg, const int* __restrict__ cnt,
    float* __restrict__ p1, float* __restrict__ p3) {
  __shared__ ushort smem[8192];
  ushort* As = smem;
  ushort* Bs = smem + 4096;
  const int z = blockIdx.z;
  const int which = z & 1;
  const int eks = z >> 1;
  const int e = eks >> 3, ks = eks & 7;
  const int m0 = seg[e], M = cnt[e];
  const int row0 = blockIdx.y * 128, col0 = blockIdx.x * 128;
  if (row0 >= M) return;
  const int kbase = ks * 256;
  const ushort* Bsrc = (which ? dv3b : dv1b) + (long)e * R_RANK * H_DIM;
  float* P = which ? p3 : p1;
  const int tid = threadIdx.x;
  const int lane = tid & 63, wave = tid >> 6;
  const int wm = (wave >> 1) * 64, wn = (wave & 1) * 64;
  const int sub_r = tid >> 2, sub_c = (tid & 3) * 8;
  int r0c = row0 + sub_r;      if (r0c > M - 1) r0c = M - 1;
  int r1c = row0 + 64 + sub_r; if (r1c > M - 1) r1c = M - 1;
  const ushort* ar0 = xb + (long)tok[m0 + r0c] * H_DIM + kbase + sub_c;
  const ushort* ar1 = xb + (long)tok[m0 + r1c] * H_DIM + kbase + sub_c;
  int q0 = col0 + sub_r;      if (q0 > R_RANK - 1) q0 = R_RANK - 1;
  int q1 = col0 + 64 + sub_r; if (q1 > R_RANK - 1) q1 = R_RANK - 1;
  const ushort* br0 = Bsrc + (long)q0 * H_DIM + kbase + sub_c;
  const ushort* br1 = Bsrc + (long)q1 * H_DIM + kbase + sub_c;
  f32x4 acc[4][4] = {};
  kloop_bf16(ar0, ar1, br0, br1, 256, As, Bs, tid, lane, wm, wn, acc);
  const int er = (lane >> 4) * 4, ec = lane & 15;
  const long plane = (long)P_PAIRS * RP;
#pragma unroll
  for (int mi = 0; mi < 4; ++mi)
#pragma unroll
    for (int ni = 0; ni < 4; ++ni)
#pragma unroll
      for (int j = 0; j < 4; ++j) {
        int r = row0 + wm + mi * 16 + er + j;
        int c = col0 + wn + ni * 16 + ec;
        if (r < M && c < RP)
          P[(long)ks * plane + (long)(m0 + r) * RP + c] = (c < R_RANK) ? acc[mi][ni][j] : 0.f;
      }
}

// phase2: z<4 -> down split-K4 (hc@w2b^T -> dp planes); z>=4 -> t2 split-K8/expert
__global__ __launch_bounds__(256) void k_phase2(
    const ushort* __restrict__ hc, const ushort* __restrict__ w2b,
    const ushort* __restrict__ hmidg, const ushort* __restrict__ dv2b,
    const int* __restrict__ seg, const int* __restrict__ cnt,
    float* __restrict__ dp, float* __restrict__ p2) {
  __shared__ ushort smem[8192];
  ushort* As = smem;
  ushort* Bs = smem + 4096;
  const int tid = threadIdx.x;
  const int lane = tid & 63, wave = tid >> 6;
  const int wm = (wave >> 1) * 64, wn = (wave & 1) * 64;
  const int sub_r = tid >> 2, sub_c = (tid & 3) * 8;
  const int er = (lane >> 4) * 4, ec = lane & 15;

  if (blockIdx.z < 4) {
    const int ks = blockIdx.z;
    const int kbase = ks * (I_DIM / 4);
    const int row0 = blockIdx.y * 128, col0 = blockIdx.x * 128;
    const ushort* ar0 = hc + (long)(row0 + sub_r) * I_DIM + kbase + sub_c;
    const ushort* ar1 = hc + (long)(row0 + 64 + sub_r) * I_DIM + kbase + sub_c;
    const ushort* br0 = w2b + (long)(col0 + sub_r) * I_DIM + kbase + sub_c;
    const ushort* br1 = w2b + (long)(col0 + 64 + sub_r) * I_DIM + kbase + sub_c;
    f32x4 acc[4][4] = {};
    kloop_bf16(ar0, ar1, br0, br1, I_DIM / 4, As, Bs, tid, lane, wm, wn, acc);
    float* Pk = dp + (long)ks * T_TOK * H_DIM;
#pragma unroll
    for (int mi = 0; mi < 4; ++mi)
#pragma unroll
      for (int ni = 0; ni < 4; ++ni)
#pragma unroll
        for (int j = 0; j < 4; ++j) {
          int r = row0 + wm + mi * 16 + er + j;
          int c = col0 + wn + ni * 16 + ec;
          Pk[(long)r * H_DIM + c] = acc[mi][ni][j];
        }
  } else {
    const int f = (blockIdx.z - 4) * 128 + blockIdx.y * 16 + blockIdx.x;  // 0..1023
    const int eks = f >> 4;
    const int e = eks >> 3, ks = eks & 7;
    const int rsub = f & 15;
    const int x2 = rsub & 1, y2 = rsub >> 1;
    const int m0 = seg[e], M = cnt[e];
    const int row0 = y2 * 128, col0 = x2 * 128;
    if (row0 >= M) return;
    const int kbase = ks * (I_DIM / 8);
    int r0c = row0 + sub_r;      if (r0c > M - 1) r0c = M - 1;
    int r1c = row0 + 64 + sub_r; if (r1c > M - 1) r1c = M - 1;
    const ushort* ar0 = hmidg + (long)(m0 + r0c) * I_DIM + kbase + sub_c;
    const ushort* ar1 = hmidg + (long)(m0 + r1c) * I_DIM + kbase + sub_c;
    int q0 = col0 + sub_r;      if (q0 > R_RANK - 1) q0 = R_RANK - 1;
    int q1 = col0 + 64 + sub_r; if (q1 > R_RANK - 1) q1 = R_RANK - 1;
    const ushort* br0 = dv2b + (long)e * R_RANK * I_DIM + (long)q0 * I_DIM + kbase + sub_c;
    const ushort* br1 = dv2b + (long)e * R_RANK * I_DIM + (long)q1 * I_DIM + kbase + sub_c;
    f32x4 acc[4][4] = {};
    kloop_bf16(ar0, ar1, br0, br1, I_DIM / 8, As, Bs, tid, lane, wm, wn, acc);
    const long plane = (long)P_PAIRS * RP;
#pragma unroll
    for (int mi = 0; mi < 4; ++mi)
#pragma unroll
      for (int ni = 0; ni < 4; ++ni)
#pragma unroll
        for (int j = 0; j < 4; ++j) {
          int r = row0 + wm + mi * 16 + er + j;
          int c = col0 + wn + ni * 16 + ec;
          if (r < M && c < RP)
            p2[(long)ks * plane + (long)(m0 + r) * RP + c] = (c < R_RANK) ? acc[mi][ni][j] : 0.f;
        }
  }
}

// delta: per-expert deltab = t2g @ du2b^T (K=160), bf16 out   (1024 blocks)
__global__ __launch_bounds__(256) void k_delta(
    const ushort* __restrict__ t2g, const ushort* __restrict__ du2b,
    const int* __restrict__ seg, const int* __restrict__ cnt,
    ushort* __restrict__ deltab) {
  __shared__ ushort smem[16384];
  ushort* As = smem;
  ushort* Bs = smem + 4096;
  const int e = blockIdx.z;
  const int m0 = seg[e], M = cnt[e];
  const int row0 = blockIdx.y * 128, col0 = blockIdx.x * 128;
  if (row0 >= M) return;
  const int tid = threadIdx.x;
  const int lane = tid & 63, wave = tid >> 6;
  const int wm = (wave >> 1) * 64, wn = (wave & 1) * 64;
  const int sub_r = tid >> 2, sub_c = (tid & 3) * 8;
  int r0c = row0 + sub_r;      if (r0c > M - 1) r0c = M - 1;
  int r1c = row0 + 64 + sub_r; if (r1c > M - 1) r1c = M - 1;
  const ushort* ar0 = t2g + (long)(m0 + r0c) * RP + sub_c;
  const ushort* ar1 = t2g + (long)(m0 + r1c) * RP + sub_c;
  const ushort* br0 = du2b + (long)e * H_DIM * RP + (long)(col0 + sub_r) * RP + sub_c;
  const ushort* br1 = du2b + (long)e * H_DIM * RP + (long)(col0 + 64 + sub_r) * RP + sub_c;
  f32x4 acc[4][4] = {};
  kloop_bf16(ar0, ar1, br0, br1, RP, As, Bs, tid, lane, wm, wn, acc);
  epi_bf16(acc, smem, tid, lane, wm, wn, row0, col0, M, H_DIM, H_DIM,
           deltab + (long)m0 * H_DIM, H_DIM);
}

// ---------------- fused dual hmid (round-4 verbatim: 88 us known) ----------------
__global__ __launch_bounds__(256) void gemm_hmid(
    const ushort* __restrict__ t1g, const ushort* __restrict__ t3g,
    const ushort* __restrict__ du1b, const ushort* __restrict__ du3b,
    const ushort* __restrict__ bgate, const ushort* __restrict__ bup,
    const int* __restrict__ tok, const float* __restrict__ wrow,
    const int* __restrict__ seg, const int* __restrict__ cnt,
    ushort* __restrict__ hmid) {
  __shared__ ushort smem[16384];
  ushort* As1 = smem;
  ushort* As3 = smem + 4096;
  ushort* Bs1 = smem + 8192;
  ushort* Bs3 = smem + 12288;
  int e = blockIdx.z;
  int m0 = seg[e], M = cnt[e];
  if ((int)(blockIdx.y * 128) >= M) return;
  const ushort* A1 = t1g + (long)m0 * RP;
  const ushort* A3 = t3g + (long)m0 * RP;
  const ushort* B1 = du1b + (long)e * I_DIM * RP;
  const ushort* B3 = du3b + (long)e * I_DIM * RP;
  tok += m0; wrow += m0;
  ushort* H = hmid + (long)m0 * I_DIM;

  const int tid = threadIdx.x;
  const int lane = tid & 63, wave = tid >> 6;
  const int wm = (wave >> 1) * 64, wn = (wave & 1) * 64;
  const int row0 = blockIdx.y * 128, col0 = blockIdx.x * 128;
  const int sub_r = tid >> 2;
  const int sub_c = (tid & 3) * 8;

  const ushort *a1r[2], *a3r[2], *b1r[2], *b3r[2];
#pragma unroll
  for (int p = 0; p < 2; ++p) {
    int r = row0 + p * 64 + sub_r; if (r > M - 1) r = M - 1;
    a1r[p] = A1 + (long)r * RP + sub_c;
    a3r[p] = A3 + (long)r * RP + sub_c;
    int q = col0 + p * 64 + sub_r; if (q > I_DIM - 1) q = I_DIM - 1;
    b1r[p] = B1 + (long)q * RP + sub_c;
    b3r[p] = B3 + (long)q * RP + sub_c;
  }

  f32x4 acc1[4][4] = {}, acc3[4][4] = {};

  for (int k0 = 0; k0 < RP; k0 += 32) {
    __syncthreads();
#pragma unroll
    for (int p = 0; p < 2; ++p) {
      GLOAD(a1r[p] + k0, &As1[(p * 256 + tid) * 8]);
      GLOAD(a3r[p] + k0, &As3[(p * 256 + tid) * 8]);
      GLOAD(b1r[p] + k0, &Bs1[(p * 256 + tid) * 8]);
      GLOAD(b3r[p] + k0, &Bs3[(p * 256 + tid) * 8]);
    }
    __syncthreads();

    short8 av1[4], av3[4], bv1[4], bv3[4];
#pragma unroll
    for (int mi = 0; mi < 4; ++mi) {
      av1[mi] = *(const short8*)&As1[(wm + mi * 16 + (lane & 15)) * 32 + (lane >> 4) * 8];
      av3[mi] = *(const short8*)&As3[(wm + mi * 16 + (lane & 15)) * 32 + (lane >> 4) * 8];
    }
#pragma unroll
    for (int ni = 0; ni < 4; ++ni) {
      bv1[ni] = *(const short8*)&Bs1[(wn + ni * 16 + (lane & 15)) * 32 + (lane >> 4) * 8];
      bv3[ni] = *(const short8*)&Bs3[(wn + ni * 16 + (lane & 15)) * 32 + (lane >> 4) * 8];
    }
#pragma unroll
    for (int mi = 0; mi < 4; ++mi)
#pragma unroll
      for (int ni = 0; ni < 4; ++ni) {
        acc1[mi][ni] = __builtin_amdgcn_mfma_f32_16x16x32_bf16(av1[mi], bv1[ni], acc1[mi][ni], 0, 0, 0);
        acc3[mi][ni] = __builtin_amdgcn_mfma_f32_16x16x32_bf16(av3[mi], bv3[ni], acc3[mi][ni], 0, 0, 0);
      }
  }

  const int er = (lane >> 4) * 4;
  const int ec = lane & 15;
  __syncthreads();
  ushort* Cs = smem;
#pragma unroll
  for (int mi = 0; mi < 4; ++mi)
#pragma unroll
    for (int ni = 0; ni < 4; ++ni)
#pragma unroll
      for (int j = 0; j < 4; ++j) {
        int rr = wm + mi * 16 + er + j;
        int c = wn + ni * 16 + ec;
        Cs[rr * 128 + (c ^ ((rr & 7) << 3))] = f2b(acc1[mi][ni][j]);
      }
  __syncthreads();
  const int rl = tid >> 1;
  const int clb = (tid & 1) * 64;
  const int r = row0 + rl;
  const bool rok = (r < M);
  const int t = rok ? tok[r] : 0;
  const float w = rok ? wrow[r] : 0.f;
  const int k8 = (rl & 7) << 3;
  uint svp[32];
#pragma unroll
  for (int jj = 0; jj < 8; ++jj) {
    short8 gb = zero8();
    if (rok) gb = *(const short8*)&bgate[(long)t * I_DIM + col0 + clb + jj * 8];
    short8 gv = *(const short8*)&Cs[rl * 128 + ((clb + jj * 8) ^ k8)];
#pragma unroll
    for (int q = 0; q < 8; q += 2) {
      float g0 = b2f((ushort)gv[q]) + b2f((ushort)gb[q]);
      float g1 = b2f((ushort)gv[q + 1]) + b2f((ushort)gb[q + 1]);
      float s0 = g0 / (1.f + __expf(-g0));
      float s1 = g1 / (1.f + __expf(-g1));
      svp[jj * 4 + q / 2] = (uint)f2b(s0) | ((uint)f2b(s1) << 16);
    }
  }
  __syncthreads();
#pragma unroll
  for (int mi = 0; mi < 4; ++mi)
#pragma unroll
    for (int ni = 0; ni < 4; ++ni)
#pragma unroll
      for (int j = 0; j < 4; ++j) {
        int rr = wm + mi * 16 + er + j;
        int c = wn + ni * 16 + ec;
        Cs[rr * 128 + (c ^ ((rr & 7) << 3))] = f2b(acc3[mi][ni][j]);
      }
  __syncthreads();
#pragma unroll
  for (int jj = 0; jj < 8; ++jj) {
    short8 ub = zero8();
    if (rok) ub = *(const short8*)&bup[(long)t * I_DIM + col0 + clb + jj * 8];
    short8 uv = *(const short8*)&Cs[rl * 128 + ((clb + jj * 8) ^ k8)];
    short8 o;
#pragma unroll
    for (int q = 0; q < 8; q += 2) {
      uint sp = svp[jj * 4 + q / 2];
      float u0 = b2f((ushort)uv[q]) + b2f((ushort)ub[q]);
      float u1 = b2f((ushort)uv[q + 1]) + b2f((ushort)ub[q + 1]);
      o[q]     = (short)f2b(w * b2f((ushort)(sp & 0xFFFFu)) * u0);
      o[q + 1] = (short)f2b(w * b2f((ushort)(sp >> 16)) * u1);
    }
    if (rok) *(short8*)&H[(long)r * I_DIM + col0 + clb + jj * 8] = o;
  }
}

// ---------------- plan-B fallback GEMM (round-4 verbatim) ----------------
template <int AF32, int BF32, int CBF16, int PEREXP, int AMAP>
__global__ __launch_bounds__(256) void gemm_f(
    const void* __restrict__ Ap, int lda,
    const void* __restrict__ Bp, int ldb, long Bstride,
    int M, int N, int K, int Npad,
    float* __restrict__ Cf, ushort* __restrict__ Cb, int ldc,
    const int* __restrict__ tok, const int* __restrict__ seg, const int* __restrict__ cnt) {
  __shared__ ushort smem[16384];
  ushort* As = smem;
  ushort* Bs = smem + 4096;
  const float* Af = (const float*)Ap;
  const ushort* Ab = (const ushort*)Ap;
  const float* Bf = (const float*)Bp;
  const ushort* Bb = (const ushort*)Bp;
  const int* amap = tok;
  if (PEREXP) {
    int e = blockIdx.z;
    int m0 = seg[e];
    M = cnt[e];
    if ((int)(blockIdx.y * 128) >= M) return;
    if (AMAP) {
      amap = tok + m0;
    } else {
      if (AF32) Af += (long)m0 * lda; else Ab += (long)m0 * lda;
    }
    if (BF32) Bf += (long)e * Bstride; else Bb += (long)e * Bstride;
    if (CBF16) Cb += (long)m0 * ldc; else Cf += (long)m0 * ldc;
  }
  const int tid = threadIdx.x;
  const int lane = tid & 63, wave = tid >> 6;
  const int wm = (wave >> 1) * 64, wn = (wave & 1) * 64;
  const int row0 = blockIdx.y * 128, col0 = blockIdx.x * 128;
  const int sub_r = tid >> 2;
  const int sub_c = (tid & 3) * 8;

  const float* afrow[2]; const ushort* abrow[2];
  const float* bfrow[2]; const ushort* bbrow[2];
#pragma unroll
  for (int p = 0; p < 2; ++p) {
    int r = row0 + p * 64 + sub_r; if (r > M - 1) r = M - 1;
    if (AMAP) r = amap[r];
    if (AF32) afrow[p] = Af + (long)r * lda + sub_c;
    else      abrow[p] = Ab + (long)r * lda + sub_c;
    int q = col0 + p * 64 + sub_r; if (q > N - 1) q = N - 1;
    if (BF32) bfrow[p] = Bf + (long)q * ldb + sub_c;
    else      bbrow[p] = Bb + (long)q * ldb + sub_c;
  }

  f32x4 acc[4][4] = {};

  for (int k0 = 0; k0 < K; k0 += 32) {
    float4 a0[2], a1[2], b0[2], b1[2];
    if (AF32) {
#pragma unroll
      for (int p = 0; p < 2; ++p) {
        a0[p] = *(const float4*)(afrow[p] + k0);
        a1[p] = *(const float4*)(afrow[p] + k0 + 4);
      }
    }
    if (BF32) {
#pragma unroll
      for (int p = 0; p < 2; ++p) {
        b0[p] = *(const float4*)(bfrow[p] + k0);
        b1[p] = *(const float4*)(bfrow[p] + k0 + 4);
      }
    }
    __syncthreads();
#pragma unroll
    for (int p = 0; p < 2; ++p) {
      if (AF32) {
        *(short8*)&As[(p * 256 + tid) * 8] = pack8(a0[p], a1[p]);
      } else {
        GLOAD(abrow[p] + k0, &As[(p * 256 + tid) * 8]);
      }
      if (BF32) {
        *(short8*)&Bs[(p * 256 + tid) * 8] = pack8(b0[p], b1[p]);
      } else {
        GLOAD(bbrow[p] + k0, &Bs[(p * 256 + tid) * 8]);
      }
    }
    __syncthreads();

    short8 av[4], bv[4];
#pragma unroll
    for (int mi = 0; mi < 4; ++mi)
      av[mi] = *(const short8*)&As[(wm + mi * 16 + (lane & 15)) * 32 + (lane >> 4) * 8];
#pragma unroll
    for (int ni = 0; ni < 4; ++ni)
      bv[ni] = *(const short8*)&Bs[(wn + ni * 16 + (lane & 15)) * 32 + (lane >> 4) * 8];
#pragma unroll
    for (int mi = 0; mi < 4; ++mi)
#pragma unroll
      for (int ni = 0; ni < 4; ++ni)
        acc[mi][ni] = __builtin_amdgcn_mfma_f32_16x16x32_bf16(av[mi], bv[ni], acc[mi][ni], 0, 0, 0);
  }

  const int er = (lane >> 4) * 4;
  const int ec = lane & 15;
  if (CBF16) {
    __syncthreads();
    ushort* Cs = smem;
#pragma unroll
    for (int mi = 0; mi < 4; ++mi)
#pragma unroll
      for (int ni = 0; ni < 4; ++ni)
#pragma unroll
        for (int j = 0; j < 4; ++j) {
          int rr = wm + mi * 16 + er + j;
          int c = wn + ni * 16 + ec;
          Cs[rr * 128 + (c ^ ((rr & 7) << 3))] =
              (col0 + c < N) ? f2b(acc[mi][ni][j]) : (ushort)0;
        }
    __syncthreads();
    const int rl = tid >> 1;
    const int clb = (tid & 1) * 64;
    const int r = row0 + rl;
    if (r < M) {
      const int k8 = (rl & 7) << 3;
#pragma unroll
      for (int jj = 0; jj < 8; ++jj) {
        int cg = col0 + clb + jj * 8;
        if (cg < Npad) {
          short8 v = *(const short8*)&Cs[rl * 128 + ((clb + jj * 8) ^ k8)];
          *(short8*)&Cb[(long)r * ldc + cg] = v;
        }
      }
    }
  } else {
#pragma unroll
    for (int mi = 0; mi < 4; ++mi)
#pragma unroll
      for (int ni = 0; ni < 4; ++ni)
#pragma unroll
        for (int j = 0; j < 4; ++j) {
          int r = row0 + wm + mi * 16 + er + j;
          int c = col0 + wn + ni * 16 + ec;
          if (r < M && c < Npad)
            Cf[(long)r * ldc + c] = (c < N) ? acc[mi][ni][j] : 0.f;
        }
  }
}

// ---------------- launch ----------------
extern "C" void kernel_launch(void* const* d_in, const int* in_sizes, int n_in,
                              void* d_out, int out_size, void* d_ws, size_t ws_size,
                              hipStream_t stream) {
  const float* x   = (const float*)d_in[0];
  const float* gw  = (const float*)d_in[1];
  const float* Wm1 = (const float*)d_in[2];
  const float* Wm2 = (const float*)d_in[3];
  const float* Wm3 = (const float*)d_in[4];
  const float* du1 = (const float*)d_in[5];
  const float* dv1 = (const float*)d_in[6];
  const float* du2 = (const float*)d_in[7];
  const float* dv2 = (const float*)d_in[8];
  const float* du3 = (const float*)d_in[9];
  const float* dv3 = (const float*)d_in[10];

  float* out_final  = (float*)d_out;
  float* out_logits = out_final + (long)T_TOK * H_DIM;

  char* p = (char*)d_ws;
  auto alloc = [&](size_t bytes) {
    char* r = p;
    p += (bytes + 255) & ~(size_t)255;
    return r;
  };

  float* comb   = (float*)alloc((size_t)T_TOK * E_NUM * 4);
  float* wrow   = (float*)alloc((size_t)P_PAIRS * 4);
  int* cnt      = (int*)alloc(64);
  int* cursor   = (int*)alloc(64);
  int* seg      = (int*)alloc(64);
  int* sel_e    = (int*)alloc((size_t)T_TOK * 2 * 4);
  int* tok      = (int*)alloc((size_t)P_PAIRS * 4);
  int* row_of   = (int*)alloc((size_t)T_TOK * 2 * 4);
  ushort* bgate_b = (ushort*)alloc((size_t)T_TOK * I_DIM * 2);   // later: hc
  ushort* bup_b   = (ushort*)alloc((size_t)T_TOK * I_DIM * 2);   // later: p2, then deltab
  ushort* hmidg   = (ushort*)alloc((size_t)P_PAIRS * I_DIM * 2); // earlier: p1|p3
  ushort* t1g     = (ushort*)alloc((size_t)P_PAIRS * RP * 2);
  ushort* t3g     = (ushort*)alloc((size_t)P_PAIRS * RP * 2);
  ushort* t2g     = (ushort*)alloc((size_t)P_PAIRS * RP * 2);
  ushort* du1b    = (ushort*)alloc((size_t)E_NUM * I_DIM * RP * 2);  // later: dp (w/ du3b)
  ushort* du3b    = (ushort*)alloc((size_t)E_NUM * I_DIM * RP * 2);
  ushort* du2b    = (ushort*)alloc((size_t)E_NUM * H_DIM * RP * 2);
  size_t needed_B = (size_t)(p - (char*)d_ws);
  ushort* xb   = (ushort*)alloc((size_t)T_TOK * H_DIM * 2);
  ushort* w1b  = (ushort*)alloc((size_t)I_DIM * H_DIM * 2);
  ushort* w3b  = (ushort*)alloc((size_t)I_DIM * H_DIM * 2);
  ushort* dv1b = (ushort*)alloc((size_t)E_NUM * R_RANK * H_DIM * 2);
  ushort* dv3b = (ushort*)alloc((size_t)E_NUM * R_RANK * H_DIM * 2);
  size_t needed_A = (size_t)(p - (char*)d_ws);
  ushort* w2b_d  = (ushort*)alloc((size_t)I_DIM * H_DIM * 2);
  ushort* dv2b_d = (ushort*)alloc((size_t)E_NUM * R_RANK * I_DIM * 2);
  size_t needed_A2 = (size_t)(p - (char*)d_ws);

  ushort* hc     = bgate_b;
  ushort* deltab = bup_b;

  if (ws_size < needed_B) return;
  const bool planA  = (ws_size >= needed_A);
  const bool planA2 = (ws_size >= needed_A2);

  dim3 blk(256);

  init_kernel<<<1, 64, 0, stream>>>(cnt, cursor);
  router_kernel<<<T_TOK / 4, 256, 0, stream>>>(x, gw, out_logits, comb, sel_e, cnt);
  scan_kernel<<<1, 64, 0, stream>>>(cnt, seg);
  assign_kernel<<<4, 256, 0, stream>>>(sel_e, comb, seg, cursor, tok, wrow, row_of);

  padcast8_kernel<<<4480, 256, 0, stream>>>(du1, du1b, (long)E_NUM * I_DIM);
  padcast8_kernel<<<4480, 256, 0, stream>>>(du3, du3b, (long)E_NUM * I_DIM);
  padcast8_kernel<<<1280, 256, 0, stream>>>(du2, du2b, (long)E_NUM * H_DIM);

  if (planA) {
    ushort* w2b  = planA2 ? w2b_d  : w1b;
    ushort* dv2b = planA2 ? dv2b_d : w3b;

    cast8_kernel<<<1024, 256, 0, stream>>>(x, xb, (long)T_TOK * H_DIM / 8);
    cast8_kernel<<<7168, 256, 0, stream>>>(Wm1, w1b, (long)I_DIM * H_DIM / 8);
    cast8_kernel<<<7168, 256, 0, stream>>>(Wm3, w3b, (long)I_DIM * H_DIM / 8);
    cast8_kernel<<<1272, 256, 0, stream>>>(dv1, dv1b, (long)E_NUM * R_RANK * H_DIM / 8);
    cast8_kernel<<<1272, 256, 0, stream>>>(dv3, dv3b, (long)E_NUM * R_RANK * H_DIM / 8);
    if (planA2) {
      cast8_kernel<<<7168, 256, 0, stream>>>(Wm2, w2b, (long)I_DIM * H_DIM / 8);
      cast8_kernel<<<4452, 256, 0, stream>>>(dv2, dv2b, (long)E_NUM * R_RANK * I_DIM / 8);
    }

    // merged base gate+up : 896 blocks
    k_base<<<dim3(I_DIM / 128, T_TOK / 128, 2), blk, 0, stream>>>(xb, w1b, w3b, bgate_b, bup_b);

    // merged t1+t3 split-K8 : 2048 blocks, partials in hmidg region
    float* p1 = (float*)hmidg;
    float* p3 = p1 + (long)8 * P_PAIRS * RP;
    k_t13<<<dim3(2, 8, 128), blk, 0, stream>>>(xb, dv1b, dv3b, tok, seg, cnt, p1, p3);
    reduce2_kernel<<<2560, 256, 0, stream>>>(p1, p3, t1g, t3g, (long)P_PAIRS * RP);

    if (!planA2) {
      // w1b/w3b dead after k_base -> reuse for Wm2/dv2
      cast8_kernel<<<7168, 256, 0, stream>>>(Wm2, w2b, (long)I_DIM * H_DIM / 8);
      cast8_kernel<<<4452, 256, 0, stream>>>(dv2, dv2b, (long)E_NUM * R_RANK * I_DIM / 8);
    }

    // hmid (overwrites partial region)
    gemm_hmid<<<dim3(I_DIM / 128, 8, E_NUM), blk, 0, stream>>>(
        t1g, t3g, du1b, du3b, bgate_b, bup_b, tok, wrow, seg, cnt, hmidg);

    hcomb_kernel<<<(int)(((long)T_TOK * I_DIM / 8 + 255) / 256), 256, 0, stream>>>(hmidg, row_of, hc);

    // merged down split-K4 + t2 split-K8 : 1536 blocks
    float* dp = (float*)du1b;                 // 33.5MB into du1b+du3b (36.7MB)
    float* p2 = (float*)bup_b;                // 10.5MB into bup region (dead after hmid)
    k_phase2<<<dim3(H_DIM / 128, 8, 12), blk, 0, stream>>>(
        hc, w2b, hmidg, dv2b, seg, cnt, dp, p2);
    reduce_cast_kernel<8><<<1280, 256, 0, stream>>>(p2, (long)P_PAIRS * RP, t2g, (long)P_PAIRS * RP);

    // delta = t2g @ du2^T (overwrites p2 region; p2 already consumed)
    k_delta<<<dim3(H_DIM / 128, 8, E_NUM), blk, 0, stream>>>(t2g, du2b, seg, cnt, deltab);

    finalfixA_kernel<<<2048, 256, 0, stream>>>(out_final, dp, deltab, row_of);
  } else {
    // plan B fallback (round-2 structure, f32 direct)
    gemm_f<1, 1, 1, 0, 0><<<dim3(I_DIM / 128, T_TOK / 128, 1), blk, 0, stream>>>(
        x, H_DIM, Wm1, H_DIM, 0L, T_TOK, I_DIM, H_DIM, I_DIM,
        nullptr, bgate_b, I_DIM, nullptr, nullptr, nullptr);
    gemm_f<1, 1, 1, 0, 0><<<dim3(I_DIM / 128, T_TOK / 128, 1), blk, 0, stream>>>(
        x, H_DIM, Wm3, H_DIM, 0L, T_TOK, I_DIM, H_DIM, I_DIM,
        nullptr, bup_b, I_DIM, nullptr, nullptr, nullptr);
    gemm_f<1, 1, 1, 1, 1><<<dim3(2, 8, E_NUM), blk, 0, stream>>>(
        x, H_DIM, dv1, H_DIM, (long)R_RANK * H_DIM, 0, R_RANK, H_DIM, RP,
        nullptr, t1g, RP, tok, seg, cnt);
    gemm_f<1, 1, 1, 1, 1><<<dim3(2, 8, E_NUM), blk, 0, stream>>>(
        x, H_DIM, dv3, H_DIM, (long)R_RANK * H_DIM, 0, R_RANK, H_DIM, RP,
        nullptr, t3g, RP, tok, seg, cnt);
    gemm_hmid<<<dim3(I_DIM / 128, 8, E_NUM), blk, 0, stream>>>(
        t1g, t3g, du1b, du3b, bgate_b, bup_b, tok, wrow, seg, cnt, hmidg);
    hcomb_kernel<<<(int)(((long)T_TOK * I_DIM / 8 + 255) / 256), 256, 0, stream>>>(hmidg, row_of, hc);
    gemm_f<0, 1, 0, 0, 0><<<dim3(H_DIM / 128, T_TOK / 128, 1), blk, 0, stream>>>(
        hc, I_DIM, Wm2, I_DIM, 0L, T_TOK, H_DIM, I_DIM, H_DIM,
        out_final, nullptr, H_DIM, nullptr, nullptr, nullptr);
    gemm_f<0, 1, 1, 1, 0><<<dim3(2, 8, E_NUM), blk, 0, stream>>>(
        hmidg, I_DIM, dv2, I_DIM, (long)R_RANK * I_DIM, 0, R_RANK, I_DIM, RP,
        nullptr, t2g, RP, tok, seg, cnt);
    gemm_f<0, 0, 1, 1, 0><<<dim3(H_DIM / 128, 8, E_NUM), blk, 0, stream>>>(
        t2g, RP, du2b, RP, (long)H_DIM * RP, 0, H_DIM, RP, H_DIM,
        nullptr, deltab, H_DIM, tok, seg, cnt);
    finalfix_kernel<<<(int)(((long)T_TOK * H_DIM / 4 + 255) / 256), 256, 0, stream>>>(
        out_final, deltab, row_of);
  }
}

// Round 7
// 500.882 us; speedup vs baseline: 1.4850x; 1.0599x over previous
//
#include <hip/hip_runtime.h>

#define T_TOK 1024
#define H_DIM 2048
#define I_DIM 7168
#define E_NUM 8
#define R_RANK 159
#define RP 160
#define P_PAIRS 2048

typedef __attribute__((ext_vector_type(8))) short short8;
typedef __attribute__((ext_vector_type(4))) float f32x4;

__device__ __forceinline__ ushort f2b(float f) {
  uint u = __float_as_uint(f);
  uint r = (u + 0x7FFFu + ((u >> 16) & 1u)) >> 16;
  return (ushort)r;
}
__device__ __forceinline__ float b2f(ushort u) {
  return __uint_as_float(((uint)u) << 16);
}
__device__ __forceinline__ short8 pack8(float4 a, float4 b) {
  short8 o;
  o[0] = (short)f2b(a.x); o[1] = (short)f2b(a.y); o[2] = (short)f2b(a.z); o[3] = (short)f2b(a.w);
  o[4] = (short)f2b(b.x); o[5] = (short)f2b(b.y); o[6] = (short)f2b(b.z); o[7] = (short)f2b(b.w);
  return o;
}
__device__ __forceinline__ short8 zero8() {
  short8 z;
#pragma unroll
  for (int q = 0; q < 8; ++q) z[q] = 0;
  return z;
}
// bank-conflict swizzle: 16B chunk g of row -> g ^ ((row>>1)&3)  (involution)
__device__ __forceinline__ int swzofs(int row, int g) { return (g ^ ((row >> 1) & 3)) * 8; }

#define GLOAD(gptr, lptr) \
  __builtin_amdgcn_global_load_lds((const __attribute__((address_space(1))) void*)(gptr), \
                                   (__attribute__((address_space(3))) void*)(lptr), 16, 0, 0)

// ---------------- router ----------------
__global__ __launch_bounds__(256) void router_kernel(
    const float* __restrict__ x, const float* __restrict__ gw,
    float* __restrict__ logits, float* __restrict__ comb,
    int* __restrict__ sel_e, int* __restrict__ cnt) {
  int wave = threadIdx.x >> 6, lane = threadIdx.x & 63;
  int t = blockIdx.x * 4 + wave;
  const float* xr = x + (long)t * H_DIM;
  float acc[8] = {0.f,0.f,0.f,0.f,0.f,0.f,0.f,0.f};
  for (int h = lane * 4; h < H_DIM; h += 256) {
    const float4 xv = *(const float4*)&xr[h];
#pragma unroll
    for (int e = 0; e < 8; ++e) {
      const float4 gv = *(const float4*)&gw[e * H_DIM + h];
      acc[e] += xv.x * gv.x + xv.y * gv.y + xv.z * gv.z + xv.w * gv.w;
    }
  }
#pragma unroll
  for (int off = 32; off > 0; off >>= 1)
#pragma unroll
    for (int e = 0; e < 8; ++e) acc[e] += __shfl_down(acc[e], off);
  if (lane == 0) {
#pragma unroll
    for (int e = 0; e < 8; ++e) logits[(long)t * 8 + e] = acc[e];
    int i0 = 0;
    for (int e = 1; e < 8; ++e) if (acc[e] > acc[i0]) i0 = e;
    int i1 = (i0 == 0) ? 1 : 0;
    for (int e = 0; e < 8; ++e) if (e != i0 && acc[e] > acc[i1]) i1 = e;
    float ee = __expf(acc[i1] - acc[i0]);
    float w0 = 1.f / (1.f + ee), w1 = ee / (1.f + ee);
    for (int e = 0; e < 8; ++e) comb[t * 8 + e] = 0.f;
    comb[t * 8 + i0] = w0;
    comb[t * 8 + i1] = w1;
    sel_e[t * 2] = i0;
    sel_e[t * 2 + 1] = i1;
    atomicAdd(&cnt[i0], 1);
    atomicAdd(&cnt[i1], 1);
  }
}

__global__ void init_kernel(int* cnt, int* cursor) {
  int i = threadIdx.x;
  if (i < 8) { cnt[i] = 0; cursor[i] = 0; }
}

__global__ void scan_kernel(const int* cnt, int* seg) {
  if (threadIdx.x == 0) {
    int s = 0;
    for (int e = 0; e < 8; ++e) { seg[e] = s; s += cnt[e]; }
    seg[8] = s;
  }
}

__global__ void assign_kernel(const int* __restrict__ sel_e, const float* __restrict__ comb,
                              const int* __restrict__ seg, int* __restrict__ cursor,
                              int* __restrict__ tok, float* __restrict__ wrow,
                              int* __restrict__ row_of) {
  int t = blockIdx.x * blockDim.x + threadIdx.x;
  if (t >= T_TOK) return;
  for (int k = 0; k < 2; ++k) {
    int e = sel_e[t * 2 + k];
    int pos = atomicAdd(&cursor[e], 1);
    int row = seg[e] + pos;
    tok[row] = t;
    wrow[row] = comb[t * 8 + e];
    row_of[t * 2 + k] = row;
  }
}

// ---------------- casts ----------------
__global__ void cast8_kernel(const float* __restrict__ src, ushort* __restrict__ dst, long n8) {
  long idx = (long)blockIdx.x * blockDim.x + threadIdx.x;
  long stride = (long)gridDim.x * blockDim.x;
  for (long i = idx; i < n8; i += stride) {
    const float4 a = *(const float4*)&src[i * 8];
    const float4 b = *(const float4*)&src[i * 8 + 4];
    *(short8*)&dst[i * 8] = pack8(a, b);
  }
}

__global__ void padcast8_kernel(const float* __restrict__ src, ushort* __restrict__ dst, long rows) {
  long n8 = rows * (RP / 8);
  long idx = (long)blockIdx.x * blockDim.x + threadIdx.x;
  long stride = (long)gridDim.x * blockDim.x;
  for (long i = idx; i < n8; i += stride) {
    long row = i / (RP / 8);
    int c0 = (int)(i % (RP / 8)) * 8;
    short8 o;
#pragma unroll
    for (int j = 0; j < 8; ++j) {
      int c = c0 + j;
      o[j] = (c < R_RANK) ? (short)f2b(src[row * R_RANK + c]) : (short)0;
    }
    *(short8*)&dst[row * RP + c0] = o;
  }
}

__global__ void hcomb_kernel(const ushort* __restrict__ hmid, const int* __restrict__ row_of,
                             ushort* __restrict__ hc) {
  long idx = (long)blockIdx.x * blockDim.x + threadIdx.x;
  long total = (long)T_TOK * I_DIM / 8;
  if (idx >= total) return;
  long i = idx * 8;
  int t = (int)(i / I_DIM);
  int col = (int)(i % I_DIM);
  int r0 = row_of[t * 2], r1 = row_of[t * 2 + 1];
  const short8 a = *(const short8*)&hmid[(long)r0 * I_DIM + col];
  const short8 b = *(const short8*)&hmid[(long)r1 * I_DIM + col];
  short8 o;
#pragma unroll
  for (int j = 0; j < 8; ++j)
    o[j] = (short)f2b(b2f((ushort)a[j]) + b2f((ushort)b[j]));
  *(short8*)&hc[i] = o;
}

__global__ void finalfix_kernel(float* __restrict__ out, const ushort* __restrict__ delta,
                                const int* __restrict__ row_of) {
  long idx = (long)blockIdx.x * blockDim.x + threadIdx.x;
  long total = (long)T_TOK * H_DIM / 4;
  if (idx >= total) return;
  long i = idx * 4;
  int t = (int)(i / H_DIM);
  int col = (int)(i % H_DIM);
  int r0 = row_of[t * 2], r1 = row_of[t * 2 + 1];
  float4 d = *(float4*)&out[i];
  d.x += b2f(delta[(long)r0 * H_DIM + col + 0]) + b2f(delta[(long)r1 * H_DIM + col + 0]);
  d.y += b2f(delta[(long)r0 * H_DIM + col + 1]) + b2f(delta[(long)r1 * H_DIM + col + 1]);
  d.z += b2f(delta[(long)r0 * H_DIM + col + 2]) + b2f(delta[(long)r1 * H_DIM + col + 2]);
  d.w += b2f(delta[(long)r0 * H_DIM + col + 3]) + b2f(delta[(long)r1 * H_DIM + col + 3]);
  *(float4*)&out[i] = d;
}

__global__ void finalfixA_kernel(float* __restrict__ out, const float* __restrict__ dp,
                                 const ushort* __restrict__ delta, const int* __restrict__ row_of) {
  long idx = (long)blockIdx.x * blockDim.x + threadIdx.x;
  long total = (long)T_TOK * H_DIM / 4;
  if (idx >= total) return;
  long i = idx * 4;
  int t = (int)(i / H_DIM);
  int col = (int)(i % H_DIM);
  int r0 = row_of[t * 2], r1 = row_of[t * 2 + 1];
  const long plane = (long)T_TOK * H_DIM;
  float4 s = *(const float4*)&dp[i];
#pragma unroll
  for (int k = 1; k < 4; ++k) {
    const float4 q = *(const float4*)&dp[k * plane + i];
    s.x += q.x; s.y += q.y; s.z += q.z; s.w += q.w;
  }
  s.x += b2f(delta[(long)r0 * H_DIM + col + 0]) + b2f(delta[(long)r1 * H_DIM + col + 0]);
  s.y += b2f(delta[(long)r0 * H_DIM + col + 1]) + b2f(delta[(long)r1 * H_DIM + col + 1]);
  s.z += b2f(delta[(long)r0 * H_DIM + col + 2]) + b2f(delta[(long)r1 * H_DIM + col + 2]);
  s.w += b2f(delta[(long)r0 * H_DIM + col + 3]) + b2f(delta[(long)r1 * H_DIM + col + 3]);
  *(float4*)&out[i] = s;
}

template <int KS>
__global__ void reduce_cast_kernel(const float* __restrict__ P, long plane,
                                   ushort* __restrict__ out, long n) {
  long i = (long)blockIdx.x * blockDim.x + threadIdx.x;
  if (i >= n) return;
  float s = 0.f;
#pragma unroll
  for (int k = 0; k < KS; ++k) s += P[(long)k * plane + i];
  out[i] = f2b(s);
}

__global__ void reduce2_kernel(const float* __restrict__ p1, const float* __restrict__ p3,
                               ushort* __restrict__ t1g, ushort* __restrict__ t3g, long n) {
  long i = (long)blockIdx.x * blockDim.x + threadIdx.x;
  if (i >= 2 * n) return;
  const float* P = (i < n) ? p1 : p3;
  ushort* o = (i < n) ? t1g : t3g;
  long ii = (i < n) ? i : i - n;
  float s = 0.f;
#pragma unroll
  for (int k = 0; k < 8; ++k) s += P[(long)k * n + ii];
  o[ii] = f2b(s);
}

// ================= K-loops (swizzled staging + swizzled ds_read) =================
// LDS tile layout per 32-col sub-tile: [128 rows][4 groups of 16B], group XOR-swizzled.
// Staging pointers must be built with sub_c = swzofs(tid>>2, tid&3).

// BK=32: As/Bs = 4096 ushorts each
__device__ __forceinline__ void kloop32(
    const ushort* ar0, const ushort* ar1,
    const ushort* br0, const ushort* br1,
    int K, ushort* As, ushort* Bs,
    int tid, int lane, int wm, int wn, f32x4 acc[4][4]) {
  for (int k0 = 0; k0 < K; k0 += 32) {
    __syncthreads();
    GLOAD(ar0 + k0, &As[tid * 8]);
    GLOAD(ar1 + k0, &As[(256 + tid) * 8]);
    GLOAD(br0 + k0, &Bs[tid * 8]);
    GLOAD(br1 + k0, &Bs[(256 + tid) * 8]);
    __syncthreads();
    short8 av[4], bv[4];
#pragma unroll
    for (int mi = 0; mi < 4; ++mi) {
      int R = wm + mi * 16 + (lane & 15);
      av[mi] = *(const short8*)&As[R * 32 + swzofs(R, lane >> 4)];
    }
#pragma unroll
    for (int ni = 0; ni < 4; ++ni) {
      int R = wn + ni * 16 + (lane & 15);
      bv[ni] = *(const short8*)&Bs[R * 32 + swzofs(R, lane >> 4)];
    }
#pragma unroll
    for (int mi = 0; mi < 4; ++mi)
#pragma unroll
      for (int ni = 0; ni < 4; ++ni)
        acc[mi][ni] = __builtin_amdgcn_mfma_f32_16x16x32_bf16(av[mi], bv[ni], acc[mi][ni], 0, 0, 0);
  }
}

// BK=64: As/Bs = 8192 ushorts each ([2][4096]); 32 MFMA per barrier pair
__device__ __forceinline__ void kloop64(
    const ushort* ar0, const ushort* ar1,
    const ushort* br0, const ushort* br1,
    int K, ushort* As, ushort* Bs,
    int tid, int lane, int wm, int wn, f32x4 acc[4][4]) {
  for (int k0 = 0; k0 < K; k0 += 64) {
    __syncthreads();
    GLOAD(ar0 + k0,      &As[tid * 8]);
    GLOAD(ar1 + k0,      &As[(256 + tid) * 8]);
    GLOAD(ar0 + k0 + 32, &As[4096 + tid * 8]);
    GLOAD(ar1 + k0 + 32, &As[4096 + (256 + tid) * 8]);
    GLOAD(br0 + k0,      &Bs[tid * 8]);
    GLOAD(br1 + k0,      &Bs[(256 + tid) * 8]);
    GLOAD(br0 + k0 + 32, &Bs[4096 + tid * 8]);
    GLOAD(br1 + k0 + 32, &Bs[4096 + (256 + tid) * 8]);
    __syncthreads();
#pragma unroll
    for (int s = 0; s < 2; ++s) {
      short8 av[4], bv[4];
#pragma unroll
      for (int mi = 0; mi < 4; ++mi) {
        int R = wm + mi * 16 + (lane & 15);
        av[mi] = *(const short8*)&As[s * 4096 + R * 32 + swzofs(R, lane >> 4)];
      }
#pragma unroll
      for (int ni = 0; ni < 4; ++ni) {
        int R = wn + ni * 16 + (lane & 15);
        bv[ni] = *(const short8*)&Bs[s * 4096 + R * 32 + swzofs(R, lane >> 4)];
      }
#pragma unroll
      for (int mi = 0; mi < 4; ++mi)
#pragma unroll
        for (int ni = 0; ni < 4; ++ni)
          acc[mi][ni] = __builtin_amdgcn_mfma_f32_16x16x32_bf16(av[mi], bv[ni], acc[mi][ni], 0, 0, 0);
    }
  }
}

// bf16 epilogue: LDS-transpose (32KB alias), coalesced short8 stores
__device__ __forceinline__ void epi_bf16(
    f32x4 acc[4][4], ushort* smem, int tid, int lane, int wm, int wn,
    int row0, int col0, int M, int Nvalid, int Npad, ushort* Cb, int ldc) {
  const int er = (lane >> 4) * 4, ec = lane & 15;
  __syncthreads();
#pragma unroll
  for (int mi = 0; mi < 4; ++mi)
#pragma unroll
    for (int ni = 0; ni < 4; ++ni)
#pragma unroll
      for (int j = 0; j < 4; ++j) {
        int rr = wm + mi * 16 + er + j;
        int c = wn + ni * 16 + ec;
        smem[rr * 128 + (c ^ ((rr & 7) << 3))] =
            (col0 + c < Nvalid) ? f2b(acc[mi][ni][j]) : (ushort)0;
      }
  __syncthreads();
  const int rl = tid >> 1, clb = (tid & 1) * 64;
  const int r = row0 + rl;
  if (r < M) {
    const int k8 = (rl & 7) << 3;
#pragma unroll
    for (int jj = 0; jj < 8; ++jj) {
      int cg = col0 + clb + jj * 8;
      if (cg < Npad) {
        short8 v = *(const short8*)&smem[rl * 128 + ((clb + jj * 8) ^ k8)];
        *(short8*)&Cb[(long)r * ldc + cg] = v;
      }
    }
  }
}

// ================= merged launches =================

// base: z=0 -> bgate = xb@Wm1b^T ; z=1 -> bup = xb@Wm3b^T   (896 blocks, BK=64)
__global__ __launch_bounds__(256) void k_base(
    const ushort* __restrict__ xb, const ushort* __restrict__ w1b, const ushort* __restrict__ w3b,
    ushort* __restrict__ bgate, ushort* __restrict__ bup) {
  __shared__ ushort smem[16384];  // As[2][4096] | Bs[2][4096] ; epilogue Cs = 32KB
  ushort* As = smem;
  ushort* Bs = smem + 8192;
  const ushort* B = blockIdx.z ? w3b : w1b;
  ushort* C = blockIdx.z ? bup : bgate;
  const int tid = threadIdx.x;
  const int lane = tid & 63, wave = tid >> 6;
  const int wm = (wave >> 1) * 64, wn = (wave & 1) * 64;
  const int row0 = blockIdx.y * 128, col0 = blockIdx.x * 128;
  const int sub_r = tid >> 2, sub_c = swzofs(sub_r, tid & 3);
  const ushort* ar0 = xb + (long)(row0 + sub_r) * H_DIM + sub_c;
  const ushort* ar1 = xb + (long)(row0 + 64 + sub_r) * H_DIM + sub_c;
  const ushort* br0 = B + (long)(col0 + sub_r) * H_DIM + sub_c;
  const ushort* br1 = B + (long)(col0 + 64 + sub_r) * H_DIM + sub_c;
  f32x4 acc[4][4] = {};
  kloop64(ar0, ar1, br0, br1, H_DIM, As, Bs, tid, lane, wm, wn, acc);
  epi_bf16(acc, smem, tid, lane, wm, wn, row0, col0, T_TOK, I_DIM, I_DIM, C, I_DIM);
}

// t1/t3: z&1 picks matrix; z>>1 = e*8+ks ; split-K8, chunk 256 (BK=64: 4 iters)
__global__ __launch_bounds__(256) void k_t13(
    const ushort* __restrict__ xb, const ushort* __restrict__ dv1b, const ushort* __restrict__ dv3b,
    const int* __restrict__ tok, const int* __restrict__ seg, const int* __restrict__ cnt,
    float* __restrict__ p1, float* __restrict__ p3) {
  __shared__ ushort smem[16384];
  ushort* As = smem;
  ushort* Bs = smem + 8192;
  const int z = blockIdx.z;
  const int which = z & 1;
  const int eks = z >> 1;
  const int e = eks >> 3, ks = eks & 7;
  const int m0 = seg[e], M = cnt[e];
  const int row0 = blockIdx.y * 128, col0 = blockIdx.x * 128;
  if (row0 >= M) return;
  const int kbase = ks * 256;
  const ushort* Bsrc = (which ? dv3b : dv1b) + (long)e * R_RANK * H_DIM;
  float* P = which ? p3 : p1;
  const int tid = threadIdx.x;
  const int lane = tid & 63, wave = tid >> 6;
  const int wm = (wave >> 1) * 64, wn = (wave & 1) * 64;
  const int sub_r = tid >> 2, sub_c = swzofs(sub_r, tid & 3);
  int r0c = row0 + sub_r;      if (r0c > M - 1) r0c = M - 1;
  int r1c = row0 + 64 + sub_r; if (r1c > M - 1) r1c = M - 1;
  const ushort* ar0 = xb + (long)tok[m0 + r0c] * H_DIM + kbase + sub_c;
  const ushort* ar1 = xb + (long)tok[m0 + r1c] * H_DIM + kbase + sub_c;
  int q0 = col0 + sub_r;      if (q0 > R_RANK - 1) q0 = R_RANK - 1;
  int q1 = col0 + 64 + sub_r; if (q1 > R_RANK - 1) q1 = R_RANK - 1;
  const ushort* br0 = Bsrc + (long)q0 * H_DIM + kbase + sub_c;
  const ushort* br1 = Bsrc + (long)q1 * H_DIM + kbase + sub_c;
  f32x4 acc[4][4] = {};
  kloop64(ar0, ar1, br0, br1, 256, As, Bs, tid, lane, wm, wn, acc);
  const int er = (lane >> 4) * 4, ec = lane & 15;
  const long plane = (long)P_PAIRS * RP;
#pragma unroll
  for (int mi = 0; mi < 4; ++mi)
#pragma unroll
    for (int ni = 0; ni < 4; ++ni)
#pragma unroll
      for (int j = 0; j < 4; ++j) {
        int r = row0 + wm + mi * 16 + er + j;
        int c = col0 + wn + ni * 16 + ec;
        if (r < M && c < RP)
          P[(long)ks * plane + (long)(m0 + r) * RP + c] = (c < R_RANK) ? acc[mi][ni][j] : 0.f;
      }
}

// phase2: z<4 -> down split-K4 (BK=64, 28 iters); z>=4 -> t2 split-K8/expert (BK=64, 14 iters)
__global__ __launch_bounds__(256) void k_phase2(
    const ushort* __restrict__ hc, const ushort* __restrict__ w2b,
    const ushort* __restrict__ hmidg, const ushort* __restrict__ dv2b,
    const int* __restrict__ seg, const int* __restrict__ cnt,
    float* __restrict__ dp, float* __restrict__ p2) {
  __shared__ ushort smem[16384];
  ushort* As = smem;
  ushort* Bs = smem + 8192;
  const int tid = threadIdx.x;
  const int lane = tid & 63, wave = tid >> 6;
  const int wm = (wave >> 1) * 64, wn = (wave & 1) * 64;
  const int sub_r = tid >> 2, sub_c = swzofs(sub_r, tid & 3);
  const int er = (lane >> 4) * 4, ec = lane & 15;

  if (blockIdx.z < 4) {
    const int ks = blockIdx.z;
    const int kbase = ks * (I_DIM / 4);
    const int row0 = blockIdx.y * 128, col0 = blockIdx.x * 128;
    const ushort* ar0 = hc + (long)(row0 + sub_r) * I_DIM + kbase + sub_c;
    const ushort* ar1 = hc + (long)(row0 + 64 + sub_r) * I_DIM + kbase + sub_c;
    const ushort* br0 = w2b + (long)(col0 + sub_r) * I_DIM + kbase + sub_c;
    const ushort* br1 = w2b + (long)(col0 + 64 + sub_r) * I_DIM + kbase + sub_c;
    f32x4 acc[4][4] = {};
    kloop64(ar0, ar1, br0, br1, I_DIM / 4, As, Bs, tid, lane, wm, wn, acc);
    float* Pk = dp + (long)ks * T_TOK * H_DIM;
#pragma unroll
    for (int mi = 0; mi < 4; ++mi)
#pragma unroll
      for (int ni = 0; ni < 4; ++ni)
#pragma unroll
        for (int j = 0; j < 4; ++j) {
          int r = row0 + wm + mi * 16 + er + j;
          int c = col0 + wn + ni * 16 + ec;
          Pk[(long)r * H_DIM + c] = acc[mi][ni][j];
        }
  } else {
    const int f = (blockIdx.z - 4) * 128 + blockIdx.y * 16 + blockIdx.x;  // 0..1023
    const int eks = f >> 4;
    const int e = eks >> 3, ks = eks & 7;
    const int rsub = f & 15;
    const int x2 = rsub & 1, y2 = rsub >> 1;
    const int m0 = seg[e], M = cnt[e];
    const int row0 = y2 * 128, col0 = x2 * 128;
    if (row0 >= M) return;
    const int kbase = ks * (I_DIM / 8);
    int r0c = row0 + sub_r;      if (r0c > M - 1) r0c = M - 1;
    int r1c = row0 + 64 + sub_r; if (r1c > M - 1) r1c = M - 1;
    const ushort* ar0 = hmidg + (long)(m0 + r0c) * I_DIM + kbase + sub_c;
    const ushort* ar1 = hmidg + (long)(m0 + r1c) * I_DIM + kbase + sub_c;
    int q0 = col0 + sub_r;      if (q0 > R_RANK - 1) q0 = R_RANK - 1;
    int q1 = col0 + 64 + sub_r; if (q1 > R_RANK - 1) q1 = R_RANK - 1;
    const ushort* br0 = dv2b + (long)e * R_RANK * I_DIM + (long)q0 * I_DIM + kbase + sub_c;
    const ushort* br1 = dv2b + (long)e * R_RANK * I_DIM + (long)q1 * I_DIM + kbase + sub_c;
    f32x4 acc[4][4] = {};
    kloop64(ar0, ar1, br0, br1, I_DIM / 8, As, Bs, tid, lane, wm, wn, acc);
    const long plane = (long)P_PAIRS * RP;
#pragma unroll
    for (int mi = 0; mi < 4; ++mi)
#pragma unroll
      for (int ni = 0; ni < 4; ++ni)
#pragma unroll
        for (int j = 0; j < 4; ++j) {
          int r = row0 + wm + mi * 16 + er + j;
          int c = col0 + wn + ni * 16 + ec;
          if (r < M && c < RP)
            p2[(long)ks * plane + (long)(m0 + r) * RP + c] = (c < R_RANK) ? acc[mi][ni][j] : 0.f;
        }
  }
}

// delta: per-expert deltab = t2g @ du2b^T (K=160, BK=32+swizzle)
__global__ __launch_bounds__(256) void k_delta(
    const ushort* __restrict__ t2g, const ushort* __restrict__ du2b,
    const int* __restrict__ seg, const int* __restrict__ cnt,
    ushort* __restrict__ deltab) {
  __shared__ ushort smem[16384];
  ushort* As = smem;
  ushort* Bs = smem + 4096;
  const int e = blockIdx.z;
  const int m0 = seg[e], M = cnt[e];
  const int row0 = blockIdx.y * 128, col0 = blockIdx.x * 128;
  if (row0 >= M) return;
  const int tid = threadIdx.x;
  const int lane = tid & 63, wave = tid >> 6;
  const int wm = (wave >> 1) * 64, wn = (wave & 1) * 64;
  const int sub_r = tid >> 2, sub_c = swzofs(sub_r, tid & 3);
  int r0c = row0 + sub_r;      if (r0c > M - 1) r0c = M - 1;
  int r1c = row0 + 64 + sub_r; if (r1c > M - 1) r1c = M - 1;
  const ushort* ar0 = t2g + (long)(m0 + r0c) * RP + sub_c;
  const ushort* ar1 = t2g + (long)(m0 + r1c) * RP + sub_c;
  const ushort* br0 = du2b + (long)e * H_DIM * RP + (long)(col0 + sub_r) * RP + sub_c;
  const ushort* br1 = du2b + (long)e * H_DIM * RP + (long)(col0 + 64 + sub_r) * RP + sub_c;
  f32x4 acc[4][4] = {};
  kloop32(ar0, ar1, br0, br1, RP, As, Bs, tid, lane, wm, wn, acc);
  epi_bf16(acc, smem, tid, lane, wm, wn, row0, col0, M, H_DIM, H_DIM,
           deltab + (long)m0 * H_DIM, H_DIM);
}

// ---------------- fused dual hmid (BK=32, swizzled) ----------------
__global__ __launch_bounds__(256) void gemm_hmid(
    const ushort* __restrict__ t1g, const ushort* __restrict__ t3g,
    const ushort* __restrict__ du1b, const ushort* __restrict__ du3b,
    const ushort* __restrict__ bgate, const ushort* __restrict__ bup,
    const int* __restrict__ tok, const float* __restrict__ wrow,
    const int* __restrict__ seg, const int* __restrict__ cnt,
    ushort* __restrict__ hmid) {
  __shared__ ushort smem[16384];
  ushort* As1 = smem;
  ushort* As3 = smem + 4096;
  ushort* Bs1 = smem + 8192;
  ushort* Bs3 = smem + 12288;
  int e = blockIdx.z;
  int m0 = seg[e], M = cnt[e];
  if ((int)(blockIdx.y * 128) >= M) return;
  const ushort* A1 = t1g + (long)m0 * RP;
  const ushort* A3 = t3g + (long)m0 * RP;
  const ushort* B1 = du1b + (long)e * I_DIM * RP;
  const ushort* B3 = du3b + (long)e * I_DIM * RP;
  tok += m0; wrow += m0;
  ushort* H = hmid + (long)m0 * I_DIM;

  const int tid = threadIdx.x;
  const int lane = tid & 63, wave = tid >> 6;
  const int wm = (wave >> 1) * 64, wn = (wave & 1) * 64;
  const int row0 = blockIdx.y * 128, col0 = blockIdx.x * 128;
  const int sub_r = tid >> 2;
  const int sub_c = swzofs(sub_r, tid & 3);

  const ushort *a1r[2], *a3r[2], *b1r[2], *b3r[2];
#pragma unroll
  for (int p = 0; p < 2; ++p) {
    int r = row0 + p * 64 + sub_r; if (r > M - 1) r = M - 1;
    a1r[p] = A1 + (long)r * RP + sub_c;
    a3r[p] = A3 + (long)r * RP + sub_c;
    int q = col0 + p * 64 + sub_r; if (q > I_DIM - 1) q = I_DIM - 1;
    b1r[p] = B1 + (long)q * RP + sub_c;
    b3r[p] = B3 + (long)q * RP + sub_c;
  }

  f32x4 acc1[4][4] = {}, acc3[4][4] = {};

  for (int k0 = 0; k0 < RP; k0 += 32) {
    __syncthreads();
#pragma unroll
    for (int p = 0; p < 2; ++p) {
      GLOAD(a1r[p] + k0, &As1[(p * 256 + tid) * 8]);
      GLOAD(a3r[p] + k0, &As3[(p * 256 + tid) * 8]);
      GLOAD(b1r[p] + k0, &Bs1[(p * 256 + tid) * 8]);
      GLOAD(b3r[p] + k0, &Bs3[(p * 256 + tid) * 8]);
    }
    __syncthreads();

    short8 av1[4], av3[4], bv1[4], bv3[4];
#pragma unroll
    for (int mi = 0; mi < 4; ++mi) {
      int R = wm + mi * 16 + (lane & 15);
      int o = R * 32 + swzofs(R, lane >> 4);
      av1[mi] = *(const short8*)&As1[o];
      av3[mi] = *(const short8*)&As3[o];
    }
#pragma unroll
    for (int ni = 0; ni < 4; ++ni) {
      int R = wn + ni * 16 + (lane & 15);
      int o = R * 32 + swzofs(R, lane >> 4);
      bv1[ni] = *(const short8*)&Bs1[o];
      bv3[ni] = *(const short8*)&Bs3[o];
    }
#pragma unroll
    for (int mi = 0; mi < 4; ++mi)
#pragma unroll
      for (int ni = 0; ni < 4; ++ni) {
        acc1[mi][ni] = __builtin_amdgcn_mfma_f32_16x16x32_bf16(av1[mi], bv1[ni], acc1[mi][ni], 0, 0, 0);
        acc3[mi][ni] = __builtin_amdgcn_mfma_f32_16x16x32_bf16(av3[mi], bv3[ni], acc3[mi][ni], 0, 0, 0);
      }
  }

  const int er = (lane >> 4) * 4;
  const int ec = lane & 15;
  __syncthreads();
  ushort* Cs = smem;
#pragma unroll
  for (int mi = 0; mi < 4; ++mi)
#pragma unroll
    for (int ni = 0; ni < 4; ++ni)
#pragma unroll
      for (int j = 0; j < 4; ++j) {
        int rr = wm + mi * 16 + er + j;
        int c = wn + ni * 16 + ec;
        Cs[rr * 128 + (c ^ ((rr & 7) << 3))] = f2b(acc1[mi][ni][j]);
      }
  __syncthreads();
  const int rl = tid >> 1;
  const int clb = (tid & 1) * 64;
  const int r = row0 + rl;
  const bool rok = (r < M);
  const int t = rok ? tok[r] : 0;
  const float w = rok ? wrow[r] : 0.f;
  const int k8 = (rl & 7) << 3;
  uint svp[32];
#pragma unroll
  for (int jj = 0; jj < 8; ++jj) {
    short8 gb = zero8();
    if (rok) gb = *(const short8*)&bgate[(long)t * I_DIM + col0 + clb + jj * 8];
    short8 gv = *(const short8*)&Cs[rl * 128 + ((clb + jj * 8) ^ k8)];
#pragma unroll
    for (int q = 0; q < 8; q += 2) {
      float g0 = b2f((ushort)gv[q]) + b2f((ushort)gb[q]);
      float g1 = b2f((ushort)gv[q + 1]) + b2f((ushort)gb[q + 1]);
      float s0 = g0 / (1.f + __expf(-g0));
      float s1 = g1 / (1.f + __expf(-g1));
      svp[jj * 4 + q / 2] = (uint)f2b(s0) | ((uint)f2b(s1) << 16);
    }
  }
  __syncthreads();
#pragma unroll
  for (int mi = 0; mi < 4; ++mi)
#pragma unroll
    for (int ni = 0; ni < 4; ++ni)
#pragma unroll
      for (int j = 0; j < 4; ++j) {
        int rr = wm + mi * 16 + er + j;
        int c = wn + ni * 16 + ec;
        Cs[rr * 128 + (c ^ ((rr & 7) << 3))] = f2b(acc3[mi][ni][j]);
      }
  __syncthreads();
#pragma unroll
  for (int jj = 0; jj < 8; ++jj) {
    short8 ub = zero8();
    if (rok) ub = *(const short8*)&bup[(long)t * I_DIM + col0 + clb + jj * 8];
    short8 uv = *(const short8*)&Cs[rl * 128 + ((clb + jj * 8) ^ k8)];
    short8 o;
#pragma unroll
    for (int q = 0; q < 8; q += 2) {
      uint sp = svp[jj * 4 + q / 2];
      float u0 = b2f((ushort)uv[q]) + b2f((ushort)ub[q]);
      float u1 = b2f((ushort)uv[q + 1]) + b2f((ushort)ub[q + 1]);
      o[q]     = (short)f2b(w * b2f((ushort)(sp & 0xFFFFu)) * u0);
      o[q + 1] = (short)f2b(w * b2f((ushort)(sp >> 16)) * u1);
    }
    if (rok) *(short8*)&H[(long)r * I_DIM + col0 + clb + jj * 8] = o;
  }
}

// ---------------- plan-B fallback GEMM (unchanged, self-consistent layout) ----------------
template <int AF32, int BF32, int CBF16, int PEREXP, int AMAP>
__global__ __launch_bounds__(256) void gemm_f(
    const void* __restrict__ Ap, int lda,
    const void* __restrict__ Bp, int ldb, long Bstride,
    int M, int N, int K, int Npad,
    float* __restrict__ Cf, ushort* __restrict__ Cb, int ldc,
    const int* __restrict__ tok, const int* __restrict__ seg, const int* __restrict__ cnt) {
  __shared__ ushort smem[16384];
  ushort* As = smem;
  ushort* Bs = smem + 4096;
  const float* Af = (const float*)Ap;
  const ushort* Ab = (const ushort*)Ap;
  const float* Bf = (const float*)Bp;
  const ushort* Bb = (const ushort*)Bp;
  const int* amap = tok;
  if (PEREXP) {
    int e = blockIdx.z;
    int m0 = seg[e];
    M = cnt[e];
    if ((int)(blockIdx.y * 128) >= M) return;
    if (AMAP) {
      amap = tok + m0;
    } else {
      if (AF32) Af += (long)m0 * lda; else Ab += (long)m0 * lda;
    }
    if (BF32) Bf += (long)e * Bstride; else Bb += (long)e * Bstride;
    if (CBF16) Cb += (long)m0 * ldc; else Cf += (long)m0 * ldc;
  }
  const int tid = threadIdx.x;
  const int lane = tid & 63, wave = tid >> 6;
  const int wm = (wave >> 1) * 64, wn = (wave & 1) * 64;
  const int row0 = blockIdx.y * 128, col0 = blockIdx.x * 128;
  const int sub_r = tid >> 2;
  const int sub_c = (tid & 3) * 8;

  const float* afrow[2]; const ushort* abrow[2];
  const float* bfrow[2]; const ushort* bbrow[2];
#pragma unroll
  for (int p = 0; p < 2; ++p) {
    int r = row0 + p * 64 + sub_r; if (r > M - 1) r = M - 1;
    if (AMAP) r = amap[r];
    if (AF32) afrow[p] = Af + (long)r * lda + sub_c;
    else      abrow[p] = Ab + (long)r * lda + sub_c;
    int q = col0 + p * 64 + sub_r; if (q > N - 1) q = N - 1;
    if (BF32) bfrow[p] = Bf + (long)q * ldb + sub_c;
    else      bbrow[p] = Bb + (long)q * ldb + sub_c;
  }

  f32x4 acc[4][4] = {};

  for (int k0 = 0; k0 < K; k0 += 32) {
    float4 a0[2], a1[2], b0[2], b1[2];
    if (AF32) {
#pragma unroll
      for (int p = 0; p < 2; ++p) {
        a0[p] = *(const float4*)(afrow[p] + k0);
        a1[p] = *(const float4*)(afrow[p] + k0 + 4);
      }
    }
    if (BF32) {
#pragma unroll
      for (int p = 0; p < 2; ++p) {
        b0[p] = *(const float4*)(bfrow[p] + k0);
        b1[p] = *(const float4*)(bfrow[p] + k0 + 4);
      }
    }
    __syncthreads();
#pragma unroll
    for (int p = 0; p < 2; ++p) {
      if (AF32) {
        *(short8*)&As[(p * 256 + tid) * 8] = pack8(a0[p], a1[p]);
      } else {
        GLOAD(abrow[p] + k0, &As[(p * 256 + tid) * 8]);
      }
      if (BF32) {
        *(short8*)&Bs[(p * 256 + tid) * 8] = pack8(b0[p], b1[p]);
      } else {
        GLOAD(bbrow[p] + k0, &Bs[(p * 256 + tid) * 8]);
      }
    }
    __syncthreads();

    short8 av[4], bv[4];
#pragma unroll
    for (int mi = 0; mi < 4; ++mi)
      av[mi] = *(const short8*)&As[(wm + mi * 16 + (lane & 15)) * 32 + (lane >> 4) * 8];
#pragma unroll
    for (int ni = 0; ni < 4; ++ni)
      bv[ni] = *(const short8*)&Bs[(wn + ni * 16 + (lane & 15)) * 32 + (lane >> 4) * 8];
#pragma unroll
    for (int mi = 0; mi < 4; ++mi)
#pragma unroll
      for (int ni = 0; ni < 4; ++ni)
        acc[mi][ni] = __builtin_amdgcn_mfma_f32_16x16x32_bf16(av[mi], bv[ni], acc[mi][ni], 0, 0, 0);
  }

  const int er = (lane >> 4) * 4;
  const int ec = lane & 15;
  if (CBF16) {
    __syncthreads();
    ushort* Cs = smem;
#pragma unroll
    for (int mi = 0; mi < 4; ++mi)
#pragma unroll
      for (int ni = 0; ni < 4; ++ni)
#pragma unroll
        for (int j = 0; j < 4; ++j) {
          int rr = wm + mi * 16 + er + j;
          int c = wn + ni * 16 + ec;
          Cs[rr * 128 + (c ^ ((rr & 7) << 3))] =
              (col0 + c < N) ? f2b(acc[mi][ni][j]) : (ushort)0;
        }
    __syncthreads();
    const int rl = tid >> 1;
    const int clb = (tid & 1) * 64;
    const int r = row0 + rl;
    if (r < M) {
      const int k8 = (rl & 7) << 3;
#pragma unroll
      for (int jj = 0; jj < 8; ++jj) {
        int cg = col0 + clb + jj * 8;
        if (cg < Npad) {
          short8 v = *(const short8*)&Cs[rl * 128 + ((clb + jj * 8) ^ k8)];
          *(short8*)&Cb[(long)r * ldc + cg] = v;
        }
      }
    }
  } else {
#pragma unroll
    for (int mi = 0; mi < 4; ++mi)
#pragma unroll
      for (int ni = 0; ni < 4; ++ni)
#pragma unroll
        for (int j = 0; j < 4; ++j) {
          int r = row0 + wm + mi * 16 + er + j;
          int c = col0 + wn + ni * 16 + ec;
          if (r < M && c < Npad)
            Cf[(long)r * ldc + c] = (c < N) ? acc[mi][ni][j] : 0.f;
        }
  }
}

// ---------------- launch ----------------
extern "C" void kernel_launch(void* const* d_in, const int* in_sizes, int n_in,
                              void* d_out, int out_size, void* d_ws, size_t ws_size,
                              hipStream_t stream) {
  const float* x   = (const float*)d_in[0];
  const float* gw  = (const float*)d_in[1];
  const float* Wm1 = (const float*)d_in[2];
  const float* Wm2 = (const float*)d_in[3];
  const float* Wm3 = (const float*)d_in[4];
  const float* du1 = (const float*)d_in[5];
  const float* dv1 = (const float*)d_in[6];
  const float* du2 = (const float*)d_in[7];
  const float* dv2 = (const float*)d_in[8];
  const float* du3 = (const float*)d_in[9];
  const float* dv3 = (const float*)d_in[10];

  float* out_final  = (float*)d_out;
  float* out_logits = out_final + (long)T_TOK * H_DIM;

  char* p = (char*)d_ws;
  auto alloc = [&](size_t bytes) {
    char* r = p;
    p += (bytes + 255) & ~(size_t)255;
    return r;
  };

  float* comb   = (float*)alloc((size_t)T_TOK * E_NUM * 4);
  float* wrow   = (float*)alloc((size_t)P_PAIRS * 4);
  int* cnt      = (int*)alloc(64);
  int* cursor   = (int*)alloc(64);
  int* seg      = (int*)alloc(64);
  int* sel_e    = (int*)alloc((size_t)T_TOK * 2 * 4);
  int* tok      = (int*)alloc((size_t)P_PAIRS * 4);
  int* row_of   = (int*)alloc((size_t)T_TOK * 2 * 4);
  ushort* bgate_b = (ushort*)alloc((size_t)T_TOK * I_DIM * 2);   // later: hc
  ushort* bup_b   = (ushort*)alloc((size_t)T_TOK * I_DIM * 2);   // later: p2, then deltab
  ushort* hmidg   = (ushort*)alloc((size_t)P_PAIRS * I_DIM * 2); // earlier: p1|p3
  ushort* t1g     = (ushort*)alloc((size_t)P_PAIRS * RP * 2);
  ushort* t3g     = (ushort*)alloc((size_t)P_PAIRS * RP * 2);
  ushort* t2g     = (ushort*)alloc((size_t)P_PAIRS * RP * 2);
  ushort* du1b    = (ushort*)alloc((size_t)E_NUM * I_DIM * RP * 2);  // later: dp (w/ du3b)
  ushort* du3b    = (ushort*)alloc((size_t)E_NUM * I_DIM * RP * 2);
  ushort* du2b    = (ushort*)alloc((size_t)E_NUM * H_DIM * RP * 2);
  size_t needed_B = (size_t)(p - (char*)d_ws);
  ushort* xb   = (ushort*)alloc((size_t)T_TOK * H_DIM * 2);
  ushort* w1b  = (ushort*)alloc((size_t)I_DIM * H_DIM * 2);
  ushort* w3b  = (ushort*)alloc((size_t)I_DIM * H_DIM * 2);
  ushort* dv1b = (ushort*)alloc((size_t)E_NUM * R_RANK * H_DIM * 2);
  ushort* dv3b = (ushort*)alloc((size_t)E_NUM * R_RANK * H_DIM * 2);
  size_t needed_A = (size_t)(p - (char*)d_ws);
  ushort* w2b_d  = (ushort*)alloc((size_t)I_DIM * H_DIM * 2);
  ushort* dv2b_d = (ushort*)alloc((size_t)E_NUM * R_RANK * I_DIM * 2);
  size_t needed_A2 = (size_t)(p - (char*)d_ws);

  ushort* hc     = bgate_b;
  ushort* deltab = bup_b;

  if (ws_size < needed_B) return;
  const bool planA  = (ws_size >= needed_A);
  const bool planA2 = (ws_size >= needed_A2);

  dim3 blk(256);

  init_kernel<<<1, 64, 0, stream>>>(cnt, cursor);
  router_kernel<<<T_TOK / 4, 256, 0, stream>>>(x, gw, out_logits, comb, sel_e, cnt);
  scan_kernel<<<1, 64, 0, stream>>>(cnt, seg);
  assign_kernel<<<4, 256, 0, stream>>>(sel_e, comb, seg, cursor, tok, wrow, row_of);

  padcast8_kernel<<<4480, 256, 0, stream>>>(du1, du1b, (long)E_NUM * I_DIM);
  padcast8_kernel<<<4480, 256, 0, stream>>>(du3, du3b, (long)E_NUM * I_DIM);
  padcast8_kernel<<<1280, 256, 0, stream>>>(du2, du2b, (long)E_NUM * H_DIM);

  if (planA) {
    ushort* w2b  = planA2 ? w2b_d  : w1b;
    ushort* dv2b = planA2 ? dv2b_d : w3b;

    cast8_kernel<<<1024, 256, 0, stream>>>(x, xb, (long)T_TOK * H_DIM / 8);
    cast8_kernel<<<7168, 256, 0, stream>>>(Wm1, w1b, (long)I_DIM * H_DIM / 8);
    cast8_kernel<<<7168, 256, 0, stream>>>(Wm3, w3b, (long)I_DIM * H_DIM / 8);
    cast8_kernel<<<1272, 256, 0, stream>>>(dv1, dv1b, (long)E_NUM * R_RANK * H_DIM / 8);
    cast8_kernel<<<1272, 256, 0, stream>>>(dv3, dv3b, (long)E_NUM * R_RANK * H_DIM / 8);
    if (planA2) {
      cast8_kernel<<<7168, 256, 0, stream>>>(Wm2, w2b, (long)I_DIM * H_DIM / 8);
      cast8_kernel<<<4452, 256, 0, stream>>>(dv2, dv2b, (long)E_NUM * R_RANK * I_DIM / 8);
    }

    // merged base gate+up : 896 blocks, BK=64
    k_base<<<dim3(I_DIM / 128, T_TOK / 128, 2), blk, 0, stream>>>(xb, w1b, w3b, bgate_b, bup_b);

    // merged t1+t3 split-K8 : 2048 blocks, BK=64, partials in hmidg region
    float* p1 = (float*)hmidg;
    float* p3 = p1 + (long)8 * P_PAIRS * RP;
    k_t13<<<dim3(2, 8, 128), blk, 0, stream>>>(xb, dv1b, dv3b, tok, seg, cnt, p1, p3);
    reduce2_kernel<<<2560, 256, 0, stream>>>(p1, p3, t1g, t3g, (long)P_PAIRS * RP);

    if (!planA2) {
      cast8_kernel<<<7168, 256, 0, stream>>>(Wm2, w2b, (long)I_DIM * H_DIM / 8);
      cast8_kernel<<<4452, 256, 0, stream>>>(dv2, dv2b, (long)E_NUM * R_RANK * I_DIM / 8);
    }

    // hmid (overwrites partial region)
    gemm_hmid<<<dim3(I_DIM / 128, 8, E_NUM), blk, 0, stream>>>(
        t1g, t3g, du1b, du3b, bgate_b, bup_b, tok, wrow, seg, cnt, hmidg);

    hcomb_kernel<<<(int)(((long)T_TOK * I_DIM / 8 + 255) / 256), 256, 0, stream>>>(hmidg, row_of, hc);

    // merged down split-K4 + t2 split-K8 : 1536 blocks, BK=64
    float* dp = (float*)du1b;
    float* p2 = (float*)bup_b;
    k_phase2<<<dim3(H_DIM / 128, 8, 12), blk, 0, stream>>>(
        hc, w2b, hmidg, dv2b, seg, cnt, dp, p2);
    reduce_cast_kernel<8><<<1280, 256, 0, stream>>>(p2, (long)P_PAIRS * RP, t2g, (long)P_PAIRS * RP);

    // delta = t2g @ du2^T
    k_delta<<<dim3(H_DIM / 128, 8, E_NUM), blk, 0, stream>>>(t2g, du2b, seg, cnt, deltab);

    finalfixA_kernel<<<2048, 256, 0, stream>>>(out_final, dp, deltab, row_of);
  } else {
    // plan B fallback
    gemm_f<1, 1, 1, 0, 0><<<dim3(I_DIM / 128, T_TOK / 128, 1), blk, 0, stream>>>(
        x, H_DIM, Wm1, H_DIM, 0L, T_TOK, I_DIM, H_DIM, I_DIM,
        nullptr, bgate_b, I_DIM, nullptr, nullptr, nullptr);
    gemm_f<1, 1, 1, 0, 0><<<dim3(I_DIM / 128, T_TOK / 128, 1), blk, 0, stream>>>(
        x, H_DIM, Wm3, H_DIM, 0L, T_TOK, I_DIM, H_DIM, I_DIM,
        nullptr, bup_b, I_DIM, nullptr, nullptr, nullptr);
    gemm_f<1, 1, 1, 1, 1><<<dim3(2, 8, E_NUM), blk, 0, stream>>>(
        x, H_DIM, dv1, H_DIM, (long)R_RANK * H_DIM, 0, R_RANK, H_DIM, RP,
        nullptr, t1g, RP, tok, seg, cnt);
    gemm_f<1, 1, 1, 1, 1><<<dim3(2, 8, E_NUM), blk, 0, stream>>>(
        x, H_DIM, dv3, H_DIM, (long)R_RANK * H_DIM, 0, R_RANK, H_DIM, RP,
        nullptr, t3g, RP, tok, seg, cnt);
    gemm_hmid<<<dim3(I_DIM / 128, 8, E_NUM), blk, 0, stream>>>(
        t1g, t3g, du1b, du3b, bgate_b, bup_b, tok, wrow, seg, cnt, hmidg);
    hcomb_kernel<<<(int)(((long)T_TOK * I_DIM / 8 + 255) / 256), 256, 0, stream>>>(hmidg, row_of, hc);
    gemm_f<0, 1, 0, 0, 0><<<dim3(H_DIM / 128, T_TOK / 128, 1), blk, 0, stream>>>(
        hc, I_DIM, Wm2, I_DIM, 0L, T_TOK, H_DIM, I_DIM, H_DIM,
        out_final, nullptr, H_DIM, nullptr, nullptr, nullptr);
    gemm_f<0, 1, 1, 1, 0><<<dim3(2, 8, E_NUM), blk, 0, stream>>>(
        hmidg, I_DIM, dv2, I_DIM, (long)R_RANK * I_DIM, 0, R_RANK, I_DIM, RP,
        nullptr, t2g, RP, tok, seg, cnt);
    gemm_f<0, 0, 1, 1, 0><<<dim3(H_DIM / 128, 8, E_NUM), blk, 0, stream>>>(
        t2g, RP, du2b, RP, (long)H_DIM * RP, 0, H_DIM, RP, H_DIM,
        nullptr, deltab, H_DIM, tok, seg, cnt);
    finalfix_kernel<<<(int)(((long)T_TOK * H_DIM / 4 + 255) / 256), 256, 0, stream>>>(
        out_final, deltab, row_of);
  }
}

// Round 8
// 480.058 us; speedup vs baseline: 1.5494x; 1.0434x over previous
//
#include <hip/hip_runtime.h>

#define T_TOK 1024
#define H_DIM 2048
#define I_DIM 7168
#define E_NUM 8
#define R_RANK 159
#define RP 160
#define P_PAIRS 2048

// cast segment sizes in 8-element chunks
#define CH_X    262144L
#define CH_W    1835008L
#define CH_DV13 325632L
#define CH_DV2  1139712L
#define CH_DU13 1146880L
#define CH_DU2  327680L

typedef __attribute__((ext_vector_type(8))) short short8;
typedef __attribute__((ext_vector_type(4))) float f32x4;

__device__ __forceinline__ ushort f2b(float f) {
  uint u = __float_as_uint(f);
  uint r = (u + 0x7FFFu + ((u >> 16) & 1u)) >> 16;
  return (ushort)r;
}
__device__ __forceinline__ float b2f(ushort u) {
  return __uint_as_float(((uint)u) << 16);
}
__device__ __forceinline__ short8 pack8(float4 a, float4 b) {
  short8 o;
  o[0] = (short)f2b(a.x); o[1] = (short)f2b(a.y); o[2] = (short)f2b(a.z); o[3] = (short)f2b(a.w);
  o[4] = (short)f2b(b.x); o[5] = (short)f2b(b.y); o[6] = (short)f2b(b.z); o[7] = (short)f2b(b.w);
  return o;
}
__device__ __forceinline__ short8 zero8() {
  short8 z;
#pragma unroll
  for (int q = 0; q < 8; ++q) z[q] = 0;
  return z;
}
// bank-conflict swizzle (verified round 7: conflicts -> 0)
__device__ __forceinline__ int swzofs(int row, int g) { return (g ^ ((row >> 1) & 3)) * 8; }

#define GLOAD(gptr, lptr) \
  __builtin_amdgcn_global_load_lds((const __attribute__((address_space(1))) void*)(gptr), \
                                   (__attribute__((address_space(3))) void*)(lptr), 16, 0, 0)

// ---------------- router ----------------
__global__ __launch_bounds__(256) void router_kernel(
    const float* __restrict__ x, const float* __restrict__ gw,
    float* __restrict__ logits, float* __restrict__ comb,
    int* __restrict__ sel_e, int* __restrict__ cnt) {
  int wave = threadIdx.x >> 6, lane = threadIdx.x & 63;
  int t = blockIdx.x * 4 + wave;
  const float* xr = x + (long)t * H_DIM;
  float acc[8] = {0.f,0.f,0.f,0.f,0.f,0.f,0.f,0.f};
  for (int h = lane * 4; h < H_DIM; h += 256) {
    const float4 xv = *(const float4*)&xr[h];
#pragma unroll
    for (int e = 0; e < 8; ++e) {
      const float4 gv = *(const float4*)&gw[e * H_DIM + h];
      acc[e] += xv.x * gv.x + xv.y * gv.y + xv.z * gv.z + xv.w * gv.w;
    }
  }
#pragma unroll
  for (int off = 32; off > 0; off >>= 1)
#pragma unroll
    for (int e = 0; e < 8; ++e) acc[e] += __shfl_down(acc[e], off);
  if (lane == 0) {
#pragma unroll
    for (int e = 0; e < 8; ++e) logits[(long)t * 8 + e] = acc[e];
    int i0 = 0;
    for (int e = 1; e < 8; ++e) if (acc[e] > acc[i0]) i0 = e;
    int i1 = (i0 == 0) ? 1 : 0;
    for (int e = 0; e < 8; ++e) if (e != i0 && acc[e] > acc[i1]) i1 = e;
    float ee = __expf(acc[i1] - acc[i0]);
    float w0 = 1.f / (1.f + ee), w1 = ee / (1.f + ee);
    for (int e = 0; e < 8; ++e) comb[t * 8 + e] = 0.f;
    comb[t * 8 + i0] = w0;
    comb[t * 8 + i1] = w1;
    sel_e[t * 2] = i0;
    sel_e[t * 2 + 1] = i1;
    atomicAdd(&cnt[i0], 1);
    atomicAdd(&cnt[i1], 1);
  }
}

__global__ void init_kernel(int* cnt, int* cursor) {
  int i = threadIdx.x;
  if (i < 8) { cnt[i] = 0; cursor[i] = 0; }
}

__global__ void scan_kernel(const int* cnt, int* seg) {
  if (threadIdx.x == 0) {
    int s = 0;
    for (int e = 0; e < 8; ++e) { seg[e] = s; s += cnt[e]; }
    seg[8] = s;
  }
}

__global__ void assign_kernel(const int* __restrict__ sel_e, const float* __restrict__ comb,
                              const int* __restrict__ seg, int* __restrict__ cursor,
                              int* __restrict__ tok, float* __restrict__ wrow,
                              int* __restrict__ row_of) {
  int t = blockIdx.x * blockDim.x + threadIdx.x;
  if (t >= T_TOK) return;
  for (int k = 0; k < 2; ++k) {
    int e = sel_e[t * 2 + k];
    int pos = atomicAdd(&cursor[e], 1);
    int row = seg[e] + pos;
    tok[row] = t;
    wrow[row] = comb[t * 8 + e];
    row_of[t * 2 + k] = row;
  }
}

// ---------------- casts ----------------
__device__ __forceinline__ void castchunk(const float* __restrict__ s, ushort* __restrict__ d, long c) {
  const float4 a = *(const float4*)&s[c * 8];
  const float4 b = *(const float4*)&s[c * 8 + 4];
  *(short8*)&d[c * 8] = pack8(a, b);
}
__device__ __forceinline__ void padchunk(const float* __restrict__ s, ushort* __restrict__ d, long c) {
  long row = c / 20;
  int c0 = (int)(c % 20) * 8;
  short8 o;
#pragma unroll
  for (int j = 0; j < 8; ++j) {
    int cc = c0 + j;
    o[j] = (cc < R_RANK) ? (short)f2b(s[row * R_RANK + cc]) : (short)0;
  }
  *(short8*)&d[row * RP + c0] = o;
}

// all casts except Wm2/dv2, one launch
__global__ void megacast_kernel(
    const float* __restrict__ x, const float* __restrict__ Wm1, const float* __restrict__ Wm3,
    const float* __restrict__ dv1, const float* __restrict__ dv3,
    const float* __restrict__ du1, const float* __restrict__ du3, const float* __restrict__ du2,
    ushort* __restrict__ xb, ushort* __restrict__ w1b, ushort* __restrict__ w3b,
    ushort* __restrict__ dv1b, ushort* __restrict__ dv3b,
    ushort* __restrict__ du1b, ushort* __restrict__ du3b, ushort* __restrict__ du2b) {
  const long TOT = CH_W * 2 + CH_DU13 * 2 + CH_DU2 + CH_DV13 * 2 + CH_X;
  for (long c0 = (long)blockIdx.x * blockDim.x + threadIdx.x; c0 < TOT;
       c0 += (long)gridDim.x * blockDim.x) {
    long c = c0;
    if (c < CH_W)    { castchunk(Wm1, w1b, c); continue; }  c -= CH_W;
    if (c < CH_W)    { castchunk(Wm3, w3b, c); continue; }  c -= CH_W;
    if (c < CH_DU13) { padchunk(du1, du1b, c); continue; }  c -= CH_DU13;
    if (c < CH_DU13) { padchunk(du3, du3b, c); continue; }  c -= CH_DU13;
    if (c < CH_DU2)  { padchunk(du2, du2b, c); continue; }  c -= CH_DU2;
    if (c < CH_DV13) { castchunk(dv1, dv1b, c); continue; } c -= CH_DV13;
    if (c < CH_DV13) { castchunk(dv3, dv3b, c); continue; } c -= CH_DV13;
    castchunk(x, xb, c);
  }
}

// Wm2 + dv2 cast, one launch
__global__ void cast2_kernel(const float* __restrict__ Wm2, const float* __restrict__ dv2,
                             ushort* __restrict__ w2b, ushort* __restrict__ dv2b) {
  const long TOT = CH_W + CH_DV2;
  for (long c0 = (long)blockIdx.x * blockDim.x + threadIdx.x; c0 < TOT;
       c0 += (long)gridDim.x * blockDim.x) {
    long c = c0;
    if (c < CH_W) { castchunk(Wm2, w2b, c); continue; }
    c -= CH_W;
    castchunk(dv2, dv2b, c);
  }
}

// plan-B padcast
__global__ void padcast8_kernel(const float* __restrict__ src, ushort* __restrict__ dst, long rows) {
  long n8 = rows * (RP / 8);
  long idx = (long)blockIdx.x * blockDim.x + threadIdx.x;
  long stride = (long)gridDim.x * blockDim.x;
  for (long i = idx; i < n8; i += stride) padchunk(src, dst, i);
}

__global__ void hcomb_kernel(const ushort* __restrict__ hmid, const int* __restrict__ row_of,
                             ushort* __restrict__ hc) {
  long idx = (long)blockIdx.x * blockDim.x + threadIdx.x;
  long total = (long)T_TOK * I_DIM / 8;
  if (idx >= total) return;
  long i = idx * 8;
  int t = (int)(i / I_DIM);
  int col = (int)(i % I_DIM);
  int r0 = row_of[t * 2], r1 = row_of[t * 2 + 1];
  const short8 a = *(const short8*)&hmid[(long)r0 * I_DIM + col];
  const short8 b = *(const short8*)&hmid[(long)r1 * I_DIM + col];
  short8 o;
#pragma unroll
  for (int j = 0; j < 8; ++j)
    o[j] = (short)f2b(b2f((ushort)a[j]) + b2f((ushort)b[j]));
  *(short8*)&hc[i] = o;
}

__global__ void finalfix_kernel(float* __restrict__ out, const ushort* __restrict__ delta,
                                const int* __restrict__ row_of) {
  long idx = (long)blockIdx.x * blockDim.x + threadIdx.x;
  long total = (long)T_TOK * H_DIM / 4;
  if (idx >= total) return;
  long i = idx * 4;
  int t = (int)(i / H_DIM);
  int col = (int)(i % H_DIM);
  int r0 = row_of[t * 2], r1 = row_of[t * 2 + 1];
  float4 d = *(float4*)&out[i];
  d.x += b2f(delta[(long)r0 * H_DIM + col + 0]) + b2f(delta[(long)r1 * H_DIM + col + 0]);
  d.y += b2f(delta[(long)r0 * H_DIM + col + 1]) + b2f(delta[(long)r1 * H_DIM + col + 1]);
  d.z += b2f(delta[(long)r0 * H_DIM + col + 2]) + b2f(delta[(long)r1 * H_DIM + col + 2]);
  d.w += b2f(delta[(long)r0 * H_DIM + col + 3]) + b2f(delta[(long)r1 * H_DIM + col + 3]);
  *(float4*)&out[i] = d;
}

__global__ void finalfixA_kernel(float* __restrict__ out, const float* __restrict__ dp,
                                 const ushort* __restrict__ delta, const int* __restrict__ row_of) {
  long idx = (long)blockIdx.x * blockDim.x + threadIdx.x;
  long total = (long)T_TOK * H_DIM / 4;
  if (idx >= total) return;
  long i = idx * 4;
  int t = (int)(i / H_DIM);
  int col = (int)(i % H_DIM);
  int r0 = row_of[t * 2], r1 = row_of[t * 2 + 1];
  const long plane = (long)T_TOK * H_DIM;
  float4 s = *(const float4*)&dp[i];
#pragma unroll
  for (int k = 1; k < 4; ++k) {
    const float4 q = *(const float4*)&dp[k * plane + i];
    s.x += q.x; s.y += q.y; s.z += q.z; s.w += q.w;
  }
  s.x += b2f(delta[(long)r0 * H_DIM + col + 0]) + b2f(delta[(long)r1 * H_DIM + col + 0]);
  s.y += b2f(delta[(long)r0 * H_DIM + col + 1]) + b2f(delta[(long)r1 * H_DIM + col + 1]);
  s.z += b2f(delta[(long)r0 * H_DIM + col + 2]) + b2f(delta[(long)r1 * H_DIM + col + 2]);
  s.w += b2f(delta[(long)r0 * H_DIM + col + 3]) + b2f(delta[(long)r1 * H_DIM + col + 3]);
  *(float4*)&out[i] = s;
}

template <int KS>
__global__ void reduce_cast_kernel(const float* __restrict__ P, long plane,
                                   ushort* __restrict__ out, long n) {
  long i = (long)blockIdx.x * blockDim.x + threadIdx.x;
  if (i >= n) return;
  float s = 0.f;
#pragma unroll
  for (int k = 0; k < KS; ++k) s += P[(long)k * plane + i];
  out[i] = f2b(s);
}

__global__ void reduce2_kernel(const float* __restrict__ p1, const float* __restrict__ p3,
                               ushort* __restrict__ t1g, ushort* __restrict__ t3g, long n) {
  long i = (long)blockIdx.x * blockDim.x + threadIdx.x;
  if (i >= 2 * n) return;
  const float* P = (i < n) ? p1 : p3;
  ushort* o = (i < n) ? t1g : t3g;
  long ii = (i < n) ? i : i - n;
  float s = 0.f;
#pragma unroll
  for (int k = 0; k < 8; ++k) s += P[(long)k * n + ii];
  o[ii] = f2b(s);
}

// ================= K-loops (swizzled staging + swizzled ds_read) =================

// BK=32
__device__ __forceinline__ void kloop32(
    const ushort* ar0, const ushort* ar1,
    const ushort* br0, const ushort* br1,
    int K, ushort* As, ushort* Bs,
    int tid, int lane, int wm, int wn, f32x4 acc[4][4]) {
  for (int k0 = 0; k0 < K; k0 += 32) {
    __syncthreads();
    GLOAD(ar0 + k0, &As[tid * 8]);
    GLOAD(ar1 + k0, &As[(256 + tid) * 8]);
    GLOAD(br0 + k0, &Bs[tid * 8]);
    GLOAD(br1 + k0, &Bs[(256 + tid) * 8]);
    __syncthreads();
    short8 av[4], bv[4];
#pragma unroll
    for (int mi = 0; mi < 4; ++mi) {
      int R = wm + mi * 16 + (lane & 15);
      av[mi] = *(const short8*)&As[R * 32 + swzofs(R, lane >> 4)];
    }
#pragma unroll
    for (int ni = 0; ni < 4; ++ni) {
      int R = wn + ni * 16 + (lane & 15);
      bv[ni] = *(const short8*)&Bs[R * 32 + swzofs(R, lane >> 4)];
    }
#pragma unroll
    for (int mi = 0; mi < 4; ++mi)
#pragma unroll
      for (int ni = 0; ni < 4; ++ni)
        acc[mi][ni] = __builtin_amdgcn_mfma_f32_16x16x32_bf16(av[mi], bv[ni], acc[mi][ni], 0, 0, 0);
  }
}

// BK=64, NI = active 16-col B groups per wave (4 = full tile; 2 = only 32 valid cols)
template <int NI>
__device__ __forceinline__ void kloop64t(
    const ushort* ar0, const ushort* ar1,
    const ushort* br0, const ushort* br1,
    int K, ushort* As, ushort* Bs,
    int tid, int lane, int wm, int wn, f32x4 acc[4][4]) {
  const int sub_r = tid >> 2;
  for (int k0 = 0; k0 < K; k0 += 64) {
    __syncthreads();
    GLOAD(ar0 + k0,      &As[tid * 8]);
    GLOAD(ar1 + k0,      &As[(256 + tid) * 8]);
    GLOAD(ar0 + k0 + 32, &As[4096 + tid * 8]);
    GLOAD(ar1 + k0 + 32, &As[4096 + (256 + tid) * 8]);
    if (NI == 4 || sub_r < 32) {
      GLOAD(br0 + k0,      &Bs[tid * 8]);
      GLOAD(br1 + k0,      &Bs[(256 + tid) * 8]);
      GLOAD(br0 + k0 + 32, &Bs[4096 + tid * 8]);
      GLOAD(br1 + k0 + 32, &Bs[4096 + (256 + tid) * 8]);
    }
    __syncthreads();
#pragma unroll
    for (int s = 0; s < 2; ++s) {
      short8 av[4], bv[NI];
#pragma unroll
      for (int mi = 0; mi < 4; ++mi) {
        int R = wm + mi * 16 + (lane & 15);
        av[mi] = *(const short8*)&As[s * 4096 + R * 32 + swzofs(R, lane >> 4)];
      }
#pragma unroll
      for (int ni = 0; ni < NI; ++ni) {
        int R = wn + ni * 16 + (lane & 15);
        bv[ni] = *(const short8*)&Bs[s * 4096 + R * 32 + swzofs(R, lane >> 4)];
      }
#pragma unroll
      for (int mi = 0; mi < 4; ++mi)
#pragma unroll
        for (int ni = 0; ni < NI; ++ni)
          acc[mi][ni] = __builtin_amdgcn_mfma_f32_16x16x32_bf16(av[mi], bv[ni], acc[mi][ni], 0, 0, 0);
    }
  }
}

// bf16 epilogue: LDS-transpose (32KB alias), coalesced short8 stores
__device__ __forceinline__ void epi_bf16(
    f32x4 acc[4][4], ushort* smem, int tid, int lane, int wm, int wn,
    int row0, int col0, int M, int Nvalid, int Npad, ushort* Cb, int ldc) {
  const int er = (lane >> 4) * 4, ec = lane & 15;
  __syncthreads();
#pragma unroll
  for (int mi = 0; mi < 4; ++mi)
#pragma unroll
    for (int ni = 0; ni < 4; ++ni)
#pragma unroll
      for (int j = 0; j < 4; ++j) {
        int rr = wm + mi * 16 + er + j;
        int c = wn + ni * 16 + ec;
        smem[rr * 128 + (c ^ ((rr & 7) << 3))] =
            (col0 + c < Nvalid) ? f2b(acc[mi][ni][j]) : (ushort)0;
      }
  __syncthreads();
  const int rl = tid >> 1, clb = (tid & 1) * 64;
  const int r = row0 + rl;
  if (r < M) {
    const int k8 = (rl & 7) << 3;
#pragma unroll
    for (int jj = 0; jj < 8; ++jj) {
      int cg = col0 + clb + jj * 8;
      if (cg < Npad) {
        short8 v = *(const short8*)&smem[rl * 128 + ((clb + jj * 8) ^ k8)];
        *(short8*)&Cb[(long)r * ldc + cg] = v;
      }
    }
  }
}

// ================= merged launches =================

// k_early: blocks 0..895 = base gate/up GEMMs; 896..2943 = t1/t3 split-K8
__global__ __launch_bounds__(256) void k_early(
    const ushort* __restrict__ xb, const ushort* __restrict__ w1b, const ushort* __restrict__ w3b,
    const ushort* __restrict__ dv1b, const ushort* __restrict__ dv3b,
    const int* __restrict__ tok, const int* __restrict__ seg, const int* __restrict__ cnt,
    ushort* __restrict__ bgate, ushort* __restrict__ bup,
    float* __restrict__ p1, float* __restrict__ p3) {
  __shared__ ushort smem[16384];
  ushort* As = smem;
  ushort* Bs = smem + 8192;
  const int b = blockIdx.x;
  const int tid = threadIdx.x;
  const int lane = tid & 63, wave = tid >> 6;
  const int wm = (wave >> 1) * 64, wn = (wave & 1) * 64;
  const int sub_r = tid >> 2, sub_c = swzofs(sub_r, tid & 3);

  if (b < 896) {
    // ---- base: z=b/448 picks (w1b->bgate | w3b->bup) ----
    const int z = b / 448, r448 = b % 448;
    const int xk = r448 % 56, yk = r448 / 56;
    const int row0 = yk * 128, col0 = xk * 128;
    const ushort* B = z ? w3b : w1b;
    ushort* C = z ? bup : bgate;
    const ushort* ar0 = xb + (long)(row0 + sub_r) * H_DIM + sub_c;
    const ushort* ar1 = xb + (long)(row0 + 64 + sub_r) * H_DIM + sub_c;
    const ushort* br0 = B + (long)(col0 + sub_r) * H_DIM + sub_c;
    const ushort* br1 = B + (long)(col0 + 64 + sub_r) * H_DIM + sub_c;
    f32x4 acc[4][4] = {};
    kloop64t<4>(ar0, ar1, br0, br1, H_DIM, As, Bs, tid, lane, wm, wn, acc);
    epi_bf16(acc, smem, tid, lane, wm, wn, row0, col0, T_TOK, I_DIM, I_DIM, C, I_DIM);
  } else {
    // ---- t13: f = b-896; xk=f&1, yk=(f>>1)&7, zk=f>>4 ; which=zk&1, eks=zk>>1 ----
    const int f = b - 896;
    const int xk = f & 1, yk = (f >> 1) & 7, zk = f >> 4;
    const int which = zk & 1;
    const int eks = zk >> 1;
    const int e = eks >> 3, ks = eks & 7;
    const int m0 = seg[e], M = cnt[e];
    const int row0 = yk * 128, col0 = xk * 128;
    if (row0 >= M) return;
    const int kbase = ks * 256;
    const ushort* Bsrc = (which ? dv3b : dv1b) + (long)e * R_RANK * H_DIM;
    float* P = which ? p3 : p1;
    int r0c = row0 + sub_r;      if (r0c > M - 1) r0c = M - 1;
    int r1c = row0 + 64 + sub_r; if (r1c > M - 1) r1c = M - 1;
    const ushort* ar0 = xb + (long)tok[m0 + r0c] * H_DIM + kbase + sub_c;
    const ushort* ar1 = xb + (long)tok[m0 + r1c] * H_DIM + kbase + sub_c;
    int q0 = col0 + sub_r;      if (q0 > R_RANK - 1) q0 = R_RANK - 1;
    int q1 = col0 + 64 + sub_r; if (q1 > R_RANK - 1) q1 = R_RANK - 1;
    const ushort* br0 = Bsrc + (long)q0 * H_DIM + kbase + sub_c;
    const ushort* br1 = Bsrc + (long)q1 * H_DIM + kbase + sub_c;
    f32x4 acc[4][4] = {};
    if (xk == 0)
      kloop64t<4>(ar0, ar1, br0, br1, 256, As, Bs, tid, lane, wm, wn, acc);
    else
      kloop64t<2>(ar0, ar1, br0, br1, 256, As, Bs, tid, lane, wm, wn, acc);
    const int er = (lane >> 4) * 4, ec = lane & 15;
    const long plane = (long)P_PAIRS * RP;
#pragma unroll
    for (int mi = 0; mi < 4; ++mi)
#pragma unroll
      for (int ni = 0; ni < 4; ++ni)
#pragma unroll
        for (int j = 0; j < 4; ++j) {
          int r = row0 + wm + mi * 16 + er + j;
          int c = col0 + wn + ni * 16 + ec;
          if (r < M && c < RP)
            P[(long)ks * plane + (long)(m0 + r) * RP + c] = (c < R_RANK) ? acc[mi][ni][j] : 0.f;
        }
  }
}

// phase2: z<4 -> down split-K4; z>=4 -> t2 split-K8/expert (x2=1 blocks use NI=2)
__global__ __launch_bounds__(256) void k_phase2(
    const ushort* __restrict__ hc, const ushort* __restrict__ w2b,
    const ushort* __restrict__ hmidg, const ushort* __restrict__ dv2b,
    const int* __restrict__ seg, const int* __restrict__ cnt,
    float* __restrict__ dp, float* __restrict__ p2) {
  __shared__ ushort smem[16384];
  ushort* As = smem;
  ushort* Bs = smem + 8192;
  const int tid = threadIdx.x;
  const int lane = tid & 63, wave = tid >> 6;
  const int wm = (wave >> 1) * 64, wn = (wave & 1) * 64;
  const int sub_r = tid >> 2, sub_c = swzofs(sub_r, tid & 3);
  const int er = (lane >> 4) * 4, ec = lane & 15;

  if (blockIdx.z < 4) {
    const int ks = blockIdx.z;
    const int kbase = ks * (I_DIM / 4);
    const int row0 = blockIdx.y * 128, col0 = blockIdx.x * 128;
    const ushort* ar0 = hc + (long)(row0 + sub_r) * I_DIM + kbase + sub_c;
    const ushort* ar1 = hc + (long)(row0 + 64 + sub_r) * I_DIM + kbase + sub_c;
    const ushort* br0 = w2b + (long)(col0 + sub_r) * I_DIM + kbase + sub_c;
    const ushort* br1 = w2b + (long)(col0 + 64 + sub_r) * I_DIM + kbase + sub_c;
    f32x4 acc[4][4] = {};
    kloop64t<4>(ar0, ar1, br0, br1, I_DIM / 4, As, Bs, tid, lane, wm, wn, acc);
    float* Pk = dp + (long)ks * T_TOK * H_DIM;
#pragma unroll
    for (int mi = 0; mi < 4; ++mi)
#pragma unroll
      for (int ni = 0; ni < 4; ++ni)
#pragma unroll
        for (int j = 0; j < 4; ++j) {
          int r = row0 + wm + mi * 16 + er + j;
          int c = col0 + wn + ni * 16 + ec;
          Pk[(long)r * H_DIM + c] = acc[mi][ni][j];
        }
  } else {
    const int f = (blockIdx.z - 4) * 128 + blockIdx.y * 16 + blockIdx.x;  // 0..1023
    const int eks = f >> 4;
    const int e = eks >> 3, ks = eks & 7;
    const int rsub = f & 15;
    const int x2 = rsub & 1, y2 = rsub >> 1;
    const int m0 = seg[e], M = cnt[e];
    const int row0 = y2 * 128, col0 = x2 * 128;
    if (row0 >= M) return;
    const int kbase = ks * (I_DIM / 8);
    int r0c = row0 + sub_r;      if (r0c > M - 1) r0c = M - 1;
    int r1c = row0 + 64 + sub_r; if (r1c > M - 1) r1c = M - 1;
    const ushort* ar0 = hmidg + (long)(m0 + r0c) * I_DIM + kbase + sub_c;
    const ushort* ar1 = hmidg + (long)(m0 + r1c) * I_DIM + kbase + sub_c;
    int q0 = col0 + sub_r;      if (q0 > R_RANK - 1) q0 = R_RANK - 1;
    int q1 = col0 + 64 + sub_r; if (q1 > R_RANK - 1) q1 = R_RANK - 1;
    const ushort* br0 = dv2b + (long)e * R_RANK * I_DIM + (long)q0 * I_DIM + kbase + sub_c;
    const ushort* br1 = dv2b + (long)e * R_RANK * I_DIM + (long)q1 * I_DIM + kbase + sub_c;
    f32x4 acc[4][4] = {};
    if (x2 == 0)
      kloop64t<4>(ar0, ar1, br0, br1, I_DIM / 8, As, Bs, tid, lane, wm, wn, acc);
    else
      kloop64t<2>(ar0, ar1, br0, br1, I_DIM / 8, As, Bs, tid, lane, wm, wn, acc);
    const long plane = (long)P_PAIRS * RP;
#pragma unroll
    for (int mi = 0; mi < 4; ++mi)
#pragma unroll
      for (int ni = 0; ni < 4; ++ni)
#pragma unroll
        for (int j = 0; j < 4; ++j) {
          int r = row0 + wm + mi * 16 + er + j;
          int c = col0 + wn + ni * 16 + ec;
          if (r < M && c < RP)
            p2[(long)ks * plane + (long)(m0 + r) * RP + c] = (c < R_RANK) ? acc[mi][ni][j] : 0.f;
        }
  }
}

// delta: per-expert deltab = t2g @ du2b^T (K=160, BK=32+swizzle)
__global__ __launch_bounds__(256) void k_delta(
    const ushort* __restrict__ t2g, const ushort* __restrict__ du2b,
    const int* __restrict__ seg, const int* __restrict__ cnt,
    ushort* __restrict__ deltab) {
  __shared__ ushort smem[16384];
  ushort* As = smem;
  ushort* Bs = smem + 4096;
  const int e = blockIdx.z;
  const int m0 = seg[e], M = cnt[e];
  const int row0 = blockIdx.y * 128, col0 = blockIdx.x * 128;
  if (row0 >= M) return;
  const int tid = threadIdx.x;
  const int lane = tid & 63, wave = tid >> 6;
  const int wm = (wave >> 1) * 64, wn = (wave & 1) * 64;
  const int sub_r = tid >> 2, sub_c = swzofs(sub_r, tid & 3);
  int r0c = row0 + sub_r;      if (r0c > M - 1) r0c = M - 1;
  int r1c = row0 + 64 + sub_r; if (r1c > M - 1) r1c = M - 1;
  const ushort* ar0 = t2g + (long)(m0 + r0c) * RP + sub_c;
  const ushort* ar1 = t2g + (long)(m0 + r1c) * RP + sub_c;
  const ushort* br0 = du2b + (long)e * H_DIM * RP + (long)(col0 + sub_r) * RP + sub_c;
  const ushort* br1 = du2b + (long)e * H_DIM * RP + (long)(col0 + 64 + sub_r) * RP + sub_c;
  f32x4 acc[4][4] = {};
  kloop32(ar0, ar1, br0, br1, RP, As, Bs, tid, lane, wm, wn, acc);
  epi_bf16(acc, smem, tid, lane, wm, wn, row0, col0, M, H_DIM, H_DIM,
           deltab + (long)m0 * H_DIM, H_DIM);
}

// ---------------- fused dual hmid (BK=32, swizzled; round-7 verbatim) ----------------
__global__ __launch_bounds__(256) void gemm_hmid(
    const ushort* __restrict__ t1g, const ushort* __restrict__ t3g,
    const ushort* __restrict__ du1b, const ushort* __restrict__ du3b,
    const ushort* __restrict__ bgate, const ushort* __restrict__ bup,
    const int* __restrict__ tok, const float* __restrict__ wrow,
    const int* __restrict__ seg, const int* __restrict__ cnt,
    ushort* __restrict__ hmid) {
  __shared__ ushort smem[16384];
  ushort* As1 = smem;
  ushort* As3 = smem + 4096;
  ushort* Bs1 = smem + 8192;
  ushort* Bs3 = smem + 12288;
  int e = blockIdx.z;
  int m0 = seg[e], M = cnt[e];
  if ((int)(blockIdx.y * 128) >= M) return;
  const ushort* A1 = t1g + (long)m0 * RP;
  const ushort* A3 = t3g + (long)m0 * RP;
  const ushort* B1 = du1b + (long)e * I_DIM * RP;
  const ushort* B3 = du3b + (long)e * I_DIM * RP;
  tok += m0; wrow += m0;
  ushort* H = hmid + (long)m0 * I_DIM;

  const int tid = threadIdx.x;
  const int lane = tid & 63, wave = tid >> 6;
  const int wm = (wave >> 1) * 64, wn = (wave & 1) * 64;
  const int row0 = blockIdx.y * 128, col0 = blockIdx.x * 128;
  const int sub_r = tid >> 2;
  const int sub_c = swzofs(sub_r, tid & 3);

  const ushort *a1r[2], *a3r[2], *b1r[2], *b3r[2];
#pragma unroll
  for (int p = 0; p < 2; ++p) {
    int r = row0 + p * 64 + sub_r; if (r > M - 1) r = M - 1;
    a1r[p] = A1 + (long)r * RP + sub_c;
    a3r[p] = A3 + (long)r * RP + sub_c;
    int q = col0 + p * 64 + sub_r; if (q > I_DIM - 1) q = I_DIM - 1;
    b1r[p] = B1 + (long)q * RP + sub_c;
    b3r[p] = B3 + (long)q * RP + sub_c;
  }

  f32x4 acc1[4][4] = {}, acc3[4][4] = {};

  for (int k0 = 0; k0 < RP; k0 += 32) {
    __syncthreads();
#pragma unroll
    for (int p = 0; p < 2; ++p) {
      GLOAD(a1r[p] + k0, &As1[(p * 256 + tid) * 8]);
      GLOAD(a3r[p] + k0, &As3[(p * 256 + tid) * 8]);
      GLOAD(b1r[p] + k0, &Bs1[(p * 256 + tid) * 8]);
      GLOAD(b3r[p] + k0, &Bs3[(p * 256 + tid) * 8]);
    }
    __syncthreads();

    short8 av1[4], av3[4], bv1[4], bv3[4];
#pragma unroll
    for (int mi = 0; mi < 4; ++mi) {
      int R = wm + mi * 16 + (lane & 15);
      int o = R * 32 + swzofs(R, lane >> 4);
      av1[mi] = *(const short8*)&As1[o];
      av3[mi] = *(const short8*)&As3[o];
    }
#pragma unroll
    for (int ni = 0; ni < 4; ++ni) {
      int R = wn + ni * 16 + (lane & 15);
      int o = R * 32 + swzofs(R, lane >> 4);
      bv1[ni] = *(const short8*)&Bs1[o];
      bv3[ni] = *(const short8*)&Bs3[o];
    }
#pragma unroll
    for (int mi = 0; mi < 4; ++mi)
#pragma unroll
      for (int ni = 0; ni < 4; ++ni) {
        acc1[mi][ni] = __builtin_amdgcn_mfma_f32_16x16x32_bf16(av1[mi], bv1[ni], acc1[mi][ni], 0, 0, 0);
        acc3[mi][ni] = __builtin_amdgcn_mfma_f32_16x16x32_bf16(av3[mi], bv3[ni], acc3[mi][ni], 0, 0, 0);
      }
  }

  const int er = (lane >> 4) * 4;
  const int ec = lane & 15;
  __syncthreads();
  ushort* Cs = smem;
#pragma unroll
  for (int mi = 0; mi < 4; ++mi)
#pragma unroll
    for (int ni = 0; ni < 4; ++ni)
#pragma unroll
      for (int j = 0; j < 4; ++j) {
        int rr = wm + mi * 16 + er + j;
        int c = wn + ni * 16 + ec;
        Cs[rr * 128 + (c ^ ((rr & 7) << 3))] = f2b(acc1[mi][ni][j]);
      }
  __syncthreads();
  const int rl = tid >> 1;
  const int clb = (tid & 1) * 64;
  const int r = row0 + rl;
  const bool rok = (r < M);
  const int t = rok ? tok[r] : 0;
  const float w = rok ? wrow[r] : 0.f;
  const int k8 = (rl & 7) << 3;
  uint svp[32];
#pragma unroll
  for (int jj = 0; jj < 8; ++jj) {
    short8 gb = zero8();
    if (rok) gb = *(const short8*)&bgate[(long)t * I_DIM + col0 + clb + jj * 8];
    short8 gv = *(const short8*)&Cs[rl * 128 + ((clb + jj * 8) ^ k8)];
#pragma unroll
    for (int q = 0; q < 8; q += 2) {
      float g0 = b2f((ushort)gv[q]) + b2f((ushort)gb[q]);
      float g1 = b2f((ushort)gv[q + 1]) + b2f((ushort)gb[q + 1]);
      float s0 = g0 / (1.f + __expf(-g0));
      float s1 = g1 / (1.f + __expf(-g1));
      svp[jj * 4 + q / 2] = (uint)f2b(s0) | ((uint)f2b(s1) << 16);
    }
  }
  __syncthreads();
#pragma unroll
  for (int mi = 0; mi < 4; ++mi)
#pragma unroll
    for (int ni = 0; ni < 4; ++ni)
#pragma unroll
      for (int j = 0; j < 4; ++j) {
        int rr = wm + mi * 16 + er + j;
        int c = wn + ni * 16 + ec;
        Cs[rr * 128 + (c ^ ((rr & 7) << 3))] = f2b(acc3[mi][ni][j]);
      }
  __syncthreads();
#pragma unroll
  for (int jj = 0; jj < 8; ++jj) {
    short8 ub = zero8();
    if (rok) ub = *(const short8*)&bup[(long)t * I_DIM + col0 + clb + jj * 8];
    short8 uv = *(const short8*)&Cs[rl * 128 + ((clb + jj * 8) ^ k8)];
    short8 o;
#pragma unroll
    for (int q = 0; q < 8; q += 2) {
      uint sp = svp[jj * 4 + q / 2];
      float u0 = b2f((ushort)uv[q]) + b2f((ushort)ub[q]);
      float u1 = b2f((ushort)uv[q + 1]) + b2f((ushort)ub[q + 1]);
      o[q]     = (short)f2b(w * b2f((ushort)(sp & 0xFFFFu)) * u0);
      o[q + 1] = (short)f2b(w * b2f((ushort)(sp >> 16)) * u1);
    }
    if (rok) *(short8*)&H[(long)r * I_DIM + col0 + clb + jj * 8] = o;
  }
}

// ---------------- plan-B fallback GEMM ----------------
template <int AF32, int BF32, int CBF16, int PEREXP, int AMAP>
__global__ __launch_bounds__(256) void gemm_f(
    const void* __restrict__ Ap, int lda,
    const void* __restrict__ Bp, int ldb, long Bstride,
    int M, int N, int K, int Npad,
    float* __restrict__ Cf, ushort* __restrict__ Cb, int ldc,
    const int* __restrict__ tok, const int* __restrict__ seg, const int* __restrict__ cnt) {
  __shared__ ushort smem[16384];
  ushort* As = smem;
  ushort* Bs = smem + 4096;
  const float* Af = (const float*)Ap;
  const ushort* Ab = (const ushort*)Ap;
  const float* Bf = (const float*)Bp;
  const ushort* Bb = (const ushort*)Bp;
  const int* amap = tok;
  if (PEREXP) {
    int e = blockIdx.z;
    int m0 = seg[e];
    M = cnt[e];
    if ((int)(blockIdx.y * 128) >= M) return;
    if (AMAP) {
      amap = tok + m0;
    } else {
      if (AF32) Af += (long)m0 * lda; else Ab += (long)m0 * lda;
    }
    if (BF32) Bf += (long)e * Bstride; else Bb += (long)e * Bstride;
    if (CBF16) Cb += (long)m0 * ldc; else Cf += (long)m0 * ldc;
  }
  const int tid = threadIdx.x;
  const int lane = tid & 63, wave = tid >> 6;
  const int wm = (wave >> 1) * 64, wn = (wave & 1) * 64;
  const int row0 = blockIdx.y * 128, col0 = blockIdx.x * 128;
  const int sub_r = tid >> 2;
  const int sub_c = (tid & 3) * 8;

  const float* afrow[2]; const ushort* abrow[2];
  const float* bfrow[2]; const ushort* bbrow[2];
#pragma unroll
  for (int p = 0; p < 2; ++p) {
    int r = row0 + p * 64 + sub_r; if (r > M - 1) r = M - 1;
    if (AMAP) r = amap[r];
    if (AF32) afrow[p] = Af + (long)r * lda + sub_c;
    else      abrow[p] = Ab + (long)r * lda + sub_c;
    int q = col0 + p * 64 + sub_r; if (q > N - 1) q = N - 1;
    if (BF32) bfrow[p] = Bf + (long)q * ldb + sub_c;
    else      bbrow[p] = Bb + (long)q * ldb + sub_c;
  }

  f32x4 acc[4][4] = {};

  for (int k0 = 0; k0 < K; k0 += 32) {
    float4 a0[2], a1[2], b0[2], b1[2];
    if (AF32) {
#pragma unroll
      for (int p = 0; p < 2; ++p) {
        a0[p] = *(const float4*)(afrow[p] + k0);
        a1[p] = *(const float4*)(afrow[p] + k0 + 4);
      }
    }
    if (BF32) {
#pragma unroll
      for (int p = 0; p < 2; ++p) {
        b0[p] = *(const float4*)(bfrow[p] + k0);
        b1[p] = *(const float4*)(bfrow[p] + k0 + 4);
      }
    }
    __syncthreads();
#pragma unroll
    for (int p = 0; p < 2; ++p) {
      if (AF32) {
        *(short8*)&As[(p * 256 + tid) * 8] = pack8(a0[p], a1[p]);
      } else {
        GLOAD(abrow[p] + k0, &As[(p * 256 + tid) * 8]);
      }
      if (BF32) {
        *(short8*)&Bs[(p * 256 + tid) * 8] = pack8(b0[p], b1[p]);
      } else {
        GLOAD(bbrow[p] + k0, &Bs[(p * 256 + tid) * 8]);
      }
    }
    __syncthreads();

    short8 av[4], bv[4];
#pragma unroll
    for (int mi = 0; mi < 4; ++mi)
      av[mi] = *(const short8*)&As[(wm + mi * 16 + (lane & 15)) * 32 + (lane >> 4) * 8];
#pragma unroll
    for (int ni = 0; ni < 4; ++ni)
      bv[ni] = *(const short8*)&Bs[(wn + ni * 16 + (lane & 15)) * 32 + (lane >> 4) * 8];
#pragma unroll
    for (int mi = 0; mi < 4; ++mi)
#pragma unroll
      for (int ni = 0; ni < 4; ++ni)
        acc[mi][ni] = __builtin_amdgcn_mfma_f32_16x16x32_bf16(av[mi], bv[ni], acc[mi][ni], 0, 0, 0);
  }

  const int er = (lane >> 4) * 4;
  const int ec = lane & 15;
  if (CBF16) {
    __syncthreads();
    ushort* Cs = smem;
#pragma unroll
    for (int mi = 0; mi < 4; ++mi)
#pragma unroll
      for (int ni = 0; ni < 4; ++ni)
#pragma unroll
        for (int j = 0; j < 4; ++j) {
          int rr = wm + mi * 16 + er + j;
          int c = wn + ni * 16 + ec;
          Cs[rr * 128 + (c ^ ((rr & 7) << 3))] =
              (col0 + c < N) ? f2b(acc[mi][ni][j]) : (ushort)0;
        }
    __syncthreads();
    const int rl = tid >> 1;
    const int clb = (tid & 1) * 64;
    const int r = row0 + rl;
    if (r < M) {
      const int k8 = (rl & 7) << 3;
#pragma unroll
      for (int jj = 0; jj < 8; ++jj) {
        int cg = col0 + clb + jj * 8;
        if (cg < Npad) {
          short8 v = *(const short8*)&Cs[rl * 128 + ((clb + jj * 8) ^ k8)];
          *(short8*)&Cb[(long)r * ldc + cg] = v;
        }
      }
    }
  } else {
#pragma unroll
    for (int mi = 0; mi < 4; ++mi)
#pragma unroll
      for (int ni = 0; ni < 4; ++ni)
#pragma unroll
        for (int j = 0; j < 4; ++j) {
          int r = row0 + wm + mi * 16 + er + j;
          int c = col0 + wn + ni * 16 + ec;
          if (r < M && c < Npad)
            Cf[(long)r * ldc + c] = (c < N) ? acc[mi][ni][j] : 0.f;
        }
  }
}

// ---------------- launch ----------------
extern "C" void kernel_launch(void* const* d_in, const int* in_sizes, int n_in,
                              void* d_out, int out_size, void* d_ws, size_t ws_size,
                              hipStream_t stream) {
  const float* x   = (const float*)d_in[0];
  const float* gw  = (const float*)d_in[1];
  const float* Wm1 = (const float*)d_in[2];
  const float* Wm2 = (const float*)d_in[3];
  const float* Wm3 = (const float*)d_in[4];
  const float* du1 = (const float*)d_in[5];
  const float* dv1 = (const float*)d_in[6];
  const float* du2 = (const float*)d_in[7];
  const float* dv2 = (const float*)d_in[8];
  const float* du3 = (const float*)d_in[9];
  const float* dv3 = (const float*)d_in[10];

  float* out_final  = (float*)d_out;
  float* out_logits = out_final + (long)T_TOK * H_DIM;

  char* p = (char*)d_ws;
  auto alloc = [&](size_t bytes) {
    char* r = p;
    p += (bytes + 255) & ~(size_t)255;
    return r;
  };

  float* comb   = (float*)alloc((size_t)T_TOK * E_NUM * 4);
  float* wrow   = (float*)alloc((size_t)P_PAIRS * 4);
  int* cnt      = (int*)alloc(64);
  int* cursor   = (int*)alloc(64);
  int* seg      = (int*)alloc(64);
  int* sel_e    = (int*)alloc((size_t)T_TOK * 2 * 4);
  int* tok      = (int*)alloc((size_t)P_PAIRS * 4);
  int* row_of   = (int*)alloc((size_t)T_TOK * 2 * 4);
  ushort* bgate_b = (ushort*)alloc((size_t)T_TOK * I_DIM * 2);   // later: hc
  ushort* bup_b   = (ushort*)alloc((size_t)T_TOK * I_DIM * 2);   // later: p2, then deltab
  ushort* hmidg   = (ushort*)alloc((size_t)P_PAIRS * I_DIM * 2); // earlier: p1|p3
  ushort* t1g     = (ushort*)alloc((size_t)P_PAIRS * RP * 2);
  ushort* t3g     = (ushort*)alloc((size_t)P_PAIRS * RP * 2);
  ushort* t2g     = (ushort*)alloc((size_t)P_PAIRS * RP * 2);
  ushort* du1b    = (ushort*)alloc((size_t)E_NUM * I_DIM * RP * 2);  // later: dp (w/ du3b)
  ushort* du3b    = (ushort*)alloc((size_t)E_NUM * I_DIM * RP * 2);
  ushort* du2b    = (ushort*)alloc((size_t)E_NUM * H_DIM * RP * 2);
  size_t needed_B = (size_t)(p - (char*)d_ws);
  ushort* xb   = (ushort*)alloc((size_t)T_TOK * H_DIM * 2);
  ushort* w1b  = (ushort*)alloc((size_t)I_DIM * H_DIM * 2);
  ushort* w3b  = (ushort*)alloc((size_t)I_DIM * H_DIM * 2);
  ushort* dv1b = (ushort*)alloc((size_t)E_NUM * R_RANK * H_DIM * 2);
  ushort* dv3b = (ushort*)alloc((size_t)E_NUM * R_RANK * H_DIM * 2);
  size_t needed_A = (size_t)(p - (char*)d_ws);
  ushort* w2b_d  = (ushort*)alloc((size_t)I_DIM * H_DIM * 2);
  ushort* dv2b_d = (ushort*)alloc((size_t)E_NUM * R_RANK * I_DIM * 2);
  size_t needed_A2 = (size_t)(p - (char*)d_ws);

  ushort* hc     = bgate_b;
  ushort* deltab = bup_b;

  if (ws_size < needed_B) return;
  const bool planA  = (ws_size >= needed_A);
  const bool planA2 = (ws_size >= needed_A2);

  dim3 blk(256);

  init_kernel<<<1, 64, 0, stream>>>(cnt, cursor);
  router_kernel<<<T_TOK / 4, 256, 0, stream>>>(x, gw, out_logits, comb, sel_e, cnt);
  scan_kernel<<<1, 64, 0, stream>>>(cnt, seg);
  assign_kernel<<<4, 256, 0, stream>>>(sel_e, comb, seg, cursor, tok, wrow, row_of);

  if (planA) {
    ushort* w2b  = planA2 ? w2b_d  : w1b;
    ushort* dv2b = planA2 ? dv2b_d : w3b;

    // all casts except Wm2/dv2 (one launch)
    megacast_kernel<<<2048, 256, 0, stream>>>(x, Wm1, Wm3, dv1, dv3, du1, du3, du2,
                                              xb, w1b, w3b, dv1b, dv3b, du1b, du3b, du2b);
    if (planA2)
      cast2_kernel<<<1024, 256, 0, stream>>>(Wm2, dv2, w2b, dv2b);

    // merged base gate/up + t1/t3 split-K8 : 2944 blocks
    float* p1 = (float*)hmidg;
    float* p3 = p1 + (long)8 * P_PAIRS * RP;
    k_early<<<2944, blk, 0, stream>>>(xb, w1b, w3b, dv1b, dv3b, tok, seg, cnt,
                                      bgate_b, bup_b, p1, p3);
    reduce2_kernel<<<2560, 256, 0, stream>>>(p1, p3, t1g, t3g, (long)P_PAIRS * RP);

    if (!planA2)  // w1b/w3b dead after k_early -> reuse for Wm2/dv2
      cast2_kernel<<<1024, 256, 0, stream>>>(Wm2, dv2, w2b, dv2b);

    // hmid (overwrites partial region)
    gemm_hmid<<<dim3(I_DIM / 128, 8, E_NUM), blk, 0, stream>>>(
        t1g, t3g, du1b, du3b, bgate_b, bup_b, tok, wrow, seg, cnt, hmidg);

    hcomb_kernel<<<(int)(((long)T_TOK * I_DIM / 8 + 255) / 256), 256, 0, stream>>>(hmidg, row_of, hc);

    // merged down split-K4 + t2 split-K8 : 1536 blocks
    float* dp = (float*)du1b;
    float* p2 = (float*)bup_b;
    k_phase2<<<dim3(H_DIM / 128, 8, 12), blk, 0, stream>>>(
        hc, w2b, hmidg, dv2b, seg, cnt, dp, p2);
    reduce_cast_kernel<8><<<1280, 256, 0, stream>>>(p2, (long)P_PAIRS * RP, t2g, (long)P_PAIRS * RP);

    // delta = t2g @ du2^T
    k_delta<<<dim3(H_DIM / 128, 8, E_NUM), blk, 0, stream>>>(t2g, du2b, seg, cnt, deltab);

    finalfixA_kernel<<<2048, 256, 0, stream>>>(out_final, dp, deltab, row_of);
  } else {
    // plan B fallback
    padcast8_kernel<<<4480, 256, 0, stream>>>(du1, du1b, (long)E_NUM * I_DIM);
    padcast8_kernel<<<4480, 256, 0, stream>>>(du3, du3b, (long)E_NUM * I_DIM);
    padcast8_kernel<<<1280, 256, 0, stream>>>(du2, du2b, (long)E_NUM * H_DIM);
    gemm_f<1, 1, 1, 0, 0><<<dim3(I_DIM / 128, T_TOK / 128, 1), blk, 0, stream>>>(
        x, H_DIM, Wm1, H_DIM, 0L, T_TOK, I_DIM, H_DIM, I_DIM,
        nullptr, bgate_b, I_DIM, nullptr, nullptr, nullptr);
    gemm_f<1, 1, 1, 0, 0><<<dim3(I_DIM / 128, T_TOK / 128, 1), blk, 0, stream>>>(
        x, H_DIM, Wm3, H_DIM, 0L, T_TOK, I_DIM, H_DIM, I_DIM,
        nullptr, bup_b, I_DIM, nullptr, nullptr, nullptr);
    gemm_f<1, 1, 1, 1, 1><<<dim3(2, 8, E_NUM), blk, 0, stream>>>(
        x, H_DIM, dv1, H_DIM, (long)R_RANK * H_DIM, 0, R_RANK, H_DIM, RP,
        nullptr, t1g, RP, tok, seg, cnt);
    gemm_f<1, 1, 1, 1, 1><<<dim3(2, 8, E_NUM), blk, 0, stream>>>(
        x, H_DIM, dv3, H_DIM, (long)R_RANK * H_DIM, 0, R_RANK, H_DIM, RP,
        nullptr, t3g, RP, tok, seg, cnt);
    gemm_hmid<<<dim3(I_DIM / 128, 8, E_NUM), blk, 0, stream>>>(
        t1g, t3g, du1b, du3b, bgate_b, bup_b, tok, wrow, seg, cnt, hmidg);
    hcomb_kernel<<<(int)(((long)T_TOK * I_DIM / 8 + 255) / 256), 256, 0, stream>>>(hmidg, row_of, hc);
    gemm_f<0, 1, 0, 0, 0><<<dim3(H_DIM / 128, T_TOK / 128, 1), blk, 0, stream>>>(
        hc, I_DIM, Wm2, I_DIM, 0L, T_TOK, H_DIM, I_DIM, H_DIM,
        out_final, nullptr, H_DIM, nullptr, nullptr, nullptr);
    gemm_f<0, 1, 1, 1, 0><<<dim3(2, 8, E_NUM), blk, 0, stream>>>(
        hmidg, I_DIM, dv2, I_DIM, (long)R_RANK * I_DIM, 0, R_RANK, I_DIM, RP,
        nullptr, t2g, RP, tok, seg, cnt);
    gemm_f<0, 0, 1, 1, 0><<<dim3(H_DIM / 128, 8, E_NUM), blk, 0, stream>>>(
        t2g, RP, du2b, RP, (long)H_DIM * RP, 0, H_DIM, RP, H_DIM,
        nullptr, deltab, H_DIM, tok, seg, cnt);
    finalfix_kernel<<<(int)(((long)T_TOK * H_DIM / 4 + 255) / 256), 256, 0, stream>>>(
        out_final, deltab, row_of);
  }
}

// Round 9
// 434.629 us; speedup vs baseline: 1.7113x; 1.1045x over previous
//
#include <hip/hip_runtime.h>

#define T_TOK 1024
#define H_DIM 2048
#define I_DIM 7168
#define E_NUM 8
#define R_RANK 159
#define RP 160
#define P_PAIRS 2048

// cast segment sizes in 8-element chunks
#define CH_X    262144L
#define CH_W    1835008L
#define CH_DV13 325632L
#define CH_DV2  1139712L
#define CH_DU13 1146880L
#define CH_DU2  327680L

typedef __attribute__((ext_vector_type(8))) short short8;
typedef __attribute__((ext_vector_type(4))) float f32x4;

__device__ __forceinline__ ushort f2b(float f) {
  uint u = __float_as_uint(f);
  uint r = (u + 0x7FFFu + ((u >> 16) & 1u)) >> 16;
  return (ushort)r;
}
__device__ __forceinline__ float b2f(ushort u) {
  return __uint_as_float(((uint)u) << 16);
}
__device__ __forceinline__ short8 pack8(float4 a, float4 b) {
  short8 o;
  o[0] = (short)f2b(a.x); o[1] = (short)f2b(a.y); o[2] = (short)f2b(a.z); o[3] = (short)f2b(a.w);
  o[4] = (short)f2b(b.x); o[5] = (short)f2b(b.y); o[6] = (short)f2b(b.z); o[7] = (short)f2b(b.w);
  return o;
}
__device__ __forceinline__ short8 zero8() {
  short8 z;
#pragma unroll
  for (int q = 0; q < 8; ++q) z[q] = 0;
  return z;
}
// bank-conflict swizzle (verified round 7: conflicts -> 0)
__device__ __forceinline__ int swzofs(int row, int g) { return (g ^ ((row >> 1) & 3)) * 8; }

#define GLOAD(gptr, lptr) \
  __builtin_amdgcn_global_load_lds((const __attribute__((address_space(1))) void*)(gptr), \
                                   (__attribute__((address_space(3))) void*)(lptr), 16, 0, 0)

// ---------------- router ----------------
__global__ __launch_bounds__(256) void router_kernel(
    const float* __restrict__ x, const float* __restrict__ gw,
    float* __restrict__ logits, float* __restrict__ comb,
    int* __restrict__ sel_e) {
  int wave = threadIdx.x >> 6, lane = threadIdx.x & 63;
  int t = blockIdx.x * 4 + wave;
  const float* xr = x + (long)t * H_DIM;
  float acc[8] = {0.f,0.f,0.f,0.f,0.f,0.f,0.f,0.f};
  for (int h = lane * 4; h < H_DIM; h += 256) {
    const float4 xv = *(const float4*)&xr[h];
#pragma unroll
    for (int e = 0; e < 8; ++e) {
      const float4 gv = *(const float4*)&gw[e * H_DIM + h];
      acc[e] += xv.x * gv.x + xv.y * gv.y + xv.z * gv.z + xv.w * gv.w;
    }
  }
#pragma unroll
  for (int off = 32; off > 0; off >>= 1)
#pragma unroll
    for (int e = 0; e < 8; ++e) acc[e] += __shfl_down(acc[e], off);
  if (lane == 0) {
#pragma unroll
    for (int e = 0; e < 8; ++e) logits[(long)t * 8 + e] = acc[e];
    int i0 = 0;
    for (int e = 1; e < 8; ++e) if (acc[e] > acc[i0]) i0 = e;
    int i1 = (i0 == 0) ? 1 : 0;
    for (int e = 0; e < 8; ++e) if (e != i0 && acc[e] > acc[i1]) i1 = e;
    float ee = __expf(acc[i1] - acc[i0]);
    float w0 = 1.f / (1.f + ee), w1 = ee / (1.f + ee);
    for (int e = 0; e < 8; ++e) comb[t * 8 + e] = 0.f;
    comb[t * 8 + i0] = w0;
    comb[t * 8 + i1] = w1;
    sel_e[t * 2] = i0;
    sel_e[t * 2 + 1] = i1;
  }
}

// one block: count per-expert, prefix, and assign rows (replaces init/scan/assign)
__global__ __launch_bounds__(256) void setup_kernel(
    const int* __restrict__ sel_e, const float* __restrict__ comb,
    int* __restrict__ cnt, int* __restrict__ seg,
    int* __restrict__ tok, float* __restrict__ wrow, int* __restrict__ row_of) {
  __shared__ int sc[8];
  __shared__ int sseg[8];
  __shared__ int scur[8];
  const int tid = threadIdx.x;
  if (tid < 8) sc[tid] = 0;
  __syncthreads();
  for (int i = tid; i < T_TOK * 2; i += 256) atomicAdd(&sc[sel_e[i]], 1);
  __syncthreads();
  if (tid == 0) {
    int s = 0;
    for (int e = 0; e < 8; ++e) { cnt[e] = sc[e]; seg[e] = s; sseg[e] = s; s += sc[e]; }
    seg[8] = s;
  }
  if (tid < 8) scur[tid] = 0;
  __syncthreads();
  for (int t = tid; t < T_TOK; t += 256) {
#pragma unroll
    for (int k = 0; k < 2; ++k) {
      int e = sel_e[t * 2 + k];
      int pos = atomicAdd(&scur[e], 1);
      int row = sseg[e] + pos;
      tok[row] = t;
      wrow[row] = comb[t * 8 + e];
      row_of[t * 2 + k] = row;
    }
  }
}

// ---------------- casts ----------------
__device__ __forceinline__ void castchunk(const float* __restrict__ s, ushort* __restrict__ d, long c) {
  const float4 a = *(const float4*)&s[c * 8];
  const float4 b = *(const float4*)&s[c * 8 + 4];
  *(short8*)&d[c * 8] = pack8(a, b);
}
__device__ __forceinline__ void padchunk(const float* __restrict__ s, ushort* __restrict__ d, long c) {
  long row = c / 20;
  int c0 = (int)(c % 20) * 8;
  short8 o;
#pragma unroll
  for (int j = 0; j < 8; ++j) {
    int cc = c0 + j;
    o[j] = (cc < R_RANK) ? (short)f2b(s[row * R_RANK + cc]) : (short)0;
  }
  *(short8*)&d[row * RP + c0] = o;
}

// all casts except Wm2/dv2, one launch
__global__ void megacast_kernel(
    const float* __restrict__ x, const float* __restrict__ Wm1, const float* __restrict__ Wm3,
    const float* __restrict__ dv1, const float* __restrict__ dv3,
    const float* __restrict__ du1, const float* __restrict__ du3, const float* __restrict__ du2,
    ushort* __restrict__ xb, ushort* __restrict__ w1b, ushort* __restrict__ w3b,
    ushort* __restrict__ dv1b, ushort* __restrict__ dv3b,
    ushort* __restrict__ du1b, ushort* __restrict__ du3b, ushort* __restrict__ du2b) {
  const long TOT = CH_W * 2 + CH_DU13 * 2 + CH_DU2 + CH_DV13 * 2 + CH_X;
  for (long c0 = (long)blockIdx.x * blockDim.x + threadIdx.x; c0 < TOT;
       c0 += (long)gridDim.x * blockDim.x) {
    long c = c0;
    if (c < CH_W)    { castchunk(Wm1, w1b, c); continue; }  c -= CH_W;
    if (c < CH_W)    { castchunk(Wm3, w3b, c); continue; }  c -= CH_W;
    if (c < CH_DU13) { padchunk(du1, du1b, c); continue; }  c -= CH_DU13;
    if (c < CH_DU13) { padchunk(du3, du3b, c); continue; }  c -= CH_DU13;
    if (c < CH_DU2)  { padchunk(du2, du2b, c); continue; }  c -= CH_DU2;
    if (c < CH_DV13) { castchunk(dv1, dv1b, c); continue; } c -= CH_DV13;
    if (c < CH_DV13) { castchunk(dv3, dv3b, c); continue; } c -= CH_DV13;
    castchunk(x, xb, c);
  }
}

// Wm2 + dv2 cast (fallback-tier standalone launch)
__global__ void cast2_kernel(const float* __restrict__ Wm2, const float* __restrict__ dv2,
                             ushort* __restrict__ w2b, ushort* __restrict__ dv2b) {
  const long TOT = CH_W + CH_DV2;
  for (long c0 = (long)blockIdx.x * blockDim.x + threadIdx.x; c0 < TOT;
       c0 += (long)gridDim.x * blockDim.x) {
    long c = c0;
    if (c < CH_W) { castchunk(Wm2, w2b, c); continue; }
    c -= CH_W;
    castchunk(dv2, dv2b, c);
  }
}

// plan-B padcast
__global__ void padcast8_kernel(const float* __restrict__ src, ushort* __restrict__ dst, long rows) {
  long n8 = rows * (RP / 8);
  long idx = (long)blockIdx.x * blockDim.x + threadIdx.x;
  long stride = (long)gridDim.x * blockDim.x;
  for (long i = idx; i < n8; i += stride) padchunk(src, dst, i);
}

__global__ void hcomb_kernel(const ushort* __restrict__ hmid, const int* __restrict__ row_of,
                             ushort* __restrict__ hc) {
  long idx = (long)blockIdx.x * blockDim.x + threadIdx.x;
  long total = (long)T_TOK * I_DIM / 8;
  if (idx >= total) return;
  long i = idx * 8;
  int t = (int)(i / I_DIM);
  int col = (int)(i % I_DIM);
  int r0 = row_of[t * 2], r1 = row_of[t * 2 + 1];
  const short8 a = *(const short8*)&hmid[(long)r0 * I_DIM + col];
  const short8 b = *(const short8*)&hmid[(long)r1 * I_DIM + col];
  short8 o;
#pragma unroll
  for (int j = 0; j < 8; ++j)
    o[j] = (short)f2b(b2f((ushort)a[j]) + b2f((ushort)b[j]));
  *(short8*)&hc[i] = o;
}

__global__ void finalfix_kernel(float* __restrict__ out, const ushort* __restrict__ delta,
                                const int* __restrict__ row_of) {
  long idx = (long)blockIdx.x * blockDim.x + threadIdx.x;
  long total = (long)T_TOK * H_DIM / 4;
  if (idx >= total) return;
  long i = idx * 4;
  int t = (int)(i / H_DIM);
  int col = (int)(i % H_DIM);
  int r0 = row_of[t * 2], r1 = row_of[t * 2 + 1];
  float4 d = *(float4*)&out[i];
  d.x += b2f(delta[(long)r0 * H_DIM + col + 0]) + b2f(delta[(long)r1 * H_DIM + col + 0]);
  d.y += b2f(delta[(long)r0 * H_DIM + col + 1]) + b2f(delta[(long)r1 * H_DIM + col + 1]);
  d.z += b2f(delta[(long)r0 * H_DIM + col + 2]) + b2f(delta[(long)r1 * H_DIM + col + 2]);
  d.w += b2f(delta[(long)r0 * H_DIM + col + 3]) + b2f(delta[(long)r1 * H_DIM + col + 3]);
  *(float4*)&out[i] = d;
}

__global__ void finalfixA_kernel(float* __restrict__ out, const float* __restrict__ dp,
                                 const ushort* __restrict__ delta, const int* __restrict__ row_of) {
  long idx = (long)blockIdx.x * blockDim.x + threadIdx.x;
  long total = (long)T_TOK * H_DIM / 4;
  if (idx >= total) return;
  long i = idx * 4;
  int t = (int)(i / H_DIM);
  int col = (int)(i % H_DIM);
  int r0 = row_of[t * 2], r1 = row_of[t * 2 + 1];
  const long plane = (long)T_TOK * H_DIM;
  float4 s = *(const float4*)&dp[i];
#pragma unroll
  for (int k = 1; k < 4; ++k) {
    const float4 q = *(const float4*)&dp[k * plane + i];
    s.x += q.x; s.y += q.y; s.z += q.z; s.w += q.w;
  }
  s.x += b2f(delta[(long)r0 * H_DIM + col + 0]) + b2f(delta[(long)r1 * H_DIM + col + 0]);
  s.y += b2f(delta[(long)r0 * H_DIM + col + 1]) + b2f(delta[(long)r1 * H_DIM + col + 1]);
  s.z += b2f(delta[(long)r0 * H_DIM + col + 2]) + b2f(delta[(long)r1 * H_DIM + col + 2]);
  s.w += b2f(delta[(long)r0 * H_DIM + col + 3]) + b2f(delta[(long)r1 * H_DIM + col + 3]);
  *(float4*)&out[i] = s;
}

template <int KS>
__global__ void reduce_cast_kernel(const float* __restrict__ P, long plane,
                                   ushort* __restrict__ out, long n) {
  long i = (long)blockIdx.x * blockDim.x + threadIdx.x;
  if (i >= n) return;
  float s = 0.f;
#pragma unroll
  for (int k = 0; k < KS; ++k) s += P[(long)k * plane + i];
  out[i] = f2b(s);
}

__global__ void reduce2_kernel(const float* __restrict__ p1, const float* __restrict__ p3,
                               ushort* __restrict__ t1g, ushort* __restrict__ t3g, long n) {
  long i = (long)blockIdx.x * blockDim.x + threadIdx.x;
  if (i >= 2 * n) return;
  const float* P = (i < n) ? p1 : p3;
  ushort* o = (i < n) ? t1g : t3g;
  long ii = (i < n) ? i : i - n;
  float s = 0.f;
#pragma unroll
  for (int k = 0; k < 8; ++k) s += P[(long)k * n + ii];
  o[ii] = f2b(s);
}

// ================= K-loops (swizzled staging + swizzled ds_read) =================

// BK=32
__device__ __forceinline__ void kloop32(
    const ushort* ar0, const ushort* ar1,
    const ushort* br0, const ushort* br1,
    int K, ushort* As, ushort* Bs,
    int tid, int lane, int wm, int wn, f32x4 acc[4][4]) {
  for (int k0 = 0; k0 < K; k0 += 32) {
    __syncthreads();
    GLOAD(ar0 + k0, &As[tid * 8]);
    GLOAD(ar1 + k0, &As[(256 + tid) * 8]);
    GLOAD(br0 + k0, &Bs[tid * 8]);
    GLOAD(br1 + k0, &Bs[(256 + tid) * 8]);
    __syncthreads();
    short8 av[4], bv[4];
#pragma unroll
    for (int mi = 0; mi < 4; ++mi) {
      int R = wm + mi * 16 + (lane & 15);
      av[mi] = *(const short8*)&As[R * 32 + swzofs(R, lane >> 4)];
    }
#pragma unroll
    for (int ni = 0; ni < 4; ++ni) {
      int R = wn + ni * 16 + (lane & 15);
      bv[ni] = *(const short8*)&Bs[R * 32 + swzofs(R, lane >> 4)];
    }
#pragma unroll
    for (int mi = 0; mi < 4; ++mi)
#pragma unroll
      for (int ni = 0; ni < 4; ++ni)
        acc[mi][ni] = __builtin_amdgcn_mfma_f32_16x16x32_bf16(av[mi], bv[ni], acc[mi][ni], 0, 0, 0);
  }
}

// BK=64, NI = active 16-col B groups per wave (4 = full tile; 2 = only 32 valid cols)
template <int NI>
__device__ __forceinline__ void kloop64t(
    const ushort* ar0, const ushort* ar1,
    const ushort* br0, const ushort* br1,
    int K, ushort* As, ushort* Bs,
    int tid, int lane, int wm, int wn, f32x4 acc[4][4]) {
  const int sub_r = tid >> 2;
  for (int k0 = 0; k0 < K; k0 += 64) {
    __syncthreads();
    GLOAD(ar0 + k0,      &As[tid * 8]);
    GLOAD(ar1 + k0,      &As[(256 + tid) * 8]);
    GLOAD(ar0 + k0 + 32, &As[4096 + tid * 8]);
    GLOAD(ar1 + k0 + 32, &As[4096 + (256 + tid) * 8]);
    if (NI == 4 || sub_r < 32) {
      GLOAD(br0 + k0,      &Bs[tid * 8]);
      GLOAD(br1 + k0,      &Bs[(256 + tid) * 8]);
      GLOAD(br0 + k0 + 32, &Bs[4096 + tid * 8]);
      GLOAD(br1 + k0 + 32, &Bs[4096 + (256 + tid) * 8]);
    }
    __syncthreads();
#pragma unroll
    for (int s = 0; s < 2; ++s) {
      short8 av[4], bv[NI];
#pragma unroll
      for (int mi = 0; mi < 4; ++mi) {
        int R = wm + mi * 16 + (lane & 15);
        av[mi] = *(const short8*)&As[s * 4096 + R * 32 + swzofs(R, lane >> 4)];
      }
#pragma unroll
      for (int ni = 0; ni < NI; ++ni) {
        int R = wn + ni * 16 + (lane & 15);
        bv[ni] = *(const short8*)&Bs[s * 4096 + R * 32 + swzofs(R, lane >> 4)];
      }
#pragma unroll
      for (int mi = 0; mi < 4; ++mi)
#pragma unroll
        for (int ni = 0; ni < NI; ++ni)
          acc[mi][ni] = __builtin_amdgcn_mfma_f32_16x16x32_bf16(av[mi], bv[ni], acc[mi][ni], 0, 0, 0);
    }
  }
}

// bf16 epilogue: LDS-transpose (32KB alias), coalesced short8 stores
__device__ __forceinline__ void epi_bf16(
    f32x4 acc[4][4], ushort* smem, int tid, int lane, int wm, int wn,
    int row0, int col0, int M, int Nvalid, int Npad, ushort* Cb, int ldc) {
  const int er = (lane >> 4) * 4, ec = lane & 15;
  __syncthreads();
#pragma unroll
  for (int mi = 0; mi < 4; ++mi)
#pragma unroll
    for (int ni = 0; ni < 4; ++ni)
#pragma unroll
      for (int j = 0; j < 4; ++j) {
        int rr = wm + mi * 16 + er + j;
        int c = wn + ni * 16 + ec;
        smem[rr * 128 + (c ^ ((rr & 7) << 3))] =
            (col0 + c < Nvalid) ? f2b(acc[mi][ni][j]) : (ushort)0;
      }
  __syncthreads();
  const int rl = tid >> 1, clb = (tid & 1) * 64;
  const int r = row0 + rl;
  if (r < M) {
    const int k8 = (rl & 7) << 3;
#pragma unroll
    for (int jj = 0; jj < 8; ++jj) {
      int cg = col0 + clb + jj * 8;
      if (cg < Npad) {
        short8 v = *(const short8*)&smem[rl * 128 + ((clb + jj * 8) ^ k8)];
        *(short8*)&Cb[(long)r * ldc + cg] = v;
      }
    }
  }
}

// ================= merged launches =================

// k_early: blocks 0..895 = base gate/up; 896..2943 = t1/t3 split-K8;
// 2944..3455 = Wm2/dv2 cast (docast tier only; outputs consumed by k_phase2 later)
__global__ __launch_bounds__(256) void k_early(
    const ushort* __restrict__ xb, const ushort* __restrict__ w1b, const ushort* __restrict__ w3b,
    const ushort* __restrict__ dv1b, const ushort* __restrict__ dv3b,
    const int* __restrict__ tok, const int* __restrict__ seg, const int* __restrict__ cnt,
    ushort* __restrict__ bgate, ushort* __restrict__ bup,
    float* __restrict__ p1, float* __restrict__ p3,
    const float* __restrict__ Wm2, const float* __restrict__ dv2,
    ushort* __restrict__ w2b, ushort* __restrict__ dv2b, int docast) {
  __shared__ ushort smem[16384];
  ushort* As = smem;
  ushort* Bs = smem + 8192;
  const int b = blockIdx.x;
  const int tid = threadIdx.x;
  const int lane = tid & 63, wave = tid >> 6;
  const int wm = (wave >> 1) * 64, wn = (wave & 1) * 64;
  const int sub_r = tid >> 2, sub_c = swzofs(sub_r, tid & 3);

  if (b < 896) {
    // ---- base: z=b/448 picks (w1b->bgate | w3b->bup) ----
    const int z = b / 448, r448 = b % 448;
    const int xk = r448 % 56, yk = r448 / 56;
    const int row0 = yk * 128, col0 = xk * 128;
    const ushort* B = z ? w3b : w1b;
    ushort* C = z ? bup : bgate;
    const ushort* ar0 = xb + (long)(row0 + sub_r) * H_DIM + sub_c;
    const ushort* ar1 = xb + (long)(row0 + 64 + sub_r) * H_DIM + sub_c;
    const ushort* br0 = B + (long)(col0 + sub_r) * H_DIM + sub_c;
    const ushort* br1 = B + (long)(col0 + 64 + sub_r) * H_DIM + sub_c;
    f32x4 acc[4][4] = {};
    kloop64t<4>(ar0, ar1, br0, br1, H_DIM, As, Bs, tid, lane, wm, wn, acc);
    epi_bf16(acc, smem, tid, lane, wm, wn, row0, col0, T_TOK, I_DIM, I_DIM, C, I_DIM);
  } else if (b < 2944) {
    // ---- t13 ----
    const int f = b - 896;
    const int xk = f & 1, yk = (f >> 1) & 7, zk = f >> 4;
    const int which = zk & 1;
    const int eks = zk >> 1;
    const int e = eks >> 3, ks = eks & 7;
    const int m0 = seg[e], M = cnt[e];
    const int row0 = yk * 128, col0 = xk * 128;
    if (row0 >= M) return;
    const int kbase = ks * 256;
    const ushort* Bsrc = (which ? dv3b : dv1b) + (long)e * R_RANK * H_DIM;
    float* P = which ? p3 : p1;
    int r0c = row0 + sub_r;      if (r0c > M - 1) r0c = M - 1;
    int r1c = row0 + 64 + sub_r; if (r1c > M - 1) r1c = M - 1;
    const ushort* ar0 = xb + (long)tok[m0 + r0c] * H_DIM + kbase + sub_c;
    const ushort* ar1 = xb + (long)tok[m0 + r1c] * H_DIM + kbase + sub_c;
    int q0 = col0 + sub_r;      if (q0 > R_RANK - 1) q0 = R_RANK - 1;
    int q1 = col0 + 64 + sub_r; if (q1 > R_RANK - 1) q1 = R_RANK - 1;
    const ushort* br0 = Bsrc + (long)q0 * H_DIM + kbase + sub_c;
    const ushort* br1 = Bsrc + (long)q1 * H_DIM + kbase + sub_c;
    f32x4 acc[4][4] = {};
    if (xk == 0)
      kloop64t<4>(ar0, ar1, br0, br1, 256, As, Bs, tid, lane, wm, wn, acc);
    else
      kloop64t<2>(ar0, ar1, br0, br1, 256, As, Bs, tid, lane, wm, wn, acc);
    const int er = (lane >> 4) * 4, ec = lane & 15;
    const long plane = (long)P_PAIRS * RP;
#pragma unroll
    for (int mi = 0; mi < 4; ++mi)
#pragma unroll
      for (int ni = 0; ni < 4; ++ni)
#pragma unroll
        for (int j = 0; j < 4; ++j) {
          int r = row0 + wm + mi * 16 + er + j;
          int c = col0 + wn + ni * 16 + ec;
          if (r < M && c < RP)
            P[(long)ks * plane + (long)(m0 + r) * RP + c] = (c < R_RANK) ? acc[mi][ni][j] : 0.f;
        }
  } else if (docast) {
    // ---- Wm2/dv2 cast riding under the GEMM latency shadow ----
    const long TOT = CH_W + CH_DV2;
    for (long c0 = (long)(b - 2944) * 256 + tid; c0 < TOT; c0 += 512L * 256L) {
      long c = c0;
      if (c < CH_W) { castchunk(Wm2, w2b, c); continue; }
      c -= CH_W;
      castchunk(dv2, dv2b, c);
    }
  }
}

// phase2: z<4 -> down split-K4; z>=4 -> t2 split-K8/expert (x2=1 blocks use NI=2)
__global__ __launch_bounds__(256) void k_phase2(
    const ushort* __restrict__ hc, const ushort* __restrict__ w2b,
    const ushort* __restrict__ hmidg, const ushort* __restrict__ dv2b,
    const int* __restrict__ seg, const int* __restrict__ cnt,
    float* __restrict__ dp, float* __restrict__ p2) {
  __shared__ ushort smem[16384];
  ushort* As = smem;
  ushort* Bs = smem + 8192;
  const int tid = threadIdx.x;
  const int lane = tid & 63, wave = tid >> 6;
  const int wm = (wave >> 1) * 64, wn = (wave & 1) * 64;
  const int sub_r = tid >> 2, sub_c = swzofs(sub_r, tid & 3);
  const int er = (lane >> 4) * 4, ec = lane & 15;

  if (blockIdx.z < 4) {
    const int ks = blockIdx.z;
    const int kbase = ks * (I_DIM / 4);
    const int row0 = blockIdx.y * 128, col0 = blockIdx.x * 128;
    const ushort* ar0 = hc + (long)(row0 + sub_r) * I_DIM + kbase + sub_c;
    const ushort* ar1 = hc + (long)(row0 + 64 + sub_r) * I_DIM + kbase + sub_c;
    const ushort* br0 = w2b + (long)(col0 + sub_r) * I_DIM + kbase + sub_c;
    const ushort* br1 = w2b + (long)(col0 + 64 + sub_r) * I_DIM + kbase + sub_c;
    f32x4 acc[4][4] = {};
    kloop64t<4>(ar0, ar1, br0, br1, I_DIM / 4, As, Bs, tid, lane, wm, wn, acc);
    float* Pk = dp + (long)ks * T_TOK * H_DIM;
#pragma unroll
    for (int mi = 0; mi < 4; ++mi)
#pragma unroll
      for (int ni = 0; ni < 4; ++ni)
#pragma unroll
        for (int j = 0; j < 4; ++j) {
          int r = row0 + wm + mi * 16 + er + j;
          int c = col0 + wn + ni * 16 + ec;
          Pk[(long)r * H_DIM + c] = acc[mi][ni][j];
        }
  } else {
    const int f = (blockIdx.z - 4) * 128 + blockIdx.y * 16 + blockIdx.x;  // 0..1023
    const int eks = f >> 4;
    const int e = eks >> 3, ks = eks & 7;
    const int rsub = f & 15;
    const int x2 = rsub & 1, y2 = rsub >> 1;
    const int m0 = seg[e], M = cnt[e];
    const int row0 = y2 * 128, col0 = x2 * 128;
    if (row0 >= M) return;
    const int kbase = ks * (I_DIM / 8);
    int r0c = row0 + sub_r;      if (r0c > M - 1) r0c = M - 1;
    int r1c = row0 + 64 + sub_r; if (r1c > M - 1) r1c = M - 1;
    const ushort* ar0 = hmidg + (long)(m0 + r0c) * I_DIM + kbase + sub_c;
    const ushort* ar1 = hmidg + (long)(m0 + r1c) * I_DIM + kbase + sub_c;
    int q0 = col0 + sub_r;      if (q0 > R_RANK - 1) q0 = R_RANK - 1;
    int q1 = col0 + 64 + sub_r; if (q1 > R_RANK - 1) q1 = R_RANK - 1;
    const ushort* br0 = dv2b + (long)e * R_RANK * I_DIM + (long)q0 * I_DIM + kbase + sub_c;
    const ushort* br1 = dv2b + (long)e * R_RANK * I_DIM + (long)q1 * I_DIM + kbase + sub_c;
    f32x4 acc[4][4] = {};
    if (x2 == 0)
      kloop64t<4>(ar0, ar1, br0, br1, I_DIM / 8, As, Bs, tid, lane, wm, wn, acc);
    else
      kloop64t<2>(ar0, ar1, br0, br1, I_DIM / 8, As, Bs, tid, lane, wm, wn, acc);
    const long plane = (long)P_PAIRS * RP;
#pragma unroll
    for (int mi = 0; mi < 4; ++mi)
#pragma unroll
      for (int ni = 0; ni < 4; ++ni)
#pragma unroll
        for (int j = 0; j < 4; ++j) {
          int r = row0 + wm + mi * 16 + er + j;
          int c = col0 + wn + ni * 16 + ec;
          if (r < M && c < RP)
            p2[(long)ks * plane + (long)(m0 + r) * RP + c] = (c < R_RANK) ? acc[mi][ni][j] : 0.f;
        }
  }
}

// delta: per-expert deltab = t2g @ du2b^T (K=160, BK=32+swizzle)
__global__ __launch_bounds__(256) void k_delta(
    const ushort* __restrict__ t2g, const ushort* __restrict__ du2b,
    const int* __restrict__ seg, const int* __restrict__ cnt,
    ushort* __restrict__ deltab) {
  __shared__ ushort smem[16384];
  ushort* As = smem;
  ushort* Bs = smem + 4096;
  const int e = blockIdx.z;
  const int m0 = seg[e], M = cnt[e];
  const int row0 = blockIdx.y * 128, col0 = blockIdx.x * 128;
  if (row0 >= M) return;
  const int tid = threadIdx.x;
  const int lane = tid & 63, wave = tid >> 6;
  const int wm = (wave >> 1) * 64, wn = (wave & 1) * 64;
  const int sub_r = tid >> 2, sub_c = swzofs(sub_r, tid & 3);
  int r0c = row0 + sub_r;      if (r0c > M - 1) r0c = M - 1;
  int r1c = row0 + 64 + sub_r; if (r1c > M - 1) r1c = M - 1;
  const ushort* ar0 = t2g + (long)(m0 + r0c) * RP + sub_c;
  const ushort* ar1 = t2g + (long)(m0 + r1c) * RP + sub_c;
  const ushort* br0 = du2b + (long)e * H_DIM * RP + (long)(col0 + sub_r) * RP + sub_c;
  const ushort* br1 = du2b + (long)e * H_DIM * RP + (long)(col0 + 64 + sub_r) * RP + sub_c;
  f32x4 acc[4][4] = {};
  kloop32(ar0, ar1, br0, br1, RP, As, Bs, tid, lane, wm, wn, acc);
  epi_bf16(acc, smem, tid, lane, wm, wn, row0, col0, M, H_DIM, H_DIM,
           deltab + (long)m0 * H_DIM, H_DIM);
}

// ---------------- fused dual hmid (BK=32, swizzled) ----------------
__global__ __launch_bounds__(256) void gemm_hmid(
    const ushort* __restrict__ t1g, const ushort* __restrict__ t3g,
    const ushort* __restrict__ du1b, const ushort* __restrict__ du3b,
    const ushort* __restrict__ bgate, const ushort* __restrict__ bup,
    const int* __restrict__ tok, const float* __restrict__ wrow,
    const int* __restrict__ seg, const int* __restrict__ cnt,
    ushort* __restrict__ hmid) {
  __shared__ ushort smem[16384];
  ushort* As1 = smem;
  ushort* As3 = smem + 4096;
  ushort* Bs1 = smem + 8192;
  ushort* Bs3 = smem + 12288;
  int e = blockIdx.z;
  int m0 = seg[e], M = cnt[e];
  if ((int)(blockIdx.y * 128) >= M) return;
  const ushort* A1 = t1g + (long)m0 * RP;
  const ushort* A3 = t3g + (long)m0 * RP;
  const ushort* B1 = du1b + (long)e * I_DIM * RP;
  const ushort* B3 = du3b + (long)e * I_DIM * RP;
  tok += m0; wrow += m0;
  ushort* H = hmid + (long)m0 * I_DIM;

  const int tid = threadIdx.x;
  const int lane = tid & 63, wave = tid >> 6;
  const int wm = (wave >> 1) * 64, wn = (wave & 1) * 64;
  const int row0 = blockIdx.y * 128, col0 = blockIdx.x * 128;
  const int sub_r = tid >> 2;
  const int sub_c = swzofs(sub_r, tid & 3);

  const ushort *a1r[2], *a3r[2], *b1r[2], *b3r[2];
#pragma unroll
  for (int p = 0; p < 2; ++p) {
    int r = row0 + p * 64 + sub_r; if (r > M - 1) r = M - 1;
    a1r[p] = A1 + (long)r * RP + sub_c;
    a3r[p] = A3 + (long)r * RP + sub_c;
    int q = col0 + p * 64 + sub_r; if (q > I_DIM - 1) q = I_DIM - 1;
    b1r[p] = B1 + (long)q * RP + sub_c;
    b3r[p] = B3 + (long)q * RP + sub_c;
  }

  f32x4 acc1[4][4] = {}, acc3[4][4] = {};

  for (int k0 = 0; k0 < RP; k0 += 32) {
    __syncthreads();
#pragma unroll
    for (int p = 0; p < 2; ++p) {
      GLOAD(a1r[p] + k0, &As1[(p * 256 + tid) * 8]);
      GLOAD(a3r[p] + k0, &As3[(p * 256 + tid) * 8]);
      GLOAD(b1r[p] + k0, &Bs1[(p * 256 + tid) * 8]);
      GLOAD(b3r[p] + k0, &Bs3[(p * 256 + tid) * 8]);
    }
    __syncthreads();

    short8 av1[4], av3[4], bv1[4], bv3[4];
#pragma unroll
    for (int mi = 0; mi < 4; ++mi) {
      int R = wm + mi * 16 + (lane & 15);
      int o = R * 32 + swzofs(R, lane >> 4);
      av1[mi] = *(const short8*)&As1[o];
      av3[mi] = *(const short8*)&As3[o];
    }
#pragma unroll
    for (int ni = 0; ni < 4; ++ni) {
      int R = wn + ni * 16 + (lane & 15);
      int o = R * 32 + swzofs(R, lane >> 4);
      bv1[ni] = *(const short8*)&Bs1[o];
      bv3[ni] = *(const short8*)&Bs3[o];
    }
#pragma unroll
    for (int mi = 0; mi < 4; ++mi)
#pragma unroll
      for (int ni = 0; ni < 4; ++ni) {
        acc1[mi][ni] = __builtin_amdgcn_mfma_f32_16x16x32_bf16(av1[mi], bv1[ni], acc1[mi][ni], 0, 0, 0);
        acc3[mi][ni] = __builtin_amdgcn_mfma_f32_16x16x32_bf16(av3[mi], bv3[ni], acc3[mi][ni], 0, 0, 0);
      }
  }

  const int er = (lane >> 4) * 4;
  const int ec = lane & 15;
  __syncthreads();
  ushort* Cs = smem;
#pragma unroll
  for (int mi = 0; mi < 4; ++mi)
#pragma unroll
    for (int ni = 0; ni < 4; ++ni)
#pragma unroll
      for (int j = 0; j < 4; ++j) {
        int rr = wm + mi * 16 + er + j;
        int c = wn + ni * 16 + ec;
        Cs[rr * 128 + (c ^ ((rr & 7) << 3))] = f2b(acc1[mi][ni][j]);
      }
  __syncthreads();
  const int rl = tid >> 1;
  const int clb = (tid & 1) * 64;
  const int r = row0 + rl;
  const bool rok = (r < M);
  const int t = rok ? tok[r] : 0;
  const float w = rok ? wrow[r] : 0.f;
  const int k8 = (rl & 7) << 3;
  uint svp[32];
#pragma unroll
  for (int jj = 0; jj < 8; ++jj) {
    short8 gb = zero8();
    if (rok) gb = *(const short8*)&bgate[(long)t * I_DIM + col0 + clb + jj * 8];
    short8 gv = *(const short8*)&Cs[rl * 128 + ((clb + jj * 8) ^ k8)];
#pragma unroll
    for (int q = 0; q < 8; q += 2) {
      float g0 = b2f((ushort)gv[q]) + b2f((ushort)gb[q]);
      float g1 = b2f((ushort)gv[q + 1]) + b2f((ushort)gb[q + 1]);
      float s0 = g0 / (1.f + __expf(-g0));
      float s1 = g1 / (1.f + __expf(-g1));
      svp[jj * 4 + q / 2] = (uint)f2b(s0) | ((uint)f2b(s1) << 16);
    }
  }
  __syncthreads();
#pragma unroll
  for (int mi = 0; mi < 4; ++mi)
#pragma unroll
    for (int ni = 0; ni < 4; ++ni)
#pragma unroll
      for (int j = 0; j < 4; ++j) {
        int rr = wm + mi * 16 + er + j;
        int c = wn + ni * 16 + ec;
        Cs[rr * 128 + (c ^ ((rr & 7) << 3))] = f2b(acc3[mi][ni][j]);
      }
  __syncthreads();
#pragma unroll
  for (int jj = 0; jj < 8; ++jj) {
    short8 ub = zero8();
    if (rok) ub = *(const short8*)&bup[(long)t * I_DIM + col0 + clb + jj * 8];
    short8 uv = *(const short8*)&Cs[rl * 128 + ((clb + jj * 8) ^ k8)];
    short8 o;
#pragma unroll
    for (int q = 0; q < 8; q += 2) {
      uint sp = svp[jj * 4 + q / 2];
      float u0 = b2f((ushort)uv[q]) + b2f((ushort)ub[q]);
      float u1 = b2f((ushort)uv[q + 1]) + b2f((ushort)ub[q + 1]);
      o[q]     = (short)f2b(w * b2f((ushort)(sp & 0xFFFFu)) * u0);
      o[q + 1] = (short)f2b(w * b2f((ushort)(sp >> 16)) * u1);
    }
    if (rok) *(short8*)&H[(long)r * I_DIM + col0 + clb + jj * 8] = o;
  }
}

// ---------------- plan-B fallback GEMM ----------------
template <int AF32, int BF32, int CBF16, int PEREXP, int AMAP>
__global__ __launch_bounds__(256) void gemm_f(
    const void* __restrict__ Ap, int lda,
    const void* __restrict__ Bp, int ldb, long Bstride,
    int M, int N, int K, int Npad,
    float* __restrict__ Cf, ushort* __restrict__ Cb, int ldc,
    const int* __restrict__ tok, const int* __restrict__ seg, const int* __restrict__ cnt) {
  __shared__ ushort smem[16384];
  ushort* As = smem;
  ushort* Bs = smem + 4096;
  const float* Af = (const float*)Ap;
  const ushort* Ab = (const ushort*)Ap;
  const float* Bf = (const float*)Bp;
  const ushort* Bb = (const ushort*)Bp;
  const int* amap = tok;
  if (PEREXP) {
    int e = blockIdx.z;
    int m0 = seg[e];
    M = cnt[e];
    if ((int)(blockIdx.y * 128) >= M) return;
    if (AMAP) {
      amap = tok + m0;
    } else {
      if (AF32) Af += (long)m0 * lda; else Ab += (long)m0 * lda;
    }
    if (BF32) Bf += (long)e * Bstride; else Bb += (long)e * Bstride;
    if (CBF16) Cb += (long)m0 * ldc; else Cf += (long)m0 * ldc;
  }
  const int tid = threadIdx.x;
  const int lane = tid & 63, wave = tid >> 6;
  const int wm = (wave >> 1) * 64, wn = (wave & 1) * 64;
  const int row0 = blockIdx.y * 128, col0 = blockIdx.x * 128;
  const int sub_r = tid >> 2;
  const int sub_c = (tid & 3) * 8;

  const float* afrow[2]; const ushort* abrow[2];
  const float* bfrow[2]; const ushort* bbrow[2];
#pragma unroll
  for (int p = 0; p < 2; ++p) {
    int r = row0 + p * 64 + sub_r; if (r > M - 1) r = M - 1;
    if (AMAP) r = amap[r];
    if (AF32) afrow[p] = Af + (long)r * lda + sub_c;
    else      abrow[p] = Ab + (long)r * lda + sub_c;
    int q = col0 + p * 64 + sub_r; if (q > N - 1) q = N - 1;
    if (BF32) bfrow[p] = Bf + (long)q * ldb + sub_c;
    else      bbrow[p] = Bb + (long)q * ldb + sub_c;
  }

  f32x4 acc[4][4] = {};

  for (int k0 = 0; k0 < K; k0 += 32) {
    float4 a0[2], a1[2], b0[2], b1[2];
    if (AF32) {
#pragma unroll
      for (int p = 0; p < 2; ++p) {
        a0[p] = *(const float4*)(afrow[p] + k0);
        a1[p] = *(const float4*)(afrow[p] + k0 + 4);
      }
    }
    if (BF32) {
#pragma unroll
      for (int p = 0; p < 2; ++p) {
        b0[p] = *(const float4*)(bfrow[p] + k0);
        b1[p] = *(const float4*)(bfrow[p] + k0 + 4);
      }
    }
    __syncthreads();
#pragma unroll
    for (int p = 0; p < 2; ++p) {
      if (AF32) {
        *(short8*)&As[(p * 256 + tid) * 8] = pack8(a0[p], a1[p]);
      } else {
        GLOAD(abrow[p] + k0, &As[(p * 256 + tid) * 8]);
      }
      if (BF32) {
        *(short8*)&Bs[(p * 256 + tid) * 8] = pack8(b0[p], b1[p]);
      } else {
        GLOAD(bbrow[p] + k0, &Bs[(p * 256 + tid) * 8]);
      }
    }
    __syncthreads();

    short8 av[4], bv[4];
#pragma unroll
    for (int mi = 0; mi < 4; ++mi)
      av[mi] = *(const short8*)&As[(wm + mi * 16 + (lane & 15)) * 32 + (lane >> 4) * 8];
#pragma unroll
    for (int ni = 0; ni < 4; ++ni)
      bv[ni] = *(const short8*)&Bs[(wn + ni * 16 + (lane & 15)) * 32 + (lane >> 4) * 8];
#pragma unroll
    for (int mi = 0; mi < 4; ++mi)
#pragma unroll
      for (int ni = 0; ni < 4; ++ni)
        acc[mi][ni] = __builtin_amdgcn_mfma_f32_16x16x32_bf16(av[mi], bv[ni], acc[mi][ni], 0, 0, 0);
  }

  const int er = (lane >> 4) * 4;
  const int ec = lane & 15;
  if (CBF16) {
    __syncthreads();
    ushort* Cs = smem;
#pragma unroll
    for (int mi = 0; mi < 4; ++mi)
#pragma unroll
      for (int ni = 0; ni < 4; ++ni)
#pragma unroll
        for (int j = 0; j < 4; ++j) {
          int rr = wm + mi * 16 + er + j;
          int c = wn + ni * 16 + ec;
          Cs[rr * 128 + (c ^ ((rr & 7) << 3))] =
              (col0 + c < N) ? f2b(acc[mi][ni][j]) : (ushort)0;
        }
    __syncthreads();
    const int rl = tid >> 1;
    const int clb = (tid & 1) * 64;
    const int r = row0 + rl;
    if (r < M) {
      const int k8 = (rl & 7) << 3;
#pragma unroll
      for (int jj = 0; jj < 8; ++jj) {
        int cg = col0 + clb + jj * 8;
        if (cg < Npad) {
          short8 v = *(const short8*)&Cs[rl * 128 + ((clb + jj * 8) ^ k8)];
          *(short8*)&Cb[(long)r * ldc + cg] = v;
        }
      }
    }
  } else {
#pragma unroll
    for (int mi = 0; mi < 4; ++mi)
#pragma unroll
      for (int ni = 0; ni < 4; ++ni)
#pragma unroll
        for (int j = 0; j < 4; ++j) {
          int r = row0 + wm + mi * 16 + er + j;
          int c = col0 + wn + ni * 16 + ec;
          if (r < M && c < Npad)
            Cf[(long)r * ldc + c] = (c < N) ? acc[mi][ni][j] : 0.f;
        }
  }
}

// ---------------- launch ----------------
extern "C" void kernel_launch(void* const* d_in, const int* in_sizes, int n_in,
                              void* d_out, int out_size, void* d_ws, size_t ws_size,
                              hipStream_t stream) {
  const float* x   = (const float*)d_in[0];
  const float* gw  = (const float*)d_in[1];
  const float* Wm1 = (const float*)d_in[2];
  const float* Wm2 = (const float*)d_in[3];
  const float* Wm3 = (const float*)d_in[4];
  const float* du1 = (const float*)d_in[5];
  const float* dv1 = (const float*)d_in[6];
  const float* du2 = (const float*)d_in[7];
  const float* dv2 = (const float*)d_in[8];
  const float* du3 = (const float*)d_in[9];
  const float* dv3 = (const float*)d_in[10];

  float* out_final  = (float*)d_out;
  float* out_logits = out_final + (long)T_TOK * H_DIM;

  char* p = (char*)d_ws;
  auto alloc = [&](size_t bytes) {
    char* r = p;
    p += (bytes + 255) & ~(size_t)255;
    return r;
  };

  float* comb   = (float*)alloc((size_t)T_TOK * E_NUM * 4);
  float* wrow   = (float*)alloc((size_t)P_PAIRS * 4);
  int* cnt      = (int*)alloc(64);
  int* seg      = (int*)alloc(64);
  int* sel_e    = (int*)alloc((size_t)T_TOK * 2 * 4);
  int* tok      = (int*)alloc((size_t)P_PAIRS * 4);
  int* row_of   = (int*)alloc((size_t)T_TOK * 2 * 4);
  ushort* bgate_b = (ushort*)alloc((size_t)T_TOK * I_DIM * 2);   // later: hc
  ushort* bup_b   = (ushort*)alloc((size_t)T_TOK * I_DIM * 2);   // later: p2, then deltab
  ushort* hmidg   = (ushort*)alloc((size_t)P_PAIRS * I_DIM * 2); // earlier: p1|p3
  ushort* t1g     = (ushort*)alloc((size_t)P_PAIRS * RP * 2);
  ushort* t3g     = (ushort*)alloc((size_t)P_PAIRS * RP * 2);
  ushort* t2g     = (ushort*)alloc((size_t)P_PAIRS * RP * 2);
  ushort* du1b    = (ushort*)alloc((size_t)E_NUM * I_DIM * RP * 2);  // later: dp (w/ du3b)
  ushort* du3b    = (ushort*)alloc((size_t)E_NUM * I_DIM * RP * 2);
  ushort* du2b    = (ushort*)alloc((size_t)E_NUM * H_DIM * RP * 2);
  size_t needed_B = (size_t)(p - (char*)d_ws);
  ushort* xb   = (ushort*)alloc((size_t)T_TOK * H_DIM * 2);
  ushort* w1b  = (ushort*)alloc((size_t)I_DIM * H_DIM * 2);
  ushort* w3b  = (ushort*)alloc((size_t)I_DIM * H_DIM * 2);
  ushort* dv1b = (ushort*)alloc((size_t)E_NUM * R_RANK * H_DIM * 2);
  ushort* dv3b = (ushort*)alloc((size_t)E_NUM * R_RANK * H_DIM * 2);
  size_t needed_A = (size_t)(p - (char*)d_ws);
  ushort* w2b_d  = (ushort*)alloc((size_t)I_DIM * H_DIM * 2);
  ushort* dv2b_d = (ushort*)alloc((size_t)E_NUM * R_RANK * I_DIM * 2);
  size_t needed_A2 = (size_t)(p - (char*)d_ws);

  ushort* hc     = bgate_b;
  ushort* deltab = bup_b;

  if (ws_size < needed_B) return;
  const bool planA  = (ws_size >= needed_A);
  const bool planA2 = (ws_size >= needed_A2);

  dim3 blk(256);

  router_kernel<<<T_TOK / 4, 256, 0, stream>>>(x, gw, out_logits, comb, sel_e);
  setup_kernel<<<1, 256, 0, stream>>>(sel_e, comb, cnt, seg, tok, wrow, row_of);

  if (planA) {
    ushort* w2b  = planA2 ? w2b_d  : w1b;
    ushort* dv2b = planA2 ? dv2b_d : w3b;

    // all casts except Wm2/dv2 (one launch)
    megacast_kernel<<<2048, 256, 0, stream>>>(x, Wm1, Wm3, dv1, dv3, du1, du3, du2,
                                              xb, w1b, w3b, dv1b, dv3b, du1b, du3b, du2b);

    // merged base gate/up + t1/t3 split-K8 + (planA2) Wm2/dv2 cast : 3456 blocks
    float* p1 = (float*)hmidg;
    float* p3 = p1 + (long)8 * P_PAIRS * RP;
    k_early<<<3456, blk, 0, stream>>>(xb, w1b, w3b, dv1b, dv3b, tok, seg, cnt,
                                      bgate_b, bup_b, p1, p3,
                                      Wm2, dv2, w2b, dv2b, planA2 ? 1 : 0);
    reduce2_kernel<<<2560, 256, 0, stream>>>(p1, p3, t1g, t3g, (long)P_PAIRS * RP);

    if (!planA2)  // w1b/w3b dead after k_early -> reuse for Wm2/dv2
      cast2_kernel<<<1024, 256, 0, stream>>>(Wm2, dv2, w2b, dv2b);

    // hmid (overwrites partial region)
    gemm_hmid<<<dim3(I_DIM / 128, 8, E_NUM), blk, 0, stream>>>(
        t1g, t3g, du1b, du3b, bgate_b, bup_b, tok, wrow, seg, cnt, hmidg);

    hcomb_kernel<<<(int)(((long)T_TOK * I_DIM / 8 + 255) / 256), 256, 0, stream>>>(hmidg, row_of, hc);

    // merged down split-K4 + t2 split-K8 : 1536 blocks
    float* dp = (float*)du1b;
    float* p2 = (float*)bup_b;
    k_phase2<<<dim3(H_DIM / 128, 8, 12), blk, 0, stream>>>(
        hc, w2b, hmidg, dv2b, seg, cnt, dp, p2);
    reduce_cast_kernel<8><<<1280, 256, 0, stream>>>(p2, (long)P_PAIRS * RP, t2g, (long)P_PAIRS * RP);

    // delta = t2g @ du2^T
    k_delta<<<dim3(H_DIM / 128, 8, E_NUM), blk, 0, stream>>>(t2g, du2b, seg, cnt, deltab);

    finalfixA_kernel<<<2048, 256, 0, stream>>>(out_final, dp, deltab, row_of);
  } else {
    // plan B fallback
    padcast8_kernel<<<4480, 256, 0, stream>>>(du1, du1b, (long)E_NUM * I_DIM);
    padcast8_kernel<<<4480, 256, 0, stream>>>(du3, du3b, (long)E_NUM * I_DIM);
    padcast8_kernel<<<1280, 256, 0, stream>>>(du2, du2b, (long)E_NUM * H_DIM);
    gemm_f<1, 1, 1, 0, 0><<<dim3(I_DIM / 128, T_TOK / 128, 1), blk, 0, stream>>>(
        x, H_DIM, Wm1, H_DIM, 0L, T_TOK, I_DIM, H_DIM, I_DIM,
        nullptr, bgate_b, I_DIM, nullptr, nullptr, nullptr);
    gemm_f<1, 1, 1, 0, 0><<<dim3(I_DIM / 128, T_TOK / 128, 1), blk, 0, stream>>>(
        x, H_DIM, Wm3, H_DIM, 0L, T_TOK, I_DIM, H_DIM, I_DIM,
        nullptr, bup_b, I_DIM, nullptr, nullptr, nullptr);
    gemm_f<1, 1, 1, 1, 1><<<dim3(2, 8, E_NUM), blk, 0, stream>>>(
        x, H_DIM, dv1, H_DIM, (long)R_RANK * H_DIM, 0, R_RANK, H_DIM, RP,
        nullptr, t1g, RP, tok, seg, cnt);
    gemm_f<1, 1, 1, 1, 1><<<dim3(2, 8, E_NUM), blk, 0, stream>>>(
        x, H_DIM, dv3, H_DIM, (long)R_RANK * H_DIM, 0, R_RANK, H_DIM, RP,
        nullptr, t3g, RP, tok, seg, cnt);
    gemm_hmid<<<dim3(I_DIM / 128, 8, E_NUM), blk, 0, stream>>>(
        t1g, t3g, du1b, du3b, bgate_b, bup_b, tok, wrow, seg, cnt, hmidg);
    hcomb_kernel<<<(int)(((long)T_TOK * I_DIM / 8 + 255) / 256), 256, 0, stream>>>(hmidg, row_of, hc);
    gemm_f<0, 1, 0, 0, 0><<<dim3(H_DIM / 128, T_TOK / 128, 1), blk, 0, stream>>>(
        hc, I_DIM, Wm2, I_DIM, 0L, T_TOK, H_DIM, I_DIM, H_DIM,
        out_final, nullptr, H_DIM, nullptr, nullptr, nullptr);
    gemm_f<0, 1, 1, 1, 0><<<dim3(2, 8, E_NUM), blk, 0, stream>>>(
        hmidg, I_DIM, dv2, I_DIM, (long)R_RANK * I_DIM, 0, R_RANK, I_DIM, RP,
        nullptr, t2g, RP, tok, seg, cnt);
    gemm_f<0, 0, 1, 1, 0><<<dim3(H_DIM / 128, 8, E_NUM), blk, 0, stream>>>(
        t2g, RP, du2b, RP, (long)H_DIM * RP, 0, H_DIM, RP, H_DIM,
        nullptr, deltab, H_DIM, tok, seg, cnt);
    finalfix_kernel<<<(int)(((long)T_TOK * H_DIM / 4 + 255) / 256), 256, 0, stream>>>(
        out_final, deltab, row_of);
  }
}